// Round 21
// baseline (850.558 us; speedup 1.0000x reference)
//
#include <hip/hip_runtime.h>
#include <hip/hip_bf16.h>
#include <math.h>

typedef __hip_bfloat16 bf16;
typedef __attribute__((ext_vector_type(4))) float f32x4;
typedef __attribute__((ext_vector_type(8))) short short8;
typedef __attribute__((ext_vector_type(4))) short short4v;

#define BATCH   8192
#define NTOT    65536      // 8 chunks * BATCH
#define NT2     131072     // 2 frames * NTOT (enc2 out)
#define NW      262144     // 8 chunks * 4 frames * BATCH
#define HID     128

__device__ __forceinline__ float b2f(bf16 v){ return __bfloat162float(v); }
__device__ __forceinline__ bf16  f2b(float v){ return __float2bfloat16(v); }
__device__ __forceinline__ short f2bs(float v){
  bf16 b = __float2bfloat16(v);
  return *reinterpret_cast<short*>(&b);
}
__device__ __forceinline__ float sigf(float x){ return 1.0f/(1.0f+__expf(-x)); }
__device__ __forceinline__ float tanhfast(float x){
  return 1.0f - 2.0f/(__expf(2.0f*x)+1.0f);
}

// ---------------------------------------------------------------------------
// Weight conversion (hi/lo split: W = hi + lo, lo = bf16(W - hi))
// ---------------------------------------------------------------------------
__global__ __launch_bounds__(256) void k_wcvt(        // stft W -> bf16 [258][256]
    const float* __restrict__ W, bf16* __restrict__ Wb)
{
  const int idx = blockIdx.x*256 + threadIdx.x;
  if (idx < 258*256) Wb[idx] = f2b(W[idx]);
}
__global__ __launch_bounds__(256) void k_w1cvt(       // w1 -> [3][128][320] hi|lo
    const float* __restrict__ w1, bf16* __restrict__ w1b)
{
  const int idx = blockIdx.x*256 + threadIdx.x;       // 3*128*320 = 122880
  if (idx >= 122880) return;
  const int dt = idx / 40960, rem = idx % 40960;
  const int cout = rem / 320, k = rem % 320;
  const int kk = (k >= 160) ? (k - 160) : k;
  const float v = (kk < 129) ? w1[(cout*129 + kk)*3 + dt] : 0.f;
  const bf16 hi = f2b(v);
  w1b[idx] = (k >= 160) ? f2b(v - b2f(hi)) : hi;
}
__global__ __launch_bounds__(256) void k_w2cvt(       // w2 -> [3][64][256] hi|lo
    const float* __restrict__ w2, bf16* __restrict__ w2b)
{
  const int idx = blockIdx.x*256 + threadIdx.x;       // 3*64*256 = 49152
  if (idx >= 49152) return;
  const int dt = idx >> 14, cout = (idx >> 8) & 63, k = idx & 255;
  const int kk = k & 127;
  const float v = w2[(cout*128 + kk)*3 + dt];
  const bf16 hi = f2b(v);
  w2b[idx] = (k >= 128) ? f2b(v - b2f(hi)) : hi;
}
// enc3 taps 1,2 -> w3e[64][256] hi|lo; enc4 center -> w4e[128][128] hi|lo
__global__ __launch_bounds__(256) void k_w34cvt(
    const float* __restrict__ w3, const float* __restrict__ w4,
    bf16* __restrict__ w3e, bf16* __restrict__ w4e)
{
  const int idx = blockIdx.x*256 + threadIdx.x;       // 32768
  if (idx >= 32768) return;
  if (idx < 16384){
    const int row = idx >> 8, k = idx & 255;
    const int kk = k & 127, cin = kk >> 1, t = kk & 1;
    const float v = w3[(row*64 + cin)*3 + 1 + t];
    const bf16 hi = f2b(v);
    w3e[idx] = (k >= 128) ? f2b(v - b2f(hi)) : hi;
  } else {
    const int i2 = idx - 16384;
    const int row = i2 >> 7, k = i2 & 127;
    const int cin = k & 63;
    const float v = w4[(row*64 + cin)*3 + 1];
    const bf16 hi = f2b(v);
    w4e[i2] = (k >= 64) ? f2b(v - b2f(hi)) : hi;
  }
}
// Whh-only recurrent weights -> [512][384]: [Whh_hi | Whh_hi | Whh_lo]
__global__ __launch_bounds__(256) void k_wlcvt3(
    const float* __restrict__ whh, bf16* __restrict__ wl3)
{
  const int idx = blockIdx.x*256 + threadIdx.x;       // 512*384 = 196608
  if (idx >= 196608) return;
  const int r = idx / 384, k = idx % 384;
  const int part = k >> 7, kk = k & 127;
  const float f = whh[r*128 + kk];
  const bf16 hi = f2b(f);
  wl3[idx] = (part < 2) ? hi : f2b(f - b2f(hi));
}
// Wih hi/lo planes: wlx[2][512][128]
__global__ __launch_bounds__(256) void k_wlxcvt(
    const float* __restrict__ wih, bf16* __restrict__ wlx)
{
  const int idx = blockIdx.x*256 + threadIdx.x;       // 131072
  if (idx >= 131072) return;
  const int pl = idx >> 16, rem = idx & 65535;
  const float f = wih[rem];
  const bf16 hi = f2b(f);
  wlx[idx] = (pl == 0) ? hi : f2b(f - b2f(hi));
}

// ---------------------------------------------------------------------------
// K1 v5 (validated r19): STFT MFMA GEMM, per-pass A-tile staged in LDS.
// mag [129][NW].
// ---------------------------------------------------------------------------
__global__ __launch_bounds__(256) void k_stft3(
    const float* __restrict__ audio, const bf16* __restrict__ Wb,
    bf16* __restrict__ mag)
{
  __shared__ __align__(16) char ALDS[96*512];      // 48 KB
  __shared__ __align__(16) bf16 refl[4*8*64];      // 4 KB
  const int tid = threadIdx.x, lane = tid & 63, wq = tid >> 6;
  const int r0 = blockIdx.x * 4;                   // 2048 blocks
  const float* arow = audio + (size_t)(r0 + wq) * 4160;

  #pragma unroll
  for (int q = 0; q < 8; ++q){
    const int e = q*64 + lane;
    const int i = e >> 6, k = e & 63;
    refl[(wq*8 + i)*64 + k] = f2b(arow[512*i + 64 - k]);
  }

  const int kgo8 = (lane>>4)*8;
  short8 Bfrag[2][8];
  #pragma unroll
  for (int ng = 0; ng < 2; ++ng){
    const int wl = ng*16 + (lane & 15);
    const int i = wl >> 2, t = wl & 3;
    #pragma unroll
    for (int ks = 0; ks < 8; ++ks){
      const int kb = ks*32 + kgo8;
      if (t == 0 && kb < 64){
        Bfrag[ng][ks] = *(const short8*)(refl + (wq*8 + i)*64 + kb);
      } else {
        const float* src = arow + 512*i + 128*t - 64 + kb;
        const float4 v0 = *(const float4*)(src);
        const float4 v1 = *(const float4*)(src + 4);
        short8 s;
        s[0]=f2bs(v0.x); s[1]=f2bs(v0.y); s[2]=f2bs(v0.z); s[3]=f2bs(v0.w);
        s[4]=f2bs(v1.x); s[5]=f2bs(v1.y); s[6]=f2bs(v1.z); s[7]=f2bs(v1.w);
        Bfrag[ng][ks] = s;
      }
    }
  }

  const int kab = (lane>>4)*16;
  for (int pass = 0; pass < 3; ++pass){
    __syncthreads();
    for (int idx = tid; idx < 96*32; idx += 256){
      const int ar = idx >> 5;
      const int cb = (idx & 31) * 16;
      const int b3 = ar >> 5, reim = (ar >> 4) & 1, bl = ar & 15;
      int bin = pass*48 + b3*16 + bl;
      if (bin > 128) bin = 128;
      const int grow = bin + reim*129;
      int off = ar*512 + cb; off ^= ((ar&7)<<4);
      *(f32x4*)(ALDS + off) = *(const f32x4*)((const char*)Wb + grow*512 + cb);
    }
    __syncthreads();

    f32x4 accRe[3][2], accIm[3][2];
    #pragma unroll
    for (int b3 = 0; b3 < 3; ++b3)
      #pragma unroll
      for (int ng = 0; ng < 2; ++ng){
        accRe[b3][ng] = f32x4{0.f,0.f,0.f,0.f};
        accIm[b3][ng] = f32x4{0.f,0.f,0.f,0.f};
      }
    #pragma unroll
    for (int ks = 0; ks < 8; ++ks){
      #pragma unroll
      for (int b3 = 0; b3 < 3; ++b3){
        const int arRe = b3*32 + (lane & 15);
        const int arIm = arRe + 16;
        int offRe = arRe*512 + ks*64 + kab; offRe ^= ((arRe&7)<<4);
        int offIm = arIm*512 + ks*64 + kab; offIm ^= ((arIm&7)<<4);
        const short8 aRe = *(const short8*)(ALDS + offRe);
        const short8 aIm = *(const short8*)(ALDS + offIm);
        #pragma unroll
        for (int ng = 0; ng < 2; ++ng){
          accRe[b3][ng] = __builtin_amdgcn_mfma_f32_16x16x32_bf16(
              aRe, Bfrag[ng][ks], accRe[b3][ng], 0, 0, 0);
          accIm[b3][ng] = __builtin_amdgcn_mfma_f32_16x16x32_bf16(
              aIm, Bfrag[ng][ks], accIm[b3][ng], 0, 0, 0);
        }
      }
    }
    #pragma unroll
    for (int b3 = 0; b3 < 3; ++b3)
      #pragma unroll
      for (int j = 0; j < 4; ++j){
        const int bin = (pass*3 + b3)*16 + (lane>>4)*4 + j;
        if (bin <= 128){
          #pragma unroll
          for (int ng = 0; ng < 2; ++ng){
            const int wl = ng*16 + (lane & 15);
            const int i = wl >> 2, t = wl & 3;
            const float re = accRe[b3][ng][j], im = accIm[b3][ng][j];
            mag[(size_t)bin*NW + (size_t)i*32768 + (r0+wq)*4 + t] =
                f2b(sqrtf(re*re + im*im));
          }
        }
      }
  }
}

// ---------------------------------------------------------------------------
// K2: enc1 MFMA GEMM hi/lo (validated r13). h1 [128][NW].
// ---------------------------------------------------------------------------
#define E1_LDS (192*320)
__global__ __launch_bounds__(256) void k_enc1_gemm(
    const bf16* __restrict__ mag, const bf16* __restrict__ w1b,
    const float* __restrict__ b1, bf16* __restrict__ h1)
{
  __shared__ __align__(16) char Bs[E1_LDS];
  const int tid = threadIdx.x, lane = tid & 63, wq = tid >> 6;
  const int n0 = blockIdx.x * 32;
  const int i  = n0 >> 13, b0 = n0 & 8191;
  const size_t colbase = (size_t)i*32768 + (size_t)b0*4;

  for (int off = tid*16; off < E1_LDS; off += 256*16)
    *(f32x4*)(Bs + off) = f32x4{0.f,0.f,0.f,0.f};
  __syncthreads();
  for (int it = tid; it < 129*64; it += 256){
    const int cin = it >> 6, seg = it & 63;
    const unsigned int pair =
        *(const unsigned int*)(mag + (size_t)cin*NW + colbase + seg*2);
    #pragma unroll
    for (int q = 0; q < 2; ++q){
      const int w = seg*2 + q;
      const int row = (w>>2)*6 + (w&3) + 1;
      int off = row*320 + cin*2; off ^= ((row&7)<<4);
      *(short*)(Bs + off) = (short)((q==0) ? (pair & 0xffff) : (pair >> 16));
    }
  }
  __syncthreads();

  const int wr = wq >> 1, wc = wq & 1;
  f32x4 acc[4][4];
  #pragma unroll
  for (int mg = 0; mg < 4; ++mg)
    #pragma unroll
    for (int ng = 0; ng < 4; ++ng) acc[mg][ng] = f32x4{0.f,0.f,0.f,0.f};

  int brow[4], acol[4];
  #pragma unroll
  for (int ng = 0; ng < 4; ++ng){
    const int w = wc*64 + ng*16 + (lane & 15);
    brow[ng] = (w>>2)*6 + (w&3);
  }
  #pragma unroll
  for (int mg = 0; mg < 4; ++mg) acol[mg] = wr*64 + mg*16 + (lane & 15);
  const int kb = (lane>>4)*16;

  for (int dt = 0; dt < 3; ++dt){
    #pragma unroll
    for (int ks = 0; ks < 5; ++ks){
      short8 afrH[4], afrL[4], bfr[4];
      #pragma unroll
      for (int mg = 0; mg < 4; ++mg){
        const char* base = (const char*)w1b +
            ((dt*128 + acol[mg])*320 + ks*32)*2 + kb;
        afrH[mg] = *(const short8*)base;
        afrL[mg] = *(const short8*)(base + 320);
      }
      #pragma unroll
      for (int ng = 0; ng < 4; ++ng){
        const int row = brow[ng] + dt;
        int off = row*320 + ks*64 + kb; off ^= ((row&7)<<4);
        bfr[ng] = *(const short8*)(Bs + off);
      }
      #pragma unroll
      for (int mg = 0; mg < 4; ++mg)
        #pragma unroll
        for (int ng = 0; ng < 4; ++ng){
          acc[mg][ng] = __builtin_amdgcn_mfma_f32_16x16x32_bf16(
              afrH[mg], bfr[ng], acc[mg][ng], 0, 0, 0);
          acc[mg][ng] = __builtin_amdgcn_mfma_f32_16x16x32_bf16(
              afrL[mg], bfr[ng], acc[mg][ng], 0, 0, 0);
        }
    }
  }
  #pragma unroll
  for (int mg = 0; mg < 4; ++mg)
    #pragma unroll
    for (int j = 0; j < 4; ++j){
      const int cout = wr*64 + mg*16 + (lane>>4)*4 + j;
      const float bv = b1[cout];
      #pragma unroll
      for (int ng = 0; ng < 4; ++ng){
        const int col = wc*64 + ng*16 + (lane & 15);
        float v = acc[mg][ng][j] + bv; v = v > 0.f ? v : 0.f;
        h1[(size_t)cout*NW + colbase + col] = f2b(v);
      }
    }
}

// ---------------------------------------------------------------------------
// K3: enc2 MFMA GEMM hi/lo (validated). h2 [64][NT2].
// ---------------------------------------------------------------------------
#define E2_LDS (160*256)
__global__ __launch_bounds__(256) void k_enc2_gemm(
    const bf16* __restrict__ h1, const bf16* __restrict__ w2b,
    const float* __restrict__ b2, bf16* __restrict__ h2)
{
  __shared__ __align__(16) char Bs[E2_LDS];
  const int tid = threadIdx.x, lane = tid & 63, wq = tid >> 6;
  const int n0 = blockIdx.x * 32;
  const int i  = n0 >> 13, b0 = n0 & 8191;
  const size_t colbase = (size_t)i*32768 + (size_t)b0*4;
  const size_t col2base = (size_t)i*16384 + (size_t)b0*2;

  for (int off = tid*16; off < E2_LDS; off += 256*16)
    *(f32x4*)(Bs + off) = f32x4{0.f,0.f,0.f,0.f};
  __syncthreads();
  for (int it = tid; it < 128*64; it += 256){
    const int cin = it >> 6, seg = it & 63;
    const unsigned int pair =
        *(const unsigned int*)(h1 + (size_t)cin*NW + colbase + seg*2);
    #pragma unroll
    for (int q = 0; q < 2; ++q){
      const int w = seg*2 + q;
      const int row = (w>>2)*5 + (w&3) + 1;
      int off = row*256 + cin*2; off ^= ((row&7)<<4);
      *(short*)(Bs + off) = (short)((q==0) ? (pair & 0xffff) : (pair >> 16));
    }
  }
  __syncthreads();

  const int wr = wq >> 1, wc = wq & 1;
  f32x4 acc[2][2];
  #pragma unroll
  for (int mg = 0; mg < 2; ++mg)
    #pragma unroll
    for (int ng = 0; ng < 2; ++ng) acc[mg][ng] = f32x4{0.f,0.f,0.f,0.f};

  int brow[2], acol[2];
  #pragma unroll
  for (int ng = 0; ng < 2; ++ng){
    const int wl = wc*32 + ng*16 + (lane & 15);
    brow[ng] = (wl>>1)*5 + (wl&1)*2;
  }
  #pragma unroll
  for (int mg = 0; mg < 2; ++mg) acol[mg] = wr*32 + mg*16 + (lane & 15);
  const int kb = (lane>>4)*16;

  for (int dt = 0; dt < 3; ++dt){
    #pragma unroll
    for (int ks = 0; ks < 4; ++ks){
      short8 afrH[2], afrL[2], bfr[2];
      #pragma unroll
      for (int mg = 0; mg < 2; ++mg){
        const char* base = (const char*)w2b +
            ((dt*64 + acol[mg])*256 + ks*32)*2 + kb;
        afrH[mg] = *(const short8*)base;
        afrL[mg] = *(const short8*)(base + 256);
      }
      #pragma unroll
      for (int ng = 0; ng < 2; ++ng){
        const int row = brow[ng] + dt;
        int off = row*256 + ks*64 + kb; off ^= ((row&7)<<4);
        bfr[ng] = *(const short8*)(Bs + off);
      }
      #pragma unroll
      for (int mg = 0; mg < 2; ++mg)
        #pragma unroll
        for (int ng = 0; ng < 2; ++ng){
          acc[mg][ng] = __builtin_amdgcn_mfma_f32_16x16x32_bf16(
              afrH[mg], bfr[ng], acc[mg][ng], 0, 0, 0);
          acc[mg][ng] = __builtin_amdgcn_mfma_f32_16x16x32_bf16(
              afrL[mg], bfr[ng], acc[mg][ng], 0, 0, 0);
        }
    }
  }
  #pragma unroll
  for (int mg = 0; mg < 2; ++mg)
    #pragma unroll
    for (int j = 0; j < 4; ++j){
      const int cout = wr*32 + mg*16 + (lane>>4)*4 + j;
      const float bv = b2[cout];
      #pragma unroll
      for (int ng = 0; ng < 2; ++ng){
        const int col = wc*32 + ng*16 + (lane & 15);
        float v = acc[mg][ng][j] + bv; v = v > 0.f ? v : 0.f;
        h2[(size_t)cout*NT2 + col2base + col] = f2b(v);
      }
    }
}

// ---------------------------------------------------------------------------
// K4+K5 FUSED: enc3 -> enc4 MFMA (validated r18). h4 [128][NTOT].
// ---------------------------------------------------------------------------
__global__ __launch_bounds__(256) void k_enc34(
    const bf16* __restrict__ h2, const bf16* __restrict__ w3e,
    const float* __restrict__ b3, const bf16* __restrict__ w4e,
    const float* __restrict__ b4, bf16* __restrict__ h4)
{
  __shared__ __align__(16) char B1[64*256];       // 16 KB
  __shared__ __align__(16) char B2[64*128];       //  8 KB
  const int tid = threadIdx.x, lane = tid & 63, wq = tid >> 6;
  const int n0 = blockIdx.x * 64;                 // 1024 blocks

  for (int it = tid; it < 64*64; it += 256){
    const int cin = it >> 6, nl = it & 63;
    const int n = n0 + nl, i = n >> 13, b = n & 8191;
    const unsigned int pair =
        *(const unsigned int*)(h2 + (size_t)cin*NT2 + i*16384 + 2*b);
    int off = nl*256 + cin*4; off ^= ((nl&7)<<4);
    *(unsigned int*)(B1 + off) = pair;
  }
  __syncthreads();

  const int kb = (lane>>4)*16;
  f32x4 acc1[4];
  #pragma unroll
  for (int ng = 0; ng < 4; ++ng) acc1[ng] = f32x4{0.f,0.f,0.f,0.f};
  const int ar1 = wq*16 + (lane & 15);
  #pragma unroll
  for (int ks = 0; ks < 8; ++ks){
    const short8 a = *(const short8*)((const char*)w3e + (ar1*256 + ks*32)*2 + kb);
    #pragma unroll
    for (int ng = 0; ng < 4; ++ng){
      const int row = ng*16 + (lane & 15);
      int off = row*256 + (ks&3)*64 + kb; off ^= ((row&7)<<4);
      const short8 bfr = *(const short8*)(B1 + off);
      acc1[ng] = __builtin_amdgcn_mfma_f32_16x16x32_bf16(a, bfr, acc1[ng], 0, 0, 0);
    }
  }
  #pragma unroll
  for (int j = 0; j < 4; ++j){
    const int r1 = wq*16 + (lane>>4)*4 + j;
    const float bv = b3[r1];
    #pragma unroll
    for (int ng = 0; ng < 4; ++ng){
      const int col = ng*16 + (lane & 15);
      float v = acc1[ng][j] + bv; v = v > 0.f ? v : 0.f;
      int off = col*128 + r1*2; off ^= ((col&7)<<4);
      *(short*)(B2 + off) = f2bs(v);
    }
  }
  __syncthreads();

  f32x4 acc2[2][4];
  #pragma unroll
  for (int mg = 0; mg < 2; ++mg)
    #pragma unroll
    for (int ng = 0; ng < 4; ++ng) acc2[mg][ng] = f32x4{0.f,0.f,0.f,0.f};
  #pragma unroll
  for (int ks = 0; ks < 4; ++ks){
    short8 bfr[4];
    #pragma unroll
    for (int ng = 0; ng < 4; ++ng){
      const int row = ng*16 + (lane & 15);
      int off = row*128 + (ks&1)*64 + kb; off ^= ((row&7)<<4);
      bfr[ng] = *(const short8*)(B2 + off);
    }
    #pragma unroll
    for (int mg = 0; mg < 2; ++mg){
      const int ar2 = wq*32 + mg*16 + (lane & 15);
      const short8 a = *(const short8*)((const char*)w4e + (ar2*128 + ks*32)*2 + kb);
      #pragma unroll
      for (int ng = 0; ng < 4; ++ng)
        acc2[mg][ng] = __builtin_amdgcn_mfma_f32_16x16x32_bf16(a, bfr[ng], acc2[mg][ng], 0, 0, 0);
    }
  }
  #pragma unroll
  for (int mg = 0; mg < 2; ++mg)
    #pragma unroll
    for (int j = 0; j < 4; ++j){
      const int cout = wq*32 + mg*16 + (lane>>4)*4 + j;
      const float bv = b4[cout];
      #pragma unroll
      for (int ng = 0; ng < 4; ++ng){
        const int n = n0 + ng*16 + (lane & 15);
        float v = acc2[mg][ng][j] + bv; v = v > 0.f ? v : 0.f;
        h4[(size_t)cout*NTOT + n] = f2b(v);
      }
    }
}

// K6: transpose h0/c0 [B,128] -> [128][B]
__global__ __launch_bounds__(256) void k_init(
    const float* __restrict__ h0, const float* __restrict__ c0,
    float* __restrict__ hT0, float* __restrict__ cT)
{
  const int idx = blockIdx.x*256 + threadIdx.x;   // 1M
  const int b = idx >> 7, c = idx & 127;
  hT0[c*BATCH + b] = h0[idx];
  cT [c*BATCH + b] = c0[idx];
}

// ---------------------------------------------------------------------------
// K-GX: xg[512][32768] = Wih @ x for 4 steps (one half).
// ---------------------------------------------------------------------------
__global__ __launch_bounds__(256) void k_gatex(
    const bf16* __restrict__ h4, const bf16* __restrict__ wlx,
    float* __restrict__ xg, int half)
{
  __shared__ __align__(16) char Bs[32*256];
  const int tid = threadIdx.x, lane = tid & 63, wq = tid >> 6;
  const int n0 = blockIdx.x * 32;
  const int gcol = half*32768 + n0;

  for (int it = tid; it < 128*32; it += 256){
    const int cp = it >> 5, nl = it & 31;
    const bf16 v = h4[(size_t)cp*NTOT + gcol + nl];
    int off = nl*256 + cp*2; off ^= ((nl&7)<<4);
    *(short*)(Bs + off) = *(const short*)&v;
  }
  __syncthreads();

  f32x4 acc[8][2];
  #pragma unroll
  for (int mg = 0; mg < 8; ++mg)
    #pragma unroll
    for (int ng = 0; ng < 2; ++ng) acc[mg][ng] = f32x4{0.f,0.f,0.f,0.f};

  int arow[8];
  #pragma unroll
  for (int mg = 0; mg < 8; ++mg) arow[mg] = wq*128 + mg*16 + (lane & 15);
  const int kb = (lane>>4)*16;

  #pragma unroll
  for (int ks = 0; ks < 4; ++ks){
    short8 bfr[2];
    #pragma unroll
    for (int ng = 0; ng < 2; ++ng){
      const int row = ng*16 + (lane & 15);
      int off = row*256 + ks*64 + kb; off ^= ((row&7)<<4);
      bfr[ng] = *(const short8*)(Bs + off);
    }
    #pragma unroll
    for (int pl = 0; pl < 2; ++pl)
      #pragma unroll
      for (int mg = 0; mg < 8; ++mg){
        const short8 a = *(const short8*)((const char*)wlx +
            ((size_t)(pl*512 + arow[mg])*128 + ks*32)*2 + kb);
        #pragma unroll
        for (int ng = 0; ng < 2; ++ng)
          acc[mg][ng] = __builtin_amdgcn_mfma_f32_16x16x32_bf16(
              a, bfr[ng], acc[mg][ng], 0, 0, 0);
      }
  }

  #pragma unroll
  for (int mg = 0; mg < 8; ++mg)
    #pragma unroll
    for (int j = 0; j < 4; ++j){
      const int row = wq*128 + mg*16 + (lane>>4)*4 + j;
      #pragma unroll
      for (int ng = 0; ng < 2; ++ng){
        const int col = n0 + ng*16 + (lane & 15);
        xg[(size_t)row*32768 + col] = acc[mg][ng][j];
      }
    }
}

// ---------------------------------------------------------------------------
// K7 v3: one recurrent LSTM step, Whh-only MFMA (K=384), 256 blocks x 32
// batch cols, with the wl3 A-tile COOPERATIVELY STAGED in LDS per k-step
// (two 256-row halves, stride 80B -> uniform b128 bank windows). Converts
// 96 scattered per-lane L2 A-loads into coalesced pipelined staging.
// ---------------------------------------------------------------------------
__global__ __launch_bounds__(256) void k_lstm_rec(
    const float* __restrict__ xg, const bf16* __restrict__ wl3,
    const float* __restrict__ bih, const float* __restrict__ bhh,
    const float* __restrict__ hprev, float* __restrict__ hout,
    float* __restrict__ cT, int s)
{
  __shared__ __align__(16) char Bs[32*768];       // 24 KB (validated h staging)
  __shared__ __align__(16) char AL[256*80];       // 20 KB A half-tile
  const int tid = threadIdx.x, lane = tid & 63, wq = tid >> 6;
  const int b0 = blockIdx.x * 32;

  for (int it = tid; it < 128*32; it += 256){
    const int cp = it >> 5, bl = it & 31;
    const float v = hprev[cp*BATCH + b0 + bl];
    const bf16 hi = f2b(v);
    const bf16 lo = f2b(v - b2f(hi));
    int off1 = bl*768 + cp*2;        off1 ^= ((bl&7)<<4);
    int off2 = bl*768 + (128+cp)*2;  off2 ^= ((bl&7)<<4);
    int off3 = bl*768 + (256+cp)*2;  off3 ^= ((bl&7)<<4);
    *(short*)(Bs + off1) = *(const short*)&hi;
    *(short*)(Bs + off2) = *(const short*)&lo;
    *(short*)(Bs + off3) = *(const short*)&hi;
  }
  __syncthreads();

  const int c0r = wq*32;
  f32x4 acc[4][2];
  #pragma unroll
  for (int g = 0; g < 4; ++g)
    #pragma unroll
    for (int h = 0; h < 2; ++h) acc[g][h] = f32x4{0.f,0.f,0.f,0.f};

  for (int ks = 0; ks < 12; ++ks){
    // B fragments for this ks (from validated Bs layout)
    short8 bfr[2];
    #pragma unroll
    for (int ng = 0; ng < 2; ++ng){
      const int row = ng*16 + (lane & 15);
      int off = row*768 + ks*64 + (lane>>4)*16; off ^= ((row&7)<<4);
      bfr[ng] = *(const short8*)(Bs + off);
    }
    #pragma unroll
    for (int half = 0; half < 2; ++half){
      __syncthreads();                            // WAR: prev readers done
      for (int it2 = tid; it2 < 1024; it2 += 256){
        const int row = it2 >> 2;                 // 0..255
        const int cb  = (it2 & 3)*16;
        *(f32x4*)(AL + row*80 + cb) =
            *(const f32x4*)((const char*)wl3 +
                (size_t)(half*256 + row)*768 + ks*64 + cb);
      }
      __syncthreads();                            // RAW: tile ready
      #pragma unroll
      for (int gg = 0; gg < 2; ++gg){
        const int g = half*2 + gg;
        #pragma unroll
        for (int h = 0; h < 2; ++h){
          const int rhalf = gg*128 + c0r + h*16 + (lane & 15);
          const short8 a = *(const short8*)(AL + rhalf*80 + (lane>>4)*16);
          #pragma unroll
          for (int ng = 0; ng < 2; ++ng){
            // note: acc layout [g][h] with ng folded via two accumulators
            acc[g][h] = __builtin_amdgcn_mfma_f32_16x16x32_bf16(
                a, bfr[ng], acc[g][h], 0, 0, 0);
            if (ng == 0) { /* placeholder to keep both ng accumulations */ }
          }
        }
      }
    }
  }
  // NOTE: the loop above folded ng into acc[g][h] incorrectly if left as-is;
  // we need separate accumulators per ng. Use acc2 layout below instead.
  // (acc[g][h] accumulated BOTH ng fragments — wrong. Recompute correctly:)
  // --- To keep correctness, the kernel actually uses acc4 below. ---
  (void)acc;
  // Correct accumulation pass (structured like validated r18, reading AL):
  f32x4 acc4[4][2][2];
  #pragma unroll
  for (int g = 0; g < 4; ++g)
    #pragma unroll
    for (int h = 0; h < 2; ++h)
      #pragma unroll
      for (int ng = 0; ng < 2; ++ng) acc4[g][h][ng] = f32x4{0.f,0.f,0.f,0.f};

  for (int ks = 0; ks < 12; ++ks){
    short8 bfr[2];
    #pragma unroll
    for (int ng = 0; ng < 2; ++ng){
      const int row = ng*16 + (lane & 15);
      int off = row*768 + ks*64 + (lane>>4)*16; off ^= ((row&7)<<4);
      bfr[ng] = *(const short8*)(Bs + off);
    }
    #pragma unroll
    for (int half = 0; half < 2; ++half){
      __syncthreads();
      for (int it2 = tid; it2 < 1024; it2 += 256){
        const int row = it2 >> 2;
        const int cb  = (it2 & 3)*16;
        *(f32x4*)(AL + row*80 + cb) =
            *(const f32x4*)((const char*)wl3 +
                (size_t)(half*256 + row)*768 + ks*64 + cb);
      }
      __syncthreads();
      #pragma unroll
      for (int gg = 0; gg < 2; ++gg){
        const int g = half*2 + gg;
        #pragma unroll
        for (int h = 0; h < 2; ++h){
          const int rhalf = gg*128 + c0r + h*16 + (lane & 15);
          const short8 a = *(const short8*)(AL + rhalf*80 + (lane>>4)*16);
          #pragma unroll
          for (int ng = 0; ng < 2; ++ng)
            acc4[g][h][ng] = __builtin_amdgcn_mfma_f32_16x16x32_bf16(
                a, bfr[ng], acc4[g][h][ng], 0, 0, 0);
        }
      }
    }
  }

  const size_t xcolbase = (size_t)(s & 3)*8192 + b0;
  #pragma unroll
  for (int h = 0; h < 2; ++h)
    #pragma unroll
    for (int ng = 0; ng < 2; ++ng)
      #pragma unroll
      for (int j = 0; j < 4; ++j){
        const int c = c0r + h*16 + (lane>>4)*4 + j;
        const int b = b0 + ng*16 + (lane & 15);
        const size_t xc = xcolbase + ng*16 + (lane & 15);
        const float ig = acc4[0][h][ng][j] + xg[(size_t)(0*128+c)*32768 + xc] + bih[c]       + bhh[c];
        const float fg = acc4[1][h][ng][j] + xg[(size_t)(1*128+c)*32768 + xc] + bih[128 + c] + bhh[128 + c];
        const float gg = acc4[2][h][ng][j] + xg[(size_t)(2*128+c)*32768 + xc] + bih[256 + c] + bhh[256 + c];
        const float og = acc4[3][h][ng][j] + xg[(size_t)(3*128+c)*32768 + xc] + bih[384 + c] + bhh[384 + c];
        const float cold = cT[c*BATCH + b];
        const float cn = sigf(fg)*cold + sigf(ig)*tanhfast(gg);
        const float hn = sigf(og)*tanhfast(cn);
        cT  [c*BATCH + b] = cn;
        hout[c*BATCH + b] = hn;
      }
}

// K8a: P[s][b] = sigmoid(ow . hseq[s][:,b] + ob)
__global__ __launch_bounds__(256) void k_headp(
    const float* __restrict__ hseq, const float* __restrict__ ow,
    const float* __restrict__ ob, float* __restrict__ P)
{
  const int idx = blockIdx.x*256 + threadIdx.x;   // 65536
  const int s = idx >> 13, b = idx & (BATCH-1);
  const float* hp = hseq + (size_t)s*HID*BATCH;
  float acc = ob[0];
  for (int c = 0; c < 128; ++c) acc += ow[c]*hp[c*BATCH + b];
  P[s*BATCH + b] = sigf(acc);
}
// K8b: final = 1 - prod(1 - P[s])
__global__ __launch_bounds__(256) void k_head2(
    const float* __restrict__ P, float* __restrict__ outp)
{
  const int b = blockIdx.x*256 + threadIdx.x;     // 8192
  float prod = 1.f;
  #pragma unroll
  for (int s = 0; s < 8; ++s) prod *= (1.f - P[s*BATCH + b]);
  outp[b] = 1.f - prod;
}

// K9: transpose h_fin, c_fin to [B,128] in d_out
__global__ __launch_bounds__(256) void k_outT(
    const float* __restrict__ h7, const float* __restrict__ cT,
    float* __restrict__ out)
{
  const int idx = blockIdx.x*256 + threadIdx.x;   // 1M
  const int b = idx >> 7, c = idx & 127;
  out[8192 + idx]           = h7[c*BATCH + b];
  out[8192 + 1048576 + idx] = cT[c*BATCH + b];
}

// ---------------------------------------------------------------------------
extern "C" void kernel_launch(void* const* d_in, const int* in_sizes, int n_in,
                              void* d_out, int out_size, void* d_ws, size_t ws_size,
                              hipStream_t stream)
{
  (void)in_sizes; (void)n_in; (void)out_size; (void)ws_size;
  const float* audio = (const float*)d_in[0];
  const float* h0    = (const float*)d_in[1];
  const float* c0    = (const float*)d_in[2];
  const float* stftw = (const float*)d_in[3];
  const float* w1 = (const float*)d_in[4];  const float* b1 = (const float*)d_in[5];
  const float* w2 = (const float*)d_in[6];  const float* b2 = (const float*)d_in[7];
  const float* w3 = (const float*)d_in[8];  const float* b3 = (const float*)d_in[9];
  const float* w4 = (const float*)d_in[10]; const float* b4 = (const float*)d_in[11];
  const float* wih = (const float*)d_in[12]; const float* whh = (const float*)d_in[13];
  const float* bih = (const float*)d_in[14]; const float* bhh = (const float*)d_in[15];
  const float* ow  = (const float*)d_in[16]; const float* ob  = (const float*)d_in[17];
  float* out = (float*)d_out;

  // Workspace schedule (validated r18/r20):
  char* ws = (char*)d_ws;
  bf16*  mag  = (bf16*) (ws + 0);
  bf16*  w2b  = (bf16*) (ws + 0);
  bf16*  w3e  = (bf16*) (ws + 1048576);
  bf16*  w4e  = (bf16*) (ws + 1081344);
  bf16*  h4   = (bf16*) (ws + 8388608);
  float* xg   = (float*)(ws + 25165824);
  float* hseq = (float*)(ws + 92274688);
  float* hT0  = (float*)(ws + 125829120);
  float* cT   = (float*)(ws + 130023424);
  bf16*  h1   = (bf16*) (ws + 67633152);
  bf16*  Wbf  = (bf16*) (ws + 67633152);
  bf16*  h2   = (bf16*) (ws + 134742016);
  bf16*  w1b  = (bf16*) (ws + 134742016);
  bf16*  wl3  = (bf16*) (ws + 134742016);
  bf16*  wlx  = (bf16*) (ws + 135135232);
  float* Pbuf = (float*)(ws + 135397376);

  k_wcvt  <<<258, 256, 0, stream>>>(stftw, Wbf);
  k_w1cvt <<<480, 256, 0, stream>>>(w1, w1b);
  k_stft3<<<2048, 256, 0, stream>>>(audio, Wbf, mag);
  k_enc1_gemm<<<2048, 256, 0, stream>>>(mag, w1b, b1, h1);
  k_w2cvt <<<192, 256, 0, stream>>>(w2, w2b);           // after enc1: mag dead
  k_w34cvt<<<128, 256, 0, stream>>>(w3, w4, w3e, w4e);  // after enc1: mag dead
  k_enc2_gemm<<<2048, 256, 0, stream>>>(h1, w2b, b2, h2);
  k_init <<<4096, 256, 0, stream>>>(h0, c0, hT0, cT);   // after enc2: h1 dead
  k_enc34<<<1024, 256, 0, stream>>>(h2, w3e, b3, w4e, b4, h4);
  k_wlcvt3<<<768, 256, 0, stream>>>(whh, wl3);          // after enc34: h2 dead
  k_wlxcvt<<<512, 256, 0, stream>>>(wih, wlx);
  for (int half = 0; half < 2; ++half){
    k_gatex<<<1024, 256, 0, stream>>>(h4, wlx, xg, half);
    for (int q = 0; q < 4; ++q){
      const int s = half*4 + q;
      const float* hprev = (s == 0) ? hT0 : (hseq + (size_t)(s-1)*HID*BATCH);
      k_lstm_rec<<<256, 256, 0, stream>>>(xg, wl3, bih, bhh, hprev,
                                          hseq + (size_t)s*HID*BATCH, cT, s);
    }
  }
  k_headp<<<256, 256, 0, stream>>>(hseq, ow, ob, Pbuf);
  k_head2<<<32, 256, 0, stream>>>(Pbuf, out);
  k_outT<<<4096, 256, 0, stream>>>(hseq + (size_t)7*HID*BATCH, cT, out);
}

// Round 22
// 715.810 us; speedup vs baseline: 1.1882x; 1.1882x over previous
//
#include <hip/hip_runtime.h>
#include <hip/hip_bf16.h>
#include <math.h>

typedef __hip_bfloat16 bf16;
typedef __attribute__((ext_vector_type(4))) float f32x4;
typedef __attribute__((ext_vector_type(8))) short short8;
typedef __attribute__((ext_vector_type(4))) short short4v;

#define BATCH   8192
#define NTOT    65536      // 8 chunks * BATCH
#define NT2     131072     // 2 frames * NTOT (enc2 out)
#define NW      262144     // 8 chunks * 4 frames * BATCH
#define HID     128

__device__ __forceinline__ float b2f(bf16 v){ return __bfloat162float(v); }
__device__ __forceinline__ bf16  f2b(float v){ return __float2bfloat16(v); }
__device__ __forceinline__ short f2bs(float v){
  bf16 b = __float2bfloat16(v);
  return *reinterpret_cast<short*>(&b);
}
__device__ __forceinline__ float sigf(float x){ return 1.0f/(1.0f+__expf(-x)); }
__device__ __forceinline__ float tanhfast(float x){
  return 1.0f - 2.0f/(__expf(2.0f*x)+1.0f);
}

// ---------------------------------------------------------------------------
// Weight conversion (hi/lo split: W = hi + lo, lo = bf16(W - hi))
// ---------------------------------------------------------------------------
__global__ __launch_bounds__(256) void k_wcvt(        // stft W -> bf16 [258][256]
    const float* __restrict__ W, bf16* __restrict__ Wb)
{
  const int idx = blockIdx.x*256 + threadIdx.x;
  if (idx < 258*256) Wb[idx] = f2b(W[idx]);
}
__global__ __launch_bounds__(256) void k_w1cvt(       // w1 -> [3][128][320] hi|lo
    const float* __restrict__ w1, bf16* __restrict__ w1b)
{
  const int idx = blockIdx.x*256 + threadIdx.x;       // 3*128*320 = 122880
  if (idx >= 122880) return;
  const int dt = idx / 40960, rem = idx % 40960;
  const int cout = rem / 320, k = rem % 320;
  const int kk = (k >= 160) ? (k - 160) : k;
  const float v = (kk < 129) ? w1[(cout*129 + kk)*3 + dt] : 0.f;
  const bf16 hi = f2b(v);
  w1b[idx] = (k >= 160) ? f2b(v - b2f(hi)) : hi;
}
__global__ __launch_bounds__(256) void k_w2cvt(       // w2 -> [3][64][256] hi|lo
    const float* __restrict__ w2, bf16* __restrict__ w2b)
{
  const int idx = blockIdx.x*256 + threadIdx.x;       // 3*64*256 = 49152
  if (idx >= 49152) return;
  const int dt = idx >> 14, cout = (idx >> 8) & 63, k = idx & 255;
  const int kk = k & 127;
  const float v = w2[(cout*128 + kk)*3 + dt];
  const bf16 hi = f2b(v);
  w2b[idx] = (k >= 128) ? f2b(v - b2f(hi)) : hi;
}
// enc3 taps 1,2 -> w3e[64][256] hi|lo; enc4 center -> w4e[128][128] hi|lo
__global__ __launch_bounds__(256) void k_w34cvt(
    const float* __restrict__ w3, const float* __restrict__ w4,
    bf16* __restrict__ w3e, bf16* __restrict__ w4e)
{
  const int idx = blockIdx.x*256 + threadIdx.x;       // 32768
  if (idx >= 32768) return;
  if (idx < 16384){
    const int row = idx >> 8, k = idx & 255;
    const int kk = k & 127, cin = kk >> 1, t = kk & 1;
    const float v = w3[(row*64 + cin)*3 + 1 + t];
    const bf16 hi = f2b(v);
    w3e[idx] = (k >= 128) ? f2b(v - b2f(hi)) : hi;
  } else {
    const int i2 = idx - 16384;
    const int row = i2 >> 7, k = i2 & 127;
    const int cin = k & 63;
    const float v = w4[(row*64 + cin)*3 + 1];
    const bf16 hi = f2b(v);
    w4e[i2] = (k >= 64) ? f2b(v - b2f(hi)) : hi;
  }
}
// Whh-only recurrent weights -> [512][384]: [Whh_hi | Whh_hi | Whh_lo]
__global__ __launch_bounds__(256) void k_wlcvt3(
    const float* __restrict__ whh, bf16* __restrict__ wl3)
{
  const int idx = blockIdx.x*256 + threadIdx.x;       // 512*384 = 196608
  if (idx >= 196608) return;
  const int r = idx / 384, k = idx % 384;
  const int part = k >> 7, kk = k & 127;
  const float f = whh[r*128 + kk];
  const bf16 hi = f2b(f);
  wl3[idx] = (part < 2) ? hi : f2b(f - b2f(hi));
}
// Wih hi/lo planes: wlx[2][512][128]
__global__ __launch_bounds__(256) void k_wlxcvt(
    const float* __restrict__ wih, bf16* __restrict__ wlx)
{
  const int idx = blockIdx.x*256 + threadIdx.x;       // 131072
  if (idx >= 131072) return;
  const int pl = idx >> 16, rem = idx & 65535;
  const float f = wih[rem];
  const bf16 hi = f2b(f);
  wlx[idx] = (pl == 0) ? hi : f2b(f - b2f(hi));
}

// ---------------------------------------------------------------------------
// K1 v5 (validated r19): STFT MFMA GEMM, per-pass A-tile staged in LDS.
// mag [129][NW].
// ---------------------------------------------------------------------------
__global__ __launch_bounds__(256) void k_stft3(
    const float* __restrict__ audio, const bf16* __restrict__ Wb,
    bf16* __restrict__ mag)
{
  __shared__ __align__(16) char ALDS[96*512];      // 48 KB
  __shared__ __align__(16) bf16 refl[4*8*64];      // 4 KB
  const int tid = threadIdx.x, lane = tid & 63, wq = tid >> 6;
  const int r0 = blockIdx.x * 4;                   // 2048 blocks
  const float* arow = audio + (size_t)(r0 + wq) * 4160;

  #pragma unroll
  for (int q = 0; q < 8; ++q){
    const int e = q*64 + lane;
    const int i = e >> 6, k = e & 63;
    refl[(wq*8 + i)*64 + k] = f2b(arow[512*i + 64 - k]);
  }

  const int kgo8 = (lane>>4)*8;
  short8 Bfrag[2][8];
  #pragma unroll
  for (int ng = 0; ng < 2; ++ng){
    const int wl = ng*16 + (lane & 15);
    const int i = wl >> 2, t = wl & 3;
    #pragma unroll
    for (int ks = 0; ks < 8; ++ks){
      const int kb = ks*32 + kgo8;
      if (t == 0 && kb < 64){
        Bfrag[ng][ks] = *(const short8*)(refl + (wq*8 + i)*64 + kb);
      } else {
        const float* src = arow + 512*i + 128*t - 64 + kb;
        const float4 v0 = *(const float4*)(src);
        const float4 v1 = *(const float4*)(src + 4);
        short8 s;
        s[0]=f2bs(v0.x); s[1]=f2bs(v0.y); s[2]=f2bs(v0.z); s[3]=f2bs(v0.w);
        s[4]=f2bs(v1.x); s[5]=f2bs(v1.y); s[6]=f2bs(v1.z); s[7]=f2bs(v1.w);
        Bfrag[ng][ks] = s;
      }
    }
  }

  const int kab = (lane>>4)*16;
  for (int pass = 0; pass < 3; ++pass){
    __syncthreads();
    for (int idx = tid; idx < 96*32; idx += 256){
      const int ar = idx >> 5;
      const int cb = (idx & 31) * 16;
      const int b3 = ar >> 5, reim = (ar >> 4) & 1, bl = ar & 15;
      int bin = pass*48 + b3*16 + bl;
      if (bin > 128) bin = 128;
      const int grow = bin + reim*129;
      int off = ar*512 + cb; off ^= ((ar&7)<<4);
      *(f32x4*)(ALDS + off) = *(const f32x4*)((const char*)Wb + grow*512 + cb);
    }
    __syncthreads();

    f32x4 accRe[3][2], accIm[3][2];
    #pragma unroll
    for (int b3 = 0; b3 < 3; ++b3)
      #pragma unroll
      for (int ng = 0; ng < 2; ++ng){
        accRe[b3][ng] = f32x4{0.f,0.f,0.f,0.f};
        accIm[b3][ng] = f32x4{0.f,0.f,0.f,0.f};
      }
    #pragma unroll
    for (int ks = 0; ks < 8; ++ks){
      #pragma unroll
      for (int b3 = 0; b3 < 3; ++b3){
        const int arRe = b3*32 + (lane & 15);
        const int arIm = arRe + 16;
        int offRe = arRe*512 + ks*64 + kab; offRe ^= ((arRe&7)<<4);
        int offIm = arIm*512 + ks*64 + kab; offIm ^= ((arIm&7)<<4);
        const short8 aRe = *(const short8*)(ALDS + offRe);
        const short8 aIm = *(const short8*)(ALDS + offIm);
        #pragma unroll
        for (int ng = 0; ng < 2; ++ng){
          accRe[b3][ng] = __builtin_amdgcn_mfma_f32_16x16x32_bf16(
              aRe, Bfrag[ng][ks], accRe[b3][ng], 0, 0, 0);
          accIm[b3][ng] = __builtin_amdgcn_mfma_f32_16x16x32_bf16(
              aIm, Bfrag[ng][ks], accIm[b3][ng], 0, 0, 0);
        }
      }
    }
    #pragma unroll
    for (int b3 = 0; b3 < 3; ++b3)
      #pragma unroll
      for (int j = 0; j < 4; ++j){
        const int bin = (pass*3 + b3)*16 + (lane>>4)*4 + j;
        if (bin <= 128){
          #pragma unroll
          for (int ng = 0; ng < 2; ++ng){
            const int wl = ng*16 + (lane & 15);
            const int i = wl >> 2, t = wl & 3;
            const float re = accRe[b3][ng][j], im = accIm[b3][ng][j];
            mag[(size_t)bin*NW + (size_t)i*32768 + (r0+wq)*4 + t] =
                f2b(sqrtf(re*re + im*im));
          }
        }
      }
  }
}

// ---------------------------------------------------------------------------
// K2: enc1 MFMA GEMM hi/lo (validated r13). h1 [128][NW].
// ---------------------------------------------------------------------------
#define E1_LDS (192*320)
__global__ __launch_bounds__(256) void k_enc1_gemm(
    const bf16* __restrict__ mag, const bf16* __restrict__ w1b,
    const float* __restrict__ b1, bf16* __restrict__ h1)
{
  __shared__ __align__(16) char Bs[E1_LDS];
  const int tid = threadIdx.x, lane = tid & 63, wq = tid >> 6;
  const int n0 = blockIdx.x * 32;
  const int i  = n0 >> 13, b0 = n0 & 8191;
  const size_t colbase = (size_t)i*32768 + (size_t)b0*4;

  for (int off = tid*16; off < E1_LDS; off += 256*16)
    *(f32x4*)(Bs + off) = f32x4{0.f,0.f,0.f,0.f};
  __syncthreads();
  for (int it = tid; it < 129*64; it += 256){
    const int cin = it >> 6, seg = it & 63;
    const unsigned int pair =
        *(const unsigned int*)(mag + (size_t)cin*NW + colbase + seg*2);
    #pragma unroll
    for (int q = 0; q < 2; ++q){
      const int w = seg*2 + q;
      const int row = (w>>2)*6 + (w&3) + 1;
      int off = row*320 + cin*2; off ^= ((row&7)<<4);
      *(short*)(Bs + off) = (short)((q==0) ? (pair & 0xffff) : (pair >> 16));
    }
  }
  __syncthreads();

  const int wr = wq >> 1, wc = wq & 1;
  f32x4 acc[4][4];
  #pragma unroll
  for (int mg = 0; mg < 4; ++mg)
    #pragma unroll
    for (int ng = 0; ng < 4; ++ng) acc[mg][ng] = f32x4{0.f,0.f,0.f,0.f};

  int brow[4], acol[4];
  #pragma unroll
  for (int ng = 0; ng < 4; ++ng){
    const int w = wc*64 + ng*16 + (lane & 15);
    brow[ng] = (w>>2)*6 + (w&3);
  }
  #pragma unroll
  for (int mg = 0; mg < 4; ++mg) acol[mg] = wr*64 + mg*16 + (lane & 15);
  const int kb = (lane>>4)*16;

  for (int dt = 0; dt < 3; ++dt){
    #pragma unroll
    for (int ks = 0; ks < 5; ++ks){
      short8 afrH[4], afrL[4], bfr[4];
      #pragma unroll
      for (int mg = 0; mg < 4; ++mg){
        const char* base = (const char*)w1b +
            ((dt*128 + acol[mg])*320 + ks*32)*2 + kb;
        afrH[mg] = *(const short8*)base;
        afrL[mg] = *(const short8*)(base + 320);
      }
      #pragma unroll
      for (int ng = 0; ng < 4; ++ng){
        const int row = brow[ng] + dt;
        int off = row*320 + ks*64 + kb; off ^= ((row&7)<<4);
        bfr[ng] = *(const short8*)(Bs + off);
      }
      #pragma unroll
      for (int mg = 0; mg < 4; ++mg)
        #pragma unroll
        for (int ng = 0; ng < 4; ++ng){
          acc[mg][ng] = __builtin_amdgcn_mfma_f32_16x16x32_bf16(
              afrH[mg], bfr[ng], acc[mg][ng], 0, 0, 0);
          acc[mg][ng] = __builtin_amdgcn_mfma_f32_16x16x32_bf16(
              afrL[mg], bfr[ng], acc[mg][ng], 0, 0, 0);
        }
    }
  }
  #pragma unroll
  for (int mg = 0; mg < 4; ++mg)
    #pragma unroll
    for (int j = 0; j < 4; ++j){
      const int cout = wr*64 + mg*16 + (lane>>4)*4 + j;
      const float bv = b1[cout];
      #pragma unroll
      for (int ng = 0; ng < 4; ++ng){
        const int col = wc*64 + ng*16 + (lane & 15);
        float v = acc[mg][ng][j] + bv; v = v > 0.f ? v : 0.f;
        h1[(size_t)cout*NW + colbase + col] = f2b(v);
      }
    }
}

// ---------------------------------------------------------------------------
// K3: enc2 MFMA GEMM hi/lo (validated). h2 [64][NT2].
// ---------------------------------------------------------------------------
#define E2_LDS (160*256)
__global__ __launch_bounds__(256) void k_enc2_gemm(
    const bf16* __restrict__ h1, const bf16* __restrict__ w2b,
    const float* __restrict__ b2, bf16* __restrict__ h2)
{
  __shared__ __align__(16) char Bs[E2_LDS];
  const int tid = threadIdx.x, lane = tid & 63, wq = tid >> 6;
  const int n0 = blockIdx.x * 32;
  const int i  = n0 >> 13, b0 = n0 & 8191;
  const size_t colbase = (size_t)i*32768 + (size_t)b0*4;
  const size_t col2base = (size_t)i*16384 + (size_t)b0*2;

  for (int off = tid*16; off < E2_LDS; off += 256*16)
    *(f32x4*)(Bs + off) = f32x4{0.f,0.f,0.f,0.f};
  __syncthreads();
  for (int it = tid; it < 128*64; it += 256){
    const int cin = it >> 6, seg = it & 63;
    const unsigned int pair =
        *(const unsigned int*)(h1 + (size_t)cin*NW + colbase + seg*2);
    #pragma unroll
    for (int q = 0; q < 2; ++q){
      const int w = seg*2 + q;
      const int row = (w>>2)*5 + (w&3) + 1;
      int off = row*256 + cin*2; off ^= ((row&7)<<4);
      *(short*)(Bs + off) = (short)((q==0) ? (pair & 0xffff) : (pair >> 16));
    }
  }
  __syncthreads();

  const int wr = wq >> 1, wc = wq & 1;
  f32x4 acc[2][2];
  #pragma unroll
  for (int mg = 0; mg < 2; ++mg)
    #pragma unroll
    for (int ng = 0; ng < 2; ++ng) acc[mg][ng] = f32x4{0.f,0.f,0.f,0.f};

  int brow[2], acol[2];
  #pragma unroll
  for (int ng = 0; ng < 2; ++ng){
    const int wl = wc*32 + ng*16 + (lane & 15);
    brow[ng] = (wl>>1)*5 + (wl&1)*2;
  }
  #pragma unroll
  for (int mg = 0; mg < 2; ++mg) acol[mg] = wr*32 + mg*16 + (lane & 15);
  const int kb = (lane>>4)*16;

  for (int dt = 0; dt < 3; ++dt){
    #pragma unroll
    for (int ks = 0; ks < 4; ++ks){
      short8 afrH[2], afrL[2], bfr[2];
      #pragma unroll
      for (int mg = 0; mg < 2; ++mg){
        const char* base = (const char*)w2b +
            ((dt*64 + acol[mg])*256 + ks*32)*2 + kb;
        afrH[mg] = *(const short8*)base;
        afrL[mg] = *(const short8*)(base + 256);
      }
      #pragma unroll
      for (int ng = 0; ng < 2; ++ng){
        const int row = brow[ng] + dt;
        int off = row*256 + ks*64 + kb; off ^= ((row&7)<<4);
        bfr[ng] = *(const short8*)(Bs + off);
      }
      #pragma unroll
      for (int mg = 0; mg < 2; ++mg)
        #pragma unroll
        for (int ng = 0; ng < 2; ++ng){
          acc[mg][ng] = __builtin_amdgcn_mfma_f32_16x16x32_bf16(
              afrH[mg], bfr[ng], acc[mg][ng], 0, 0, 0);
          acc[mg][ng] = __builtin_amdgcn_mfma_f32_16x16x32_bf16(
              afrL[mg], bfr[ng], acc[mg][ng], 0, 0, 0);
        }
    }
  }
  #pragma unroll
  for (int mg = 0; mg < 2; ++mg)
    #pragma unroll
    for (int j = 0; j < 4; ++j){
      const int cout = wr*32 + mg*16 + (lane>>4)*4 + j;
      const float bv = b2[cout];
      #pragma unroll
      for (int ng = 0; ng < 2; ++ng){
        const int col = wc*32 + ng*16 + (lane & 15);
        float v = acc[mg][ng][j] + bv; v = v > 0.f ? v : 0.f;
        h2[(size_t)cout*NT2 + col2base + col] = f2b(v);
      }
    }
}

// ---------------------------------------------------------------------------
// K4+K5 FUSED: enc3 -> enc4 MFMA (validated r18). h4 [128][NTOT].
// ---------------------------------------------------------------------------
__global__ __launch_bounds__(256) void k_enc34(
    const bf16* __restrict__ h2, const bf16* __restrict__ w3e,
    const float* __restrict__ b3, const bf16* __restrict__ w4e,
    const float* __restrict__ b4, bf16* __restrict__ h4)
{
  __shared__ __align__(16) char B1[64*256];       // 16 KB
  __shared__ __align__(16) char B2[64*128];       //  8 KB
  const int tid = threadIdx.x, lane = tid & 63, wq = tid >> 6;
  const int n0 = blockIdx.x * 64;                 // 1024 blocks

  for (int it = tid; it < 64*64; it += 256){
    const int cin = it >> 6, nl = it & 63;
    const int n = n0 + nl, i = n >> 13, b = n & 8191;
    const unsigned int pair =
        *(const unsigned int*)(h2 + (size_t)cin*NT2 + i*16384 + 2*b);
    int off = nl*256 + cin*4; off ^= ((nl&7)<<4);
    *(unsigned int*)(B1 + off) = pair;
  }
  __syncthreads();

  const int kb = (lane>>4)*16;
  f32x4 acc1[4];
  #pragma unroll
  for (int ng = 0; ng < 4; ++ng) acc1[ng] = f32x4{0.f,0.f,0.f,0.f};
  const int ar1 = wq*16 + (lane & 15);
  #pragma unroll
  for (int ks = 0; ks < 8; ++ks){
    const short8 a = *(const short8*)((const char*)w3e + (ar1*256 + ks*32)*2 + kb);
    #pragma unroll
    for (int ng = 0; ng < 4; ++ng){
      const int row = ng*16 + (lane & 15);
      int off = row*256 + (ks&3)*64 + kb; off ^= ((row&7)<<4);
      const short8 bfr = *(const short8*)(B1 + off);
      acc1[ng] = __builtin_amdgcn_mfma_f32_16x16x32_bf16(a, bfr, acc1[ng], 0, 0, 0);
    }
  }
  #pragma unroll
  for (int j = 0; j < 4; ++j){
    const int r1 = wq*16 + (lane>>4)*4 + j;
    const float bv = b3[r1];
    #pragma unroll
    for (int ng = 0; ng < 4; ++ng){
      const int col = ng*16 + (lane & 15);
      float v = acc1[ng][j] + bv; v = v > 0.f ? v : 0.f;
      int off = col*128 + r1*2; off ^= ((col&7)<<4);
      *(short*)(B2 + off) = f2bs(v);
    }
  }
  __syncthreads();

  f32x4 acc2[2][4];
  #pragma unroll
  for (int mg = 0; mg < 2; ++mg)
    #pragma unroll
    for (int ng = 0; ng < 4; ++ng) acc2[mg][ng] = f32x4{0.f,0.f,0.f,0.f};
  #pragma unroll
  for (int ks = 0; ks < 4; ++ks){
    short8 bfr[4];
    #pragma unroll
    for (int ng = 0; ng < 4; ++ng){
      const int row = ng*16 + (lane & 15);
      int off = row*128 + (ks&1)*64 + kb; off ^= ((row&7)<<4);
      bfr[ng] = *(const short8*)(B2 + off);
    }
    #pragma unroll
    for (int mg = 0; mg < 2; ++mg){
      const int ar2 = wq*32 + mg*16 + (lane & 15);
      const short8 a = *(const short8*)((const char*)w4e + (ar2*128 + ks*32)*2 + kb);
      #pragma unroll
      for (int ng = 0; ng < 4; ++ng)
        acc2[mg][ng] = __builtin_amdgcn_mfma_f32_16x16x32_bf16(a, bfr[ng], acc2[mg][ng], 0, 0, 0);
    }
  }
  #pragma unroll
  for (int mg = 0; mg < 2; ++mg)
    #pragma unroll
    for (int j = 0; j < 4; ++j){
      const int cout = wq*32 + mg*16 + (lane>>4)*4 + j;
      const float bv = b4[cout];
      #pragma unroll
      for (int ng = 0; ng < 4; ++ng){
        const int n = n0 + ng*16 + (lane & 15);
        float v = acc2[mg][ng][j] + bv; v = v > 0.f ? v : 0.f;
        h4[(size_t)cout*NTOT + n] = f2b(v);
      }
    }
}

// K6: transpose h0/c0 [B,128] -> [128][B]
__global__ __launch_bounds__(256) void k_init(
    const float* __restrict__ h0, const float* __restrict__ c0,
    float* __restrict__ hT0, float* __restrict__ cT)
{
  const int idx = blockIdx.x*256 + threadIdx.x;   // 1M
  const int b = idx >> 7, c = idx & 127;
  hT0[c*BATCH + b] = h0[idx];
  cT [c*BATCH + b] = c0[idx];
}

// ---------------------------------------------------------------------------
// K-GX: xg[512][32768] = Wih @ x for 4 steps (one half).
// ---------------------------------------------------------------------------
__global__ __launch_bounds__(256) void k_gatex(
    const bf16* __restrict__ h4, const bf16* __restrict__ wlx,
    float* __restrict__ xg, int half)
{
  __shared__ __align__(16) char Bs[32*256];
  const int tid = threadIdx.x, lane = tid & 63, wq = tid >> 6;
  const int n0 = blockIdx.x * 32;
  const int gcol = half*32768 + n0;

  for (int it = tid; it < 128*32; it += 256){
    const int cp = it >> 5, nl = it & 31;
    const bf16 v = h4[(size_t)cp*NTOT + gcol + nl];
    int off = nl*256 + cp*2; off ^= ((nl&7)<<4);
    *(short*)(Bs + off) = *(const short*)&v;
  }
  __syncthreads();

  f32x4 acc[8][2];
  #pragma unroll
  for (int mg = 0; mg < 8; ++mg)
    #pragma unroll
    for (int ng = 0; ng < 2; ++ng) acc[mg][ng] = f32x4{0.f,0.f,0.f,0.f};

  int arow[8];
  #pragma unroll
  for (int mg = 0; mg < 8; ++mg) arow[mg] = wq*128 + mg*16 + (lane & 15);
  const int kb = (lane>>4)*16;

  #pragma unroll
  for (int ks = 0; ks < 4; ++ks){
    short8 bfr[2];
    #pragma unroll
    for (int ng = 0; ng < 2; ++ng){
      const int row = ng*16 + (lane & 15);
      int off = row*256 + ks*64 + kb; off ^= ((row&7)<<4);
      bfr[ng] = *(const short8*)(Bs + off);
    }
    #pragma unroll
    for (int pl = 0; pl < 2; ++pl)
      #pragma unroll
      for (int mg = 0; mg < 8; ++mg){
        const short8 a = *(const short8*)((const char*)wlx +
            ((size_t)(pl*512 + arow[mg])*128 + ks*32)*2 + kb);
        #pragma unroll
        for (int ng = 0; ng < 2; ++ng)
          acc[mg][ng] = __builtin_amdgcn_mfma_f32_16x16x32_bf16(
              a, bfr[ng], acc[mg][ng], 0, 0, 0);
      }
  }

  #pragma unroll
  for (int mg = 0; mg < 8; ++mg)
    #pragma unroll
    for (int j = 0; j < 4; ++j){
      const int row = wq*128 + mg*16 + (lane>>4)*4 + j;
      #pragma unroll
      for (int ng = 0; ng < 2; ++ng){
        const int col = n0 + ng*16 + (lane & 15);
        xg[(size_t)row*32768 + col] = acc[mg][ng][j];
      }
    }
}

// ---------------------------------------------------------------------------
// K7 (validated r18/r20): one recurrent LSTM step, Whh-only MFMA (K=384),
// 32 batch cols per block, 256 blocks.
// ---------------------------------------------------------------------------
__global__ __launch_bounds__(256) void k_lstm_rec(
    const float* __restrict__ xg, const bf16* __restrict__ wl3,
    const float* __restrict__ bih, const float* __restrict__ bhh,
    const float* __restrict__ hprev, float* __restrict__ hout,
    float* __restrict__ cT, int s)
{
  __shared__ __align__(16) char Bs[32*768];
  const int tid = threadIdx.x, lane = tid & 63, wq = tid >> 6;
  const int b0 = blockIdx.x * 32;

  for (int it = tid; it < 128*32; it += 256){
    const int cp = it >> 5, bl = it & 31;
    const float v = hprev[cp*BATCH + b0 + bl];
    const bf16 hi = f2b(v);
    const bf16 lo = f2b(v - b2f(hi));
    int off1 = bl*768 + cp*2;        off1 ^= ((bl&7)<<4);
    int off2 = bl*768 + (128+cp)*2;  off2 ^= ((bl&7)<<4);
    int off3 = bl*768 + (256+cp)*2;  off3 ^= ((bl&7)<<4);
    *(short*)(Bs + off1) = *(const short*)&hi;
    *(short*)(Bs + off2) = *(const short*)&lo;
    *(short*)(Bs + off3) = *(const short*)&hi;
  }
  __syncthreads();

  const int c0r = wq*32;
  f32x4 acc[4][2][2];
  #pragma unroll
  for (int g = 0; g < 4; ++g)
    #pragma unroll
    for (int h = 0; h < 2; ++h)
      #pragma unroll
      for (int ng = 0; ng < 2; ++ng) acc[g][h][ng] = f32x4{0.f,0.f,0.f,0.f};

  int arow[4][2];
  #pragma unroll
  for (int g = 0; g < 4; ++g)
    #pragma unroll
    for (int h = 0; h < 2; ++h)
      arow[g][h] = (g*128 + c0r + h*16 + (lane&15))*768 + (lane>>4)*16;

  #pragma unroll
  for (int ks = 0; ks < 12; ++ks){
    short8 bfr[2];
    #pragma unroll
    for (int ng = 0; ng < 2; ++ng){
      const int row = ng*16 + (lane & 15);
      int off = row*768 + ks*64 + (lane>>4)*16; off ^= ((row&7)<<4);
      bfr[ng] = *(const short8*)(Bs + off);
    }
    #pragma unroll
    for (int g = 0; g < 4; ++g)
      #pragma unroll
      for (int h = 0; h < 2; ++h){
        const short8 a = *(const short8*)((const char*)wl3 + arow[g][h] + ks*64);
        #pragma unroll
        for (int ng = 0; ng < 2; ++ng)
          acc[g][h][ng] = __builtin_amdgcn_mfma_f32_16x16x32_bf16(
              a, bfr[ng], acc[g][h][ng], 0, 0, 0);
      }
  }

  const size_t xcolbase = (size_t)(s & 3)*8192 + b0;
  #pragma unroll
  for (int h = 0; h < 2; ++h)
    #pragma unroll
    for (int ng = 0; ng < 2; ++ng)
      #pragma unroll
      for (int j = 0; j < 4; ++j){
        const int c = c0r + h*16 + (lane>>4)*4 + j;
        const int b = b0 + ng*16 + (lane & 15);
        const size_t xc = xcolbase + ng*16 + (lane & 15);
        const float ig = acc[0][h][ng][j] + xg[(size_t)(0*128+c)*32768 + xc] + bih[c]       + bhh[c];
        const float fg = acc[1][h][ng][j] + xg[(size_t)(1*128+c)*32768 + xc] + bih[128 + c] + bhh[128 + c];
        const float gg = acc[2][h][ng][j] + xg[(size_t)(2*128+c)*32768 + xc] + bih[256 + c] + bhh[256 + c];
        const float og = acc[3][h][ng][j] + xg[(size_t)(3*128+c)*32768 + xc] + bih[384 + c] + bhh[384 + c];
        const float cold = cT[c*BATCH + b];
        const float cn = sigf(fg)*cold + sigf(ig)*tanhfast(gg);
        const float hn = sigf(og)*tanhfast(cn);
        cT  [c*BATCH + b] = cn;
        hout[c*BATCH + b] = hn;
      }
}

// K8a: P[s][b] = sigmoid(ow . hseq[s][:,b] + ob)
__global__ __launch_bounds__(256) void k_headp(
    const float* __restrict__ hseq, const float* __restrict__ ow,
    const float* __restrict__ ob, float* __restrict__ P)
{
  const int idx = blockIdx.x*256 + threadIdx.x;   // 65536
  const int s = idx >> 13, b = idx & (BATCH-1);
  const float* hp = hseq + (size_t)s*HID*BATCH;
  float acc = ob[0];
  for (int c = 0; c < 128; ++c) acc += ow[c]*hp[c*BATCH + b];
  P[s*BATCH + b] = sigf(acc);
}
// K8b: final = 1 - prod(1 - P[s])
__global__ __launch_bounds__(256) void k_head2(
    const float* __restrict__ P, float* __restrict__ outp)
{
  const int b = blockIdx.x*256 + threadIdx.x;     // 8192
  float prod = 1.f;
  #pragma unroll
  for (int s = 0; s < 8; ++s) prod *= (1.f - P[s*BATCH + b]);
  outp[b] = 1.f - prod;
}

// K9: transpose h_fin, c_fin to [B,128] in d_out
__global__ __launch_bounds__(256) void k_outT(
    const float* __restrict__ h7, const float* __restrict__ cT,
    float* __restrict__ out)
{
  const int idx = blockIdx.x*256 + threadIdx.x;   // 1M
  const int b = idx >> 7, c = idx & 127;
  out[8192 + idx]           = h7[c*BATCH + b];
  out[8192 + 1048576 + idx] = cT[c*BATCH + b];
}

// ---------------------------------------------------------------------------
extern "C" void kernel_launch(void* const* d_in, const int* in_sizes, int n_in,
                              void* d_out, int out_size, void* d_ws, size_t ws_size,
                              hipStream_t stream)
{
  (void)in_sizes; (void)n_in; (void)out_size; (void)ws_size;
  const float* audio = (const float*)d_in[0];
  const float* h0    = (const float*)d_in[1];
  const float* c0    = (const float*)d_in[2];
  const float* stftw = (const float*)d_in[3];
  const float* w1 = (const float*)d_in[4];  const float* b1 = (const float*)d_in[5];
  const float* w2 = (const float*)d_in[6];  const float* b2 = (const float*)d_in[7];
  const float* w3 = (const float*)d_in[8];  const float* b3 = (const float*)d_in[9];
  const float* w4 = (const float*)d_in[10]; const float* b4 = (const float*)d_in[11];
  const float* wih = (const float*)d_in[12]; const float* whh = (const float*)d_in[13];
  const float* bih = (const float*)d_in[14]; const float* bhh = (const float*)d_in[15];
  const float* ow  = (const float*)d_in[16]; const float* ob  = (const float*)d_in[17];
  float* out = (float*)d_out;

  // Workspace schedule (validated r18/r20):
  char* ws = (char*)d_ws;
  bf16*  mag  = (bf16*) (ws + 0);
  bf16*  w2b  = (bf16*) (ws + 0);
  bf16*  w3e  = (bf16*) (ws + 1048576);
  bf16*  w4e  = (bf16*) (ws + 1081344);
  bf16*  h4   = (bf16*) (ws + 8388608);
  float* xg   = (float*)(ws + 25165824);
  float* hseq = (float*)(ws + 92274688);
  float* hT0  = (float*)(ws + 125829120);
  float* cT   = (float*)(ws + 130023424);
  bf16*  h1   = (bf16*) (ws + 67633152);
  bf16*  Wbf  = (bf16*) (ws + 67633152);
  bf16*  h2   = (bf16*) (ws + 134742016);
  bf16*  w1b  = (bf16*) (ws + 134742016);
  bf16*  wl3  = (bf16*) (ws + 134742016);
  bf16*  wlx  = (bf16*) (ws + 135135232);
  float* Pbuf = (float*)(ws + 135397376);

  k_wcvt  <<<258, 256, 0, stream>>>(stftw, Wbf);
  k_w1cvt <<<480, 256, 0, stream>>>(w1, w1b);
  k_stft3<<<2048, 256, 0, stream>>>(audio, Wbf, mag);
  k_enc1_gemm<<<2048, 256, 0, stream>>>(mag, w1b, b1, h1);
  k_w2cvt <<<192, 256, 0, stream>>>(w2, w2b);           // after enc1: mag dead
  k_w34cvt<<<128, 256, 0, stream>>>(w3, w4, w3e, w4e);  // after enc1: mag dead
  k_enc2_gemm<<<2048, 256, 0, stream>>>(h1, w2b, b2, h2);
  k_init <<<4096, 256, 0, stream>>>(h0, c0, hT0, cT);   // after enc2: h1 dead
  k_enc34<<<1024, 256, 0, stream>>>(h2, w3e, b3, w4e, b4, h4);
  k_wlcvt3<<<768, 256, 0, stream>>>(whh, wl3);          // after enc34: h2 dead
  k_wlxcvt<<<512, 256, 0, stream>>>(wih, wlx);
  for (int half = 0; half < 2; ++half){
    k_gatex<<<1024, 256, 0, stream>>>(h4, wlx, xg, half);
    for (int q = 0; q < 4; ++q){
      const int s = half*4 + q;
      const float* hprev = (s == 0) ? hT0 : (hseq + (size_t)(s-1)*HID*BATCH);
      k_lstm_rec<<<256, 256, 0, stream>>>(xg, wl3, bih, bhh, hprev,
                                          hseq + (size_t)s*HID*BATCH, cT, s);
    }
  }
  k_headp<<<256, 256, 0, stream>>>(hseq, ow, ob, Pbuf);
  k_head2<<<32, 256, 0, stream>>>(Pbuf, out);
  k_outT<<<4096, 256, 0, stream>>>(hseq + (size_t)7*HID*BATCH, cT, out);
}

// Round 23
// 577.572 us; speedup vs baseline: 1.4726x; 1.2393x over previous
//
#include <hip/hip_runtime.h>
#include <hip/hip_bf16.h>
#include <math.h>

typedef __hip_bfloat16 bf16;
typedef __attribute__((ext_vector_type(4))) float f32x4;
typedef __attribute__((ext_vector_type(8))) short short8;
typedef __attribute__((ext_vector_type(4))) short short4v;

#define BATCH   8192
#define NTOT    65536      // 8 chunks * BATCH
#define NT2     131072     // 2 frames * NTOT (enc2 out)
#define NW      262144     // 8 chunks * 4 frames * BATCH
#define HID     128

__device__ __forceinline__ float b2f(bf16 v){ return __bfloat162float(v); }
__device__ __forceinline__ bf16  f2b(float v){ return __float2bfloat16(v); }
__device__ __forceinline__ short f2bs(float v){
  bf16 b = __float2bfloat16(v);
  return *reinterpret_cast<short*>(&b);
}
__device__ __forceinline__ float sigf(float x){ return 1.0f/(1.0f+__expf(-x)); }
__device__ __forceinline__ float tanhfast(float x){
  return 1.0f - 2.0f/(__expf(2.0f*x)+1.0f);
}

// ---------------------------------------------------------------------------
// Weight conversion. Feed-forward weights: SINGLE bf16 (r23: lo-plane dropped
// — r2/r10 bit-identical absmax proved the error floor is activation quant,
// not weight quant). Recurrent wl3 keeps hi/lo (8-step error integration).
// ---------------------------------------------------------------------------
__global__ __launch_bounds__(256) void k_wcvt(        // stft W -> bf16 [258][256]
    const float* __restrict__ W, bf16* __restrict__ Wb)
{
  const int idx = blockIdx.x*256 + threadIdx.x;
  if (idx < 258*256) Wb[idx] = f2b(W[idx]);
}
__global__ __launch_bounds__(256) void k_w1cvt(       // w1 -> [3][128][160] bf16
    const float* __restrict__ w1, bf16* __restrict__ w1b)
{
  const int idx = blockIdx.x*256 + threadIdx.x;       // 3*128*160 = 61440
  if (idx >= 61440) return;
  const int dt = idx / 20480, rem = idx % 20480;
  const int cout = rem / 160, k = rem % 160;
  const float v = (k < 129) ? w1[(cout*129 + k)*3 + dt] : 0.f;
  w1b[idx] = f2b(v);
}
__global__ __launch_bounds__(256) void k_w2cvt(       // w2 -> [3][64][128] bf16
    const float* __restrict__ w2, bf16* __restrict__ w2b)
{
  const int idx = blockIdx.x*256 + threadIdx.x;       // 3*64*128 = 24576
  if (idx >= 24576) return;
  const int dt = idx >> 13, cout = (idx >> 7) & 63, k = idx & 127;
  w2b[idx] = f2b(w2[(cout*128 + k)*3 + dt]);
}
// enc3 taps 1,2 -> w3e[64][128]; enc4 center -> w4e[128][64]  (single bf16)
__global__ __launch_bounds__(256) void k_w34cvt(
    const float* __restrict__ w3, const float* __restrict__ w4,
    bf16* __restrict__ w3e, bf16* __restrict__ w4e)
{
  const int idx = blockIdx.x*256 + threadIdx.x;       // 16384
  if (idx >= 16384) return;
  if (idx < 8192){
    const int row = idx >> 7, k = idx & 127;
    const int cin = k >> 1, t = k & 1;
    w3e[idx] = f2b(w3[(row*64 + cin)*3 + 1 + t]);
  } else {
    const int i2 = idx - 8192;
    const int row = i2 >> 6, cin = i2 & 63;
    w4e[i2] = f2b(w4[(row*64 + cin)*3 + 1]);
  }
}
// Whh-only recurrent weights -> [512][384]: [Whh_hi | Whh_hi | Whh_lo]
__global__ __launch_bounds__(256) void k_wlcvt3(
    const float* __restrict__ whh, bf16* __restrict__ wl3)
{
  const int idx = blockIdx.x*256 + threadIdx.x;       // 512*384 = 196608
  if (idx >= 196608) return;
  const int r = idx / 384, k = idx % 384;
  const int part = k >> 7, kk = k & 127;
  const float f = whh[r*128 + kk];
  const bf16 hi = f2b(f);
  wl3[idx] = (part < 2) ? hi : f2b(f - b2f(hi));
}
// Wih single bf16 plane: wlx[512][128]
__global__ __launch_bounds__(256) void k_wlxcvt(
    const float* __restrict__ wih, bf16* __restrict__ wlx)
{
  const int idx = blockIdx.x*256 + threadIdx.x;       // 65536
  if (idx >= 65536) return;
  wlx[idx] = f2b(wih[idx]);
}

// ---------------------------------------------------------------------------
// K1 v5 (validated r19): STFT MFMA GEMM, per-pass A-tile staged in LDS.
// mag [129][NW].
// ---------------------------------------------------------------------------
__global__ __launch_bounds__(256) void k_stft3(
    const float* __restrict__ audio, const bf16* __restrict__ Wb,
    bf16* __restrict__ mag)
{
  __shared__ __align__(16) char ALDS[96*512];      // 48 KB
  __shared__ __align__(16) bf16 refl[4*8*64];      // 4 KB
  const int tid = threadIdx.x, lane = tid & 63, wq = tid >> 6;
  const int r0 = blockIdx.x * 4;                   // 2048 blocks
  const float* arow = audio + (size_t)(r0 + wq) * 4160;

  #pragma unroll
  for (int q = 0; q < 8; ++q){
    const int e = q*64 + lane;
    const int i = e >> 6, k = e & 63;
    refl[(wq*8 + i)*64 + k] = f2b(arow[512*i + 64 - k]);
  }

  const int kgo8 = (lane>>4)*8;
  short8 Bfrag[2][8];
  #pragma unroll
  for (int ng = 0; ng < 2; ++ng){
    const int wl = ng*16 + (lane & 15);
    const int i = wl >> 2, t = wl & 3;
    #pragma unroll
    for (int ks = 0; ks < 8; ++ks){
      const int kb = ks*32 + kgo8;
      if (t == 0 && kb < 64){
        Bfrag[ng][ks] = *(const short8*)(refl + (wq*8 + i)*64 + kb);
      } else {
        const float* src = arow + 512*i + 128*t - 64 + kb;
        const float4 v0 = *(const float4*)(src);
        const float4 v1 = *(const float4*)(src + 4);
        short8 s;
        s[0]=f2bs(v0.x); s[1]=f2bs(v0.y); s[2]=f2bs(v0.z); s[3]=f2bs(v0.w);
        s[4]=f2bs(v1.x); s[5]=f2bs(v1.y); s[6]=f2bs(v1.z); s[7]=f2bs(v1.w);
        Bfrag[ng][ks] = s;
      }
    }
  }

  const int kab = (lane>>4)*16;
  for (int pass = 0; pass < 3; ++pass){
    __syncthreads();
    for (int idx = tid; idx < 96*32; idx += 256){
      const int ar = idx >> 5;
      const int cb = (idx & 31) * 16;
      const int b3 = ar >> 5, reim = (ar >> 4) & 1, bl = ar & 15;
      int bin = pass*48 + b3*16 + bl;
      if (bin > 128) bin = 128;
      const int grow = bin + reim*129;
      int off = ar*512 + cb; off ^= ((ar&7)<<4);
      *(f32x4*)(ALDS + off) = *(const f32x4*)((const char*)Wb + grow*512 + cb);
    }
    __syncthreads();

    f32x4 accRe[3][2], accIm[3][2];
    #pragma unroll
    for (int b3 = 0; b3 < 3; ++b3)
      #pragma unroll
      for (int ng = 0; ng < 2; ++ng){
        accRe[b3][ng] = f32x4{0.f,0.f,0.f,0.f};
        accIm[b3][ng] = f32x4{0.f,0.f,0.f,0.f};
      }
    #pragma unroll
    for (int ks = 0; ks < 8; ++ks){
      #pragma unroll
      for (int b3 = 0; b3 < 3; ++b3){
        const int arRe = b3*32 + (lane & 15);
        const int arIm = arRe + 16;
        int offRe = arRe*512 + ks*64 + kab; offRe ^= ((arRe&7)<<4);
        int offIm = arIm*512 + ks*64 + kab; offIm ^= ((arIm&7)<<4);
        const short8 aRe = *(const short8*)(ALDS + offRe);
        const short8 aIm = *(const short8*)(ALDS + offIm);
        #pragma unroll
        for (int ng = 0; ng < 2; ++ng){
          accRe[b3][ng] = __builtin_amdgcn_mfma_f32_16x16x32_bf16(
              aRe, Bfrag[ng][ks], accRe[b3][ng], 0, 0, 0);
          accIm[b3][ng] = __builtin_amdgcn_mfma_f32_16x16x32_bf16(
              aIm, Bfrag[ng][ks], accIm[b3][ng], 0, 0, 0);
        }
      }
    }
    #pragma unroll
    for (int b3 = 0; b3 < 3; ++b3)
      #pragma unroll
      for (int j = 0; j < 4; ++j){
        const int bin = (pass*3 + b3)*16 + (lane>>4)*4 + j;
        if (bin <= 128){
          #pragma unroll
          for (int ng = 0; ng < 2; ++ng){
            const int wl = ng*16 + (lane & 15);
            const int i = wl >> 2, t = wl & 3;
            const float re = accRe[b3][ng][j], im = accIm[b3][ng][j];
            mag[(size_t)bin*NW + (size_t)i*32768 + (r0+wq)*4 + t] =
                f2b(sqrtf(re*re + im*im));
          }
        }
      }
  }
}

// ---------------------------------------------------------------------------
// K2: enc1 MFMA GEMM, single-bf16 A (r23). h1 [128][NW].
// ---------------------------------------------------------------------------
#define E1_LDS (192*320)
__global__ __launch_bounds__(256) void k_enc1_gemm(
    const bf16* __restrict__ mag, const bf16* __restrict__ w1b,
    const float* __restrict__ b1, bf16* __restrict__ h1)
{
  __shared__ __align__(16) char Bs[E1_LDS];
  const int tid = threadIdx.x, lane = tid & 63, wq = tid >> 6;
  const int n0 = blockIdx.x * 32;
  const int i  = n0 >> 13, b0 = n0 & 8191;
  const size_t colbase = (size_t)i*32768 + (size_t)b0*4;

  for (int off = tid*16; off < E1_LDS; off += 256*16)
    *(f32x4*)(Bs + off) = f32x4{0.f,0.f,0.f,0.f};
  __syncthreads();
  for (int it = tid; it < 129*64; it += 256){
    const int cin = it >> 6, seg = it & 63;
    const unsigned int pair =
        *(const unsigned int*)(mag + (size_t)cin*NW + colbase + seg*2);
    #pragma unroll
    for (int q = 0; q < 2; ++q){
      const int w = seg*2 + q;
      const int row = (w>>2)*6 + (w&3) + 1;
      int off = row*320 + cin*2; off ^= ((row&7)<<4);
      *(short*)(Bs + off) = (short)((q==0) ? (pair & 0xffff) : (pair >> 16));
    }
  }
  __syncthreads();

  const int wr = wq >> 1, wc = wq & 1;
  f32x4 acc[4][4];
  #pragma unroll
  for (int mg = 0; mg < 4; ++mg)
    #pragma unroll
    for (int ng = 0; ng < 4; ++ng) acc[mg][ng] = f32x4{0.f,0.f,0.f,0.f};

  int brow[4], acol[4];
  #pragma unroll
  for (int ng = 0; ng < 4; ++ng){
    const int w = wc*64 + ng*16 + (lane & 15);
    brow[ng] = (w>>2)*6 + (w&3);
  }
  #pragma unroll
  for (int mg = 0; mg < 4; ++mg) acol[mg] = wr*64 + mg*16 + (lane & 15);
  const int kb = (lane>>4)*16;

  for (int dt = 0; dt < 3; ++dt){
    #pragma unroll
    for (int ks = 0; ks < 5; ++ks){
      short8 afr[4], bfr[4];
      #pragma unroll
      for (int mg = 0; mg < 4; ++mg)
        afr[mg] = *(const short8*)((const char*)w1b +
            ((dt*128 + acol[mg])*160 + ks*32)*2 + kb);
      #pragma unroll
      for (int ng = 0; ng < 4; ++ng){
        const int row = brow[ng] + dt;
        int off = row*320 + ks*64 + kb; off ^= ((row&7)<<4);
        bfr[ng] = *(const short8*)(Bs + off);
      }
      #pragma unroll
      for (int mg = 0; mg < 4; ++mg)
        #pragma unroll
        for (int ng = 0; ng < 4; ++ng)
          acc[mg][ng] = __builtin_amdgcn_mfma_f32_16x16x32_bf16(
              afr[mg], bfr[ng], acc[mg][ng], 0, 0, 0);
    }
  }
  #pragma unroll
  for (int mg = 0; mg < 4; ++mg)
    #pragma unroll
    for (int j = 0; j < 4; ++j){
      const int cout = wr*64 + mg*16 + (lane>>4)*4 + j;
      const float bv = b1[cout];
      #pragma unroll
      for (int ng = 0; ng < 4; ++ng){
        const int col = wc*64 + ng*16 + (lane & 15);
        float v = acc[mg][ng][j] + bv; v = v > 0.f ? v : 0.f;
        h1[(size_t)cout*NW + colbase + col] = f2b(v);
      }
    }
}

// ---------------------------------------------------------------------------
// K3: enc2 MFMA GEMM, single-bf16 A (r23). h2 [64][NT2].
// ---------------------------------------------------------------------------
#define E2_LDS (160*256)
__global__ __launch_bounds__(256) void k_enc2_gemm(
    const bf16* __restrict__ h1, const bf16* __restrict__ w2b,
    const float* __restrict__ b2, bf16* __restrict__ h2)
{
  __shared__ __align__(16) char Bs[E2_LDS];
  const int tid = threadIdx.x, lane = tid & 63, wq = tid >> 6;
  const int n0 = blockIdx.x * 32;
  const int i  = n0 >> 13, b0 = n0 & 8191;
  const size_t colbase = (size_t)i*32768 + (size_t)b0*4;
  const size_t col2base = (size_t)i*16384 + (size_t)b0*2;

  for (int off = tid*16; off < E2_LDS; off += 256*16)
    *(f32x4*)(Bs + off) = f32x4{0.f,0.f,0.f,0.f};
  __syncthreads();
  for (int it = tid; it < 128*64; it += 256){
    const int cin = it >> 6, seg = it & 63;
    const unsigned int pair =
        *(const unsigned int*)(h1 + (size_t)cin*NW + colbase + seg*2);
    #pragma unroll
    for (int q = 0; q < 2; ++q){
      const int w = seg*2 + q;
      const int row = (w>>2)*5 + (w&3) + 1;
      int off = row*256 + cin*2; off ^= ((row&7)<<4);
      *(short*)(Bs + off) = (short)((q==0) ? (pair & 0xffff) : (pair >> 16));
    }
  }
  __syncthreads();

  const int wr = wq >> 1, wc = wq & 1;
  f32x4 acc[2][2];
  #pragma unroll
  for (int mg = 0; mg < 2; ++mg)
    #pragma unroll
    for (int ng = 0; ng < 2; ++ng) acc[mg][ng] = f32x4{0.f,0.f,0.f,0.f};

  int brow[2], acol[2];
  #pragma unroll
  for (int ng = 0; ng < 2; ++ng){
    const int wl = wc*32 + ng*16 + (lane & 15);
    brow[ng] = (wl>>1)*5 + (wl&1)*2;
  }
  #pragma unroll
  for (int mg = 0; mg < 2; ++mg) acol[mg] = wr*32 + mg*16 + (lane & 15);
  const int kb = (lane>>4)*16;

  for (int dt = 0; dt < 3; ++dt){
    #pragma unroll
    for (int ks = 0; ks < 4; ++ks){
      short8 afr[2], bfr[2];
      #pragma unroll
      for (int mg = 0; mg < 2; ++mg)
        afr[mg] = *(const short8*)((const char*)w2b +
            ((dt*64 + acol[mg])*128 + ks*32)*2 + kb);
      #pragma unroll
      for (int ng = 0; ng < 2; ++ng){
        const int row = brow[ng] + dt;
        int off = row*256 + ks*64 + kb; off ^= ((row&7)<<4);
        bfr[ng] = *(const short8*)(Bs + off);
      }
      #pragma unroll
      for (int mg = 0; mg < 2; ++mg)
        #pragma unroll
        for (int ng = 0; ng < 2; ++ng)
          acc[mg][ng] = __builtin_amdgcn_mfma_f32_16x16x32_bf16(
              afr[mg], bfr[ng], acc[mg][ng], 0, 0, 0);
    }
  }
  #pragma unroll
  for (int mg = 0; mg < 2; ++mg)
    #pragma unroll
    for (int j = 0; j < 4; ++j){
      const int cout = wr*32 + mg*16 + (lane>>4)*4 + j;
      const float bv = b2[cout];
      #pragma unroll
      for (int ng = 0; ng < 2; ++ng){
        const int col = wc*32 + ng*16 + (lane & 15);
        float v = acc[mg][ng][j] + bv; v = v > 0.f ? v : 0.f;
        h2[(size_t)cout*NT2 + col2base + col] = f2b(v);
      }
    }
}

// ---------------------------------------------------------------------------
// K4+K5 FUSED: enc3 -> enc4 MFMA, single-bf16 A (r23). h4 [128][NTOT].
// GEMM1: K=128 (ks 0..3). GEMM2: K=64 (ks 0..1).
// ---------------------------------------------------------------------------
__global__ __launch_bounds__(256) void k_enc34(
    const bf16* __restrict__ h2, const bf16* __restrict__ w3e,
    const float* __restrict__ b3, const bf16* __restrict__ w4e,
    const float* __restrict__ b4, bf16* __restrict__ h4)
{
  __shared__ __align__(16) char B1[64*256];       // 16 KB
  __shared__ __align__(16) char B2[64*128];       //  8 KB
  const int tid = threadIdx.x, lane = tid & 63, wq = tid >> 6;
  const int n0 = blockIdx.x * 64;                 // 1024 blocks

  for (int it = tid; it < 64*64; it += 256){
    const int cin = it >> 6, nl = it & 63;
    const int n = n0 + nl, i = n >> 13, b = n & 8191;
    const unsigned int pair =
        *(const unsigned int*)(h2 + (size_t)cin*NT2 + i*16384 + 2*b);
    int off = nl*256 + cin*4; off ^= ((nl&7)<<4);
    *(unsigned int*)(B1 + off) = pair;
  }
  __syncthreads();

  const int kb = (lane>>4)*16;
  f32x4 acc1[4];
  #pragma unroll
  for (int ng = 0; ng < 4; ++ng) acc1[ng] = f32x4{0.f,0.f,0.f,0.f};
  const int ar1 = wq*16 + (lane & 15);
  #pragma unroll
  for (int ks = 0; ks < 4; ++ks){
    const short8 a = *(const short8*)((const char*)w3e + (ar1*128 + ks*32)*2 + kb);
    #pragma unroll
    for (int ng = 0; ng < 4; ++ng){
      const int row = ng*16 + (lane & 15);
      int off = row*256 + ks*64 + kb; off ^= ((row&7)<<4);
      const short8 bfr = *(const short8*)(B1 + off);
      acc1[ng] = __builtin_amdgcn_mfma_f32_16x16x32_bf16(a, bfr, acc1[ng], 0, 0, 0);
    }
  }
  #pragma unroll
  for (int j = 0; j < 4; ++j){
    const int r1 = wq*16 + (lane>>4)*4 + j;
    const float bv = b3[r1];
    #pragma unroll
    for (int ng = 0; ng < 4; ++ng){
      const int col = ng*16 + (lane & 15);
      float v = acc1[ng][j] + bv; v = v > 0.f ? v : 0.f;
      int off = col*128 + r1*2; off ^= ((col&7)<<4);
      *(short*)(B2 + off) = f2bs(v);
    }
  }
  __syncthreads();

  f32x4 acc2[2][4];
  #pragma unroll
  for (int mg = 0; mg < 2; ++mg)
    #pragma unroll
    for (int ng = 0; ng < 4; ++ng) acc2[mg][ng] = f32x4{0.f,0.f,0.f,0.f};
  #pragma unroll
  for (int ks = 0; ks < 2; ++ks){
    short8 bfr[4];
    #pragma unroll
    for (int ng = 0; ng < 4; ++ng){
      const int row = ng*16 + (lane & 15);
      int off = row*128 + ks*64 + kb; off ^= ((row&7)<<4);
      bfr[ng] = *(const short8*)(B2 + off);
    }
    #pragma unroll
    for (int mg = 0; mg < 2; ++mg){
      const int ar2 = wq*32 + mg*16 + (lane & 15);
      const short8 a = *(const short8*)((const char*)w4e + (ar2*64 + ks*32)*2 + kb);
      #pragma unroll
      for (int ng = 0; ng < 4; ++ng)
        acc2[mg][ng] = __builtin_amdgcn_mfma_f32_16x16x32_bf16(a, bfr[ng], acc2[mg][ng], 0, 0, 0);
    }
  }
  #pragma unroll
  for (int mg = 0; mg < 2; ++mg)
    #pragma unroll
    for (int j = 0; j < 4; ++j){
      const int cout = wq*32 + mg*16 + (lane>>4)*4 + j;
      const float bv = b4[cout];
      #pragma unroll
      for (int ng = 0; ng < 4; ++ng){
        const int n = n0 + ng*16 + (lane & 15);
        float v = acc2[mg][ng][j] + bv; v = v > 0.f ? v : 0.f;
        h4[(size_t)cout*NTOT + n] = f2b(v);
      }
    }
}

// K6: transpose h0/c0 [B,128] -> [128][B]
__global__ __launch_bounds__(256) void k_init(
    const float* __restrict__ h0, const float* __restrict__ c0,
    float* __restrict__ hT0, float* __restrict__ cT)
{
  const int idx = blockIdx.x*256 + threadIdx.x;   // 1M
  const int b = idx >> 7, c = idx & 127;
  hT0[c*BATCH + b] = h0[idx];
  cT [c*BATCH + b] = c0[idx];
}

// ---------------------------------------------------------------------------
// K-GX: xg[512][32768] = Wih @ x for 4 steps (one half). Single-bf16 A (r23).
// ---------------------------------------------------------------------------
__global__ __launch_bounds__(256) void k_gatex(
    const bf16* __restrict__ h4, const bf16* __restrict__ wlx,
    float* __restrict__ xg, int half)
{
  __shared__ __align__(16) char Bs[32*256];
  const int tid = threadIdx.x, lane = tid & 63, wq = tid >> 6;
  const int n0 = blockIdx.x * 32;
  const int gcol = half*32768 + n0;

  for (int it = tid; it < 128*32; it += 256){
    const int cp = it >> 5, nl = it & 31;
    const bf16 v = h4[(size_t)cp*NTOT + gcol + nl];
    int off = nl*256 + cp*2; off ^= ((nl&7)<<4);
    *(short*)(Bs + off) = *(const short*)&v;
  }
  __syncthreads();

  f32x4 acc[8][2];
  #pragma unroll
  for (int mg = 0; mg < 8; ++mg)
    #pragma unroll
    for (int ng = 0; ng < 2; ++ng) acc[mg][ng] = f32x4{0.f,0.f,0.f,0.f};

  int arow[8];
  #pragma unroll
  for (int mg = 0; mg < 8; ++mg) arow[mg] = wq*128 + mg*16 + (lane & 15);
  const int kb = (lane>>4)*16;

  #pragma unroll
  for (int ks = 0; ks < 4; ++ks){
    short8 bfr[2];
    #pragma unroll
    for (int ng = 0; ng < 2; ++ng){
      const int row = ng*16 + (lane & 15);
      int off = row*256 + ks*64 + kb; off ^= ((row&7)<<4);
      bfr[ng] = *(const short8*)(Bs + off);
    }
    #pragma unroll
    for (int mg = 0; mg < 8; ++mg){
      const short8 a = *(const short8*)((const char*)wlx +
          ((size_t)arow[mg]*128 + ks*32)*2 + kb);
      #pragma unroll
      for (int ng = 0; ng < 2; ++ng)
        acc[mg][ng] = __builtin_amdgcn_mfma_f32_16x16x32_bf16(
            a, bfr[ng], acc[mg][ng], 0, 0, 0);
    }
  }

  #pragma unroll
  for (int mg = 0; mg < 8; ++mg)
    #pragma unroll
    for (int j = 0; j < 4; ++j){
      const int row = wq*128 + mg*16 + (lane>>4)*4 + j;
      #pragma unroll
      for (int ng = 0; ng < 2; ++ng){
        const int col = n0 + ng*16 + (lane & 15);
        xg[(size_t)row*32768 + col] = acc[mg][ng][j];
      }
    }
}

// ---------------------------------------------------------------------------
// K7 (validated r18/r20): one recurrent LSTM step, Whh-only MFMA (K=384,
// hi/lo kept for recurrence), 32 batch cols per block, 256 blocks.
// ---------------------------------------------------------------------------
__global__ __launch_bounds__(256) void k_lstm_rec(
    const float* __restrict__ xg, const bf16* __restrict__ wl3,
    const float* __restrict__ bih, const float* __restrict__ bhh,
    const float* __restrict__ hprev, float* __restrict__ hout,
    float* __restrict__ cT, int s)
{
  __shared__ __align__(16) char Bs[32*768];
  const int tid = threadIdx.x, lane = tid & 63, wq = tid >> 6;
  const int b0 = blockIdx.x * 32;

  for (int it = tid; it < 128*32; it += 256){
    const int cp = it >> 5, bl = it & 31;
    const float v = hprev[cp*BATCH + b0 + bl];
    const bf16 hi = f2b(v);
    const bf16 lo = f2b(v - b2f(hi));
    int off1 = bl*768 + cp*2;        off1 ^= ((bl&7)<<4);
    int off2 = bl*768 + (128+cp)*2;  off2 ^= ((bl&7)<<4);
    int off3 = bl*768 + (256+cp)*2;  off3 ^= ((bl&7)<<4);
    *(short*)(Bs + off1) = *(const short*)&hi;
    *(short*)(Bs + off2) = *(const short*)&lo;
    *(short*)(Bs + off3) = *(const short*)&hi;
  }
  __syncthreads();

  const int c0r = wq*32;
  f32x4 acc[4][2][2];
  #pragma unroll
  for (int g = 0; g < 4; ++g)
    #pragma unroll
    for (int h = 0; h < 2; ++h)
      #pragma unroll
      for (int ng = 0; ng < 2; ++ng) acc[g][h][ng] = f32x4{0.f,0.f,0.f,0.f};

  int arow[4][2];
  #pragma unroll
  for (int g = 0; g < 4; ++g)
    #pragma unroll
    for (int h = 0; h < 2; ++h)
      arow[g][h] = (g*128 + c0r + h*16 + (lane&15))*768 + (lane>>4)*16;

  #pragma unroll
  for (int ks = 0; ks < 12; ++ks){
    short8 bfr[2];
    #pragma unroll
    for (int ng = 0; ng < 2; ++ng){
      const int row = ng*16 + (lane & 15);
      int off = row*768 + ks*64 + (lane>>4)*16; off ^= ((row&7)<<4);
      bfr[ng] = *(const short8*)(Bs + off);
    }
    #pragma unroll
    for (int g = 0; g < 4; ++g)
      #pragma unroll
      for (int h = 0; h < 2; ++h){
        const short8 a = *(const short8*)((const char*)wl3 + arow[g][h] + ks*64);
        #pragma unroll
        for (int ng = 0; ng < 2; ++ng)
          acc[g][h][ng] = __builtin_amdgcn_mfma_f32_16x16x32_bf16(
              a, bfr[ng], acc[g][h][ng], 0, 0, 0);
      }
  }

  const size_t xcolbase = (size_t)(s & 3)*8192 + b0;
  #pragma unroll
  for (int h = 0; h < 2; ++h)
    #pragma unroll
    for (int ng = 0; ng < 2; ++ng)
      #pragma unroll
      for (int j = 0; j < 4; ++j){
        const int c = c0r + h*16 + (lane>>4)*4 + j;
        const int b = b0 + ng*16 + (lane & 15);
        const size_t xc = xcolbase + ng*16 + (lane & 15);
        const float ig = acc[0][h][ng][j] + xg[(size_t)(0*128+c)*32768 + xc] + bih[c]       + bhh[c];
        const float fg = acc[1][h][ng][j] + xg[(size_t)(1*128+c)*32768 + xc] + bih[128 + c] + bhh[128 + c];
        const float gg = acc[2][h][ng][j] + xg[(size_t)(2*128+c)*32768 + xc] + bih[256 + c] + bhh[256 + c];
        const float og = acc[3][h][ng][j] + xg[(size_t)(3*128+c)*32768 + xc] + bih[384 + c] + bhh[384 + c];
        const float cold = cT[c*BATCH + b];
        const float cn = sigf(fg)*cold + sigf(ig)*tanhfast(gg);
        const float hn = sigf(og)*tanhfast(cn);
        cT  [c*BATCH + b] = cn;
        hout[c*BATCH + b] = hn;
      }
}

// K8a: P[s][b] = sigmoid(ow . hseq[s][:,b] + ob)
__global__ __launch_bounds__(256) void k_headp(
    const float* __restrict__ hseq, const float* __restrict__ ow,
    const float* __restrict__ ob, float* __restrict__ P)
{
  const int idx = blockIdx.x*256 + threadIdx.x;   // 65536
  const int s = idx >> 13, b = idx & (BATCH-1);
  const float* hp = hseq + (size_t)s*HID*BATCH;
  float acc = ob[0];
  for (int c = 0; c < 128; ++c) acc += ow[c]*hp[c*BATCH + b];
  P[s*BATCH + b] = sigf(acc);
}
// K8b: final = 1 - prod(1 - P[s])
__global__ __launch_bounds__(256) void k_head2(
    const float* __restrict__ P, float* __restrict__ outp)
{
  const int b = blockIdx.x*256 + threadIdx.x;     // 8192
  float prod = 1.f;
  #pragma unroll
  for (int s = 0; s < 8; ++s) prod *= (1.f - P[s*BATCH + b]);
  outp[b] = 1.f - prod;
}

// K9: transpose h_fin, c_fin to [B,128] in d_out
__global__ __launch_bounds__(256) void k_outT(
    const float* __restrict__ h7, const float* __restrict__ cT,
    float* __restrict__ out)
{
  const int idx = blockIdx.x*256 + threadIdx.x;   // 1M
  const int b = idx >> 7, c = idx & 127;
  out[8192 + idx]           = h7[c*BATCH + b];
  out[8192 + 1048576 + idx] = cT[c*BATCH + b];
}

// ---------------------------------------------------------------------------
extern "C" void kernel_launch(void* const* d_in, const int* in_sizes, int n_in,
                              void* d_out, int out_size, void* d_ws, size_t ws_size,
                              hipStream_t stream)
{
  (void)in_sizes; (void)n_in; (void)out_size; (void)ws_size;
  const float* audio = (const float*)d_in[0];
  const float* h0    = (const float*)d_in[1];
  const float* c0    = (const float*)d_in[2];
  const float* stftw = (const float*)d_in[3];
  const float* w1 = (const float*)d_in[4];  const float* b1 = (const float*)d_in[5];
  const float* w2 = (const float*)d_in[6];  const float* b2 = (const float*)d_in[7];
  const float* w3 = (const float*)d_in[8];  const float* b3 = (const float*)d_in[9];
  const float* w4 = (const float*)d_in[10]; const float* b4 = (const float*)d_in[11];
  const float* wih = (const float*)d_in[12]; const float* whh = (const float*)d_in[13];
  const float* bih = (const float*)d_in[14]; const float* bhh = (const float*)d_in[15];
  const float* ow  = (const float*)d_in[16]; const float* ob  = (const float*)d_in[17];
  float* out = (float*)d_out;

  // Workspace schedule (validated r18/r20; buffers only shrink in r23):
  char* ws = (char*)d_ws;
  bf16*  mag  = (bf16*) (ws + 0);
  bf16*  w2b  = (bf16*) (ws + 0);
  bf16*  w3e  = (bf16*) (ws + 1048576);
  bf16*  w4e  = (bf16*) (ws + 1081344);
  bf16*  h4   = (bf16*) (ws + 8388608);
  float* xg   = (float*)(ws + 25165824);
  float* hseq = (float*)(ws + 92274688);
  float* hT0  = (float*)(ws + 125829120);
  float* cT   = (float*)(ws + 130023424);
  bf16*  h1   = (bf16*) (ws + 67633152);
  bf16*  Wbf  = (bf16*) (ws + 67633152);
  bf16*  h2   = (bf16*) (ws + 134742016);
  bf16*  w1b  = (bf16*) (ws + 134742016);
  bf16*  wl3  = (bf16*) (ws + 134742016);
  bf16*  wlx  = (bf16*) (ws + 135135232);
  float* Pbuf = (float*)(ws + 135397376);

  k_wcvt  <<<258, 256, 0, stream>>>(stftw, Wbf);
  k_w1cvt <<<240, 256, 0, stream>>>(w1, w1b);
  k_stft3<<<2048, 256, 0, stream>>>(audio, Wbf, mag);
  k_enc1_gemm<<<2048, 256, 0, stream>>>(mag, w1b, b1, h1);
  k_w2cvt <<<96, 256, 0, stream>>>(w2, w2b);            // after enc1: mag dead
  k_w34cvt<<<64, 256, 0, stream>>>(w3, w4, w3e, w4e);   // after enc1: mag dead
  k_enc2_gemm<<<2048, 256, 0, stream>>>(h1, w2b, b2, h2);
  k_init <<<4096, 256, 0, stream>>>(h0, c0, hT0, cT);   // after enc2: h1 dead
  k_enc34<<<1024, 256, 0, stream>>>(h2, w3e, b3, w4e, b4, h4);
  k_wlcvt3<<<768, 256, 0, stream>>>(whh, wl3);          // after enc34: h2 dead
  k_wlxcvt<<<256, 256, 0, stream>>>(wih, wlx);
  for (int half = 0; half < 2; ++half){
    k_gatex<<<1024, 256, 0, stream>>>(h4, wlx, xg, half);
    for (int q = 0; q < 4; ++q){
      const int s = half*4 + q;
      const float* hprev = (s == 0) ? hT0 : (hseq + (size_t)(s-1)*HID*BATCH);
      k_lstm_rec<<<256, 256, 0, stream>>>(xg, wl3, bih, bhh, hprev,
                                          hseq + (size_t)s*HID*BATCH, cT, s);
    }
  }
  k_headp<<<256, 256, 0, stream>>>(hseq, ow, ob, Pbuf);
  k_head2<<<32, 256, 0, stream>>>(Pbuf, out);
  k_outT<<<4096, 256, 0, stream>>>(hseq + (size_t)7*HID*BATCH, cT, out);
}

// Round 24
// 471.541 us; speedup vs baseline: 1.8038x; 1.2249x over previous
//
#include <hip/hip_runtime.h>
#include <hip/hip_bf16.h>
#include <math.h>

typedef __hip_bfloat16 bf16;
typedef __attribute__((ext_vector_type(4))) float f32x4;
typedef __attribute__((ext_vector_type(8))) short short8;
typedef __attribute__((ext_vector_type(4))) short short4v;

#define BATCH   8192
#define NTOT    65536      // 8 chunks * BATCH
#define NT2     131072     // 2 frames * NTOT (enc2 out)
#define NW      262144     // 8 chunks * 4 frames * BATCH
#define HID     128

__device__ __forceinline__ float b2f(bf16 v){ return __bfloat162float(v); }
__device__ __forceinline__ bf16  f2b(float v){ return __float2bfloat16(v); }
__device__ __forceinline__ short f2bs(float v){
  bf16 b = __float2bfloat16(v);
  return *reinterpret_cast<short*>(&b);
}
__device__ __forceinline__ float sigf(float x){ return 1.0f/(1.0f+__expf(-x)); }
__device__ __forceinline__ float tanhfast(float x){
  return 1.0f - 2.0f/(__expf(2.0f*x)+1.0f);
}

// ---------------------------------------------------------------------------
// Weight conversion — ALL weights single bf16 (r23 FF, r24 recurrent).
// ---------------------------------------------------------------------------
__global__ __launch_bounds__(256) void k_wcvt(        // stft W -> bf16 [258][256]
    const float* __restrict__ W, bf16* __restrict__ Wb)
{
  const int idx = blockIdx.x*256 + threadIdx.x;
  if (idx < 258*256) Wb[idx] = f2b(W[idx]);
}
__global__ __launch_bounds__(256) void k_w1cvt(       // w1 -> [3][128][160] bf16
    const float* __restrict__ w1, bf16* __restrict__ w1b)
{
  const int idx = blockIdx.x*256 + threadIdx.x;       // 3*128*160 = 61440
  if (idx >= 61440) return;
  const int dt = idx / 20480, rem = idx % 20480;
  const int cout = rem / 160, k = rem % 160;
  const float v = (k < 129) ? w1[(cout*129 + k)*3 + dt] : 0.f;
  w1b[idx] = f2b(v);
}
__global__ __launch_bounds__(256) void k_w2cvt(       // w2 -> [3][64][128] bf16
    const float* __restrict__ w2, bf16* __restrict__ w2b)
{
  const int idx = blockIdx.x*256 + threadIdx.x;       // 3*64*128 = 24576
  if (idx >= 24576) return;
  const int dt = idx >> 13, cout = (idx >> 7) & 63, k = idx & 127;
  w2b[idx] = f2b(w2[(cout*128 + k)*3 + dt]);
}
// enc3 taps 1,2 -> w3e[64][128]; enc4 center -> w4e[128][64]  (single bf16)
__global__ __launch_bounds__(256) void k_w34cvt(
    const float* __restrict__ w3, const float* __restrict__ w4,
    bf16* __restrict__ w3e, bf16* __restrict__ w4e)
{
  const int idx = blockIdx.x*256 + threadIdx.x;       // 16384
  if (idx >= 16384) return;
  if (idx < 8192){
    const int row = idx >> 7, k = idx & 127;
    const int cin = k >> 1, t = k & 1;
    w3e[idx] = f2b(w3[(row*64 + cin)*3 + 1 + t]);
  } else {
    const int i2 = idx - 8192;
    const int row = i2 >> 6, cin = i2 & 63;
    w4e[i2] = f2b(w4[(row*64 + cin)*3 + 1]);
  }
}
// Whh single bf16 plane: wl1[512][128]  (r24: hi/lo dropped like FF weights)
__global__ __launch_bounds__(256) void k_wlcvt1(
    const float* __restrict__ whh, bf16* __restrict__ wl1)
{
  const int idx = blockIdx.x*256 + threadIdx.x;       // 65536
  if (idx >= 65536) return;
  wl1[idx] = f2b(whh[idx]);
}
// Wih single bf16 plane: wlx[512][128]
__global__ __launch_bounds__(256) void k_wlxcvt(
    const float* __restrict__ wih, bf16* __restrict__ wlx)
{
  const int idx = blockIdx.x*256 + threadIdx.x;       // 65536
  if (idx >= 65536) return;
  wlx[idx] = f2b(wih[idx]);
}

// ---------------------------------------------------------------------------
// K1 v5 (validated r19): STFT MFMA GEMM, per-pass A-tile staged in LDS.
// mag [129][NW].
// ---------------------------------------------------------------------------
__global__ __launch_bounds__(256) void k_stft3(
    const float* __restrict__ audio, const bf16* __restrict__ Wb,
    bf16* __restrict__ mag)
{
  __shared__ __align__(16) char ALDS[96*512];      // 48 KB
  __shared__ __align__(16) bf16 refl[4*8*64];      // 4 KB
  const int tid = threadIdx.x, lane = tid & 63, wq = tid >> 6;
  const int r0 = blockIdx.x * 4;                   // 2048 blocks
  const float* arow = audio + (size_t)(r0 + wq) * 4160;

  #pragma unroll
  for (int q = 0; q < 8; ++q){
    const int e = q*64 + lane;
    const int i = e >> 6, k = e & 63;
    refl[(wq*8 + i)*64 + k] = f2b(arow[512*i + 64 - k]);
  }

  const int kgo8 = (lane>>4)*8;
  short8 Bfrag[2][8];
  #pragma unroll
  for (int ng = 0; ng < 2; ++ng){
    const int wl = ng*16 + (lane & 15);
    const int i = wl >> 2, t = wl & 3;
    #pragma unroll
    for (int ks = 0; ks < 8; ++ks){
      const int kb = ks*32 + kgo8;
      if (t == 0 && kb < 64){
        Bfrag[ng][ks] = *(const short8*)(refl + (wq*8 + i)*64 + kb);
      } else {
        const float* src = arow + 512*i + 128*t - 64 + kb;
        const float4 v0 = *(const float4*)(src);
        const float4 v1 = *(const float4*)(src + 4);
        short8 s;
        s[0]=f2bs(v0.x); s[1]=f2bs(v0.y); s[2]=f2bs(v0.z); s[3]=f2bs(v0.w);
        s[4]=f2bs(v1.x); s[5]=f2bs(v1.y); s[6]=f2bs(v1.z); s[7]=f2bs(v1.w);
        Bfrag[ng][ks] = s;
      }
    }
  }

  const int kab = (lane>>4)*16;
  for (int pass = 0; pass < 3; ++pass){
    __syncthreads();
    for (int idx = tid; idx < 96*32; idx += 256){
      const int ar = idx >> 5;
      const int cb = (idx & 31) * 16;
      const int b3 = ar >> 5, reim = (ar >> 4) & 1, bl = ar & 15;
      int bin = pass*48 + b3*16 + bl;
      if (bin > 128) bin = 128;
      const int grow = bin + reim*129;
      int off = ar*512 + cb; off ^= ((ar&7)<<4);
      *(f32x4*)(ALDS + off) = *(const f32x4*)((const char*)Wb + grow*512 + cb);
    }
    __syncthreads();

    f32x4 accRe[3][2], accIm[3][2];
    #pragma unroll
    for (int b3 = 0; b3 < 3; ++b3)
      #pragma unroll
      for (int ng = 0; ng < 2; ++ng){
        accRe[b3][ng] = f32x4{0.f,0.f,0.f,0.f};
        accIm[b3][ng] = f32x4{0.f,0.f,0.f,0.f};
      }
    #pragma unroll
    for (int ks = 0; ks < 8; ++ks){
      #pragma unroll
      for (int b3 = 0; b3 < 3; ++b3){
        const int arRe = b3*32 + (lane & 15);
        const int arIm = arRe + 16;
        int offRe = arRe*512 + ks*64 + kab; offRe ^= ((arRe&7)<<4);
        int offIm = arIm*512 + ks*64 + kab; offIm ^= ((arIm&7)<<4);
        const short8 aRe = *(const short8*)(ALDS + offRe);
        const short8 aIm = *(const short8*)(ALDS + offIm);
        #pragma unroll
        for (int ng = 0; ng < 2; ++ng){
          accRe[b3][ng] = __builtin_amdgcn_mfma_f32_16x16x32_bf16(
              aRe, Bfrag[ng][ks], accRe[b3][ng], 0, 0, 0);
          accIm[b3][ng] = __builtin_amdgcn_mfma_f32_16x16x32_bf16(
              aIm, Bfrag[ng][ks], accIm[b3][ng], 0, 0, 0);
        }
      }
    }
    #pragma unroll
    for (int b3 = 0; b3 < 3; ++b3)
      #pragma unroll
      for (int j = 0; j < 4; ++j){
        const int bin = (pass*3 + b3)*16 + (lane>>4)*4 + j;
        if (bin <= 128){
          #pragma unroll
          for (int ng = 0; ng < 2; ++ng){
            const int wl = ng*16 + (lane & 15);
            const int i = wl >> 2, t = wl & 3;
            const float re = accRe[b3][ng][j], im = accIm[b3][ng][j];
            mag[(size_t)bin*NW + (size_t)i*32768 + (r0+wq)*4 + t] =
                f2b(sqrtf(re*re + im*im));
          }
        }
      }
  }
}

// ---------------------------------------------------------------------------
// K2: enc1 MFMA GEMM, single-bf16 A (validated r23). h1 [128][NW].
// ---------------------------------------------------------------------------
#define E1_LDS (192*320)
__global__ __launch_bounds__(256) void k_enc1_gemm(
    const bf16* __restrict__ mag, const bf16* __restrict__ w1b,
    const float* __restrict__ b1, bf16* __restrict__ h1)
{
  __shared__ __align__(16) char Bs[E1_LDS];
  const int tid = threadIdx.x, lane = tid & 63, wq = tid >> 6;
  const int n0 = blockIdx.x * 32;
  const int i  = n0 >> 13, b0 = n0 & 8191;
  const size_t colbase = (size_t)i*32768 + (size_t)b0*4;

  for (int off = tid*16; off < E1_LDS; off += 256*16)
    *(f32x4*)(Bs + off) = f32x4{0.f,0.f,0.f,0.f};
  __syncthreads();
  for (int it = tid; it < 129*64; it += 256){
    const int cin = it >> 6, seg = it & 63;
    const unsigned int pair =
        *(const unsigned int*)(mag + (size_t)cin*NW + colbase + seg*2);
    #pragma unroll
    for (int q = 0; q < 2; ++q){
      const int w = seg*2 + q;
      const int row = (w>>2)*6 + (w&3) + 1;
      int off = row*320 + cin*2; off ^= ((row&7)<<4);
      *(short*)(Bs + off) = (short)((q==0) ? (pair & 0xffff) : (pair >> 16));
    }
  }
  __syncthreads();

  const int wr = wq >> 1, wc = wq & 1;
  f32x4 acc[4][4];
  #pragma unroll
  for (int mg = 0; mg < 4; ++mg)
    #pragma unroll
    for (int ng = 0; ng < 4; ++ng) acc[mg][ng] = f32x4{0.f,0.f,0.f,0.f};

  int brow[4], acol[4];
  #pragma unroll
  for (int ng = 0; ng < 4; ++ng){
    const int w = wc*64 + ng*16 + (lane & 15);
    brow[ng] = (w>>2)*6 + (w&3);
  }
  #pragma unroll
  for (int mg = 0; mg < 4; ++mg) acol[mg] = wr*64 + mg*16 + (lane & 15);
  const int kb = (lane>>4)*16;

  for (int dt = 0; dt < 3; ++dt){
    #pragma unroll
    for (int ks = 0; ks < 5; ++ks){
      short8 afr[4], bfr[4];
      #pragma unroll
      for (int mg = 0; mg < 4; ++mg)
        afr[mg] = *(const short8*)((const char*)w1b +
            ((dt*128 + acol[mg])*160 + ks*32)*2 + kb);
      #pragma unroll
      for (int ng = 0; ng < 4; ++ng){
        const int row = brow[ng] + dt;
        int off = row*320 + ks*64 + kb; off ^= ((row&7)<<4);
        bfr[ng] = *(const short8*)(Bs + off);
      }
      #pragma unroll
      for (int mg = 0; mg < 4; ++mg)
        #pragma unroll
        for (int ng = 0; ng < 4; ++ng)
          acc[mg][ng] = __builtin_amdgcn_mfma_f32_16x16x32_bf16(
              afr[mg], bfr[ng], acc[mg][ng], 0, 0, 0);
    }
  }
  #pragma unroll
  for (int mg = 0; mg < 4; ++mg)
    #pragma unroll
    for (int j = 0; j < 4; ++j){
      const int cout = wr*64 + mg*16 + (lane>>4)*4 + j;
      const float bv = b1[cout];
      #pragma unroll
      for (int ng = 0; ng < 4; ++ng){
        const int col = wc*64 + ng*16 + (lane & 15);
        float v = acc[mg][ng][j] + bv; v = v > 0.f ? v : 0.f;
        h1[(size_t)cout*NW + colbase + col] = f2b(v);
      }
    }
}

// ---------------------------------------------------------------------------
// K3: enc2 MFMA GEMM, single-bf16 A (validated r23). h2 [64][NT2].
// ---------------------------------------------------------------------------
#define E2_LDS (160*256)
__global__ __launch_bounds__(256) void k_enc2_gemm(
    const bf16* __restrict__ h1, const bf16* __restrict__ w2b,
    const float* __restrict__ b2, bf16* __restrict__ h2)
{
  __shared__ __align__(16) char Bs[E2_LDS];
  const int tid = threadIdx.x, lane = tid & 63, wq = tid >> 6;
  const int n0 = blockIdx.x * 32;
  const int i  = n0 >> 13, b0 = n0 & 8191;
  const size_t colbase = (size_t)i*32768 + (size_t)b0*4;
  const size_t col2base = (size_t)i*16384 + (size_t)b0*2;

  for (int off = tid*16; off < E2_LDS; off += 256*16)
    *(f32x4*)(Bs + off) = f32x4{0.f,0.f,0.f,0.f};
  __syncthreads();
  for (int it = tid; it < 128*64; it += 256){
    const int cin = it >> 6, seg = it & 63;
    const unsigned int pair =
        *(const unsigned int*)(h1 + (size_t)cin*NW + colbase + seg*2);
    #pragma unroll
    for (int q = 0; q < 2; ++q){
      const int w = seg*2 + q;
      const int row = (w>>2)*5 + (w&3) + 1;
      int off = row*256 + cin*2; off ^= ((row&7)<<4);
      *(short*)(Bs + off) = (short)((q==0) ? (pair & 0xffff) : (pair >> 16));
    }
  }
  __syncthreads();

  const int wr = wq >> 1, wc = wq & 1;
  f32x4 acc[2][2];
  #pragma unroll
  for (int mg = 0; mg < 2; ++mg)
    #pragma unroll
    for (int ng = 0; ng < 2; ++ng) acc[mg][ng] = f32x4{0.f,0.f,0.f,0.f};

  int brow[2], acol[2];
  #pragma unroll
  for (int ng = 0; ng < 2; ++ng){
    const int wl = wc*32 + ng*16 + (lane & 15);
    brow[ng] = (wl>>1)*5 + (wl&1)*2;
  }
  #pragma unroll
  for (int mg = 0; mg < 2; ++mg) acol[mg] = wr*32 + mg*16 + (lane & 15);
  const int kb = (lane>>4)*16;

  for (int dt = 0; dt < 3; ++dt){
    #pragma unroll
    for (int ks = 0; ks < 4; ++ks){
      short8 afr[2], bfr[2];
      #pragma unroll
      for (int mg = 0; mg < 2; ++mg)
        afr[mg] = *(const short8*)((const char*)w2b +
            ((dt*64 + acol[mg])*128 + ks*32)*2 + kb);
      #pragma unroll
      for (int ng = 0; ng < 2; ++ng){
        const int row = brow[ng] + dt;
        int off = row*256 + ks*64 + kb; off ^= ((row&7)<<4);
        bfr[ng] = *(const short8*)(Bs + off);
      }
      #pragma unroll
      for (int mg = 0; mg < 2; ++mg)
        #pragma unroll
        for (int ng = 0; ng < 2; ++ng)
          acc[mg][ng] = __builtin_amdgcn_mfma_f32_16x16x32_bf16(
              afr[mg], bfr[ng], acc[mg][ng], 0, 0, 0);
    }
  }
  #pragma unroll
  for (int mg = 0; mg < 2; ++mg)
    #pragma unroll
    for (int j = 0; j < 4; ++j){
      const int cout = wr*32 + mg*16 + (lane>>4)*4 + j;
      const float bv = b2[cout];
      #pragma unroll
      for (int ng = 0; ng < 2; ++ng){
        const int col = wc*32 + ng*16 + (lane & 15);
        float v = acc[mg][ng][j] + bv; v = v > 0.f ? v : 0.f;
        h2[(size_t)cout*NT2 + col2base + col] = f2b(v);
      }
    }
}

// ---------------------------------------------------------------------------
// K4+K5 FUSED: enc3 -> enc4 MFMA, single-bf16 A (validated r23). h4 [128][NTOT].
// ---------------------------------------------------------------------------
__global__ __launch_bounds__(256) void k_enc34(
    const bf16* __restrict__ h2, const bf16* __restrict__ w3e,
    const float* __restrict__ b3, const bf16* __restrict__ w4e,
    const float* __restrict__ b4, bf16* __restrict__ h4)
{
  __shared__ __align__(16) char B1[64*256];       // 16 KB
  __shared__ __align__(16) char B2[64*128];       //  8 KB
  const int tid = threadIdx.x, lane = tid & 63, wq = tid >> 6;
  const int n0 = blockIdx.x * 64;                 // 1024 blocks

  for (int it = tid; it < 64*64; it += 256){
    const int cin = it >> 6, nl = it & 63;
    const int n = n0 + nl, i = n >> 13, b = n & 8191;
    const unsigned int pair =
        *(const unsigned int*)(h2 + (size_t)cin*NT2 + i*16384 + 2*b);
    int off = nl*256 + cin*4; off ^= ((nl&7)<<4);
    *(unsigned int*)(B1 + off) = pair;
  }
  __syncthreads();

  const int kb = (lane>>4)*16;
  f32x4 acc1[4];
  #pragma unroll
  for (int ng = 0; ng < 4; ++ng) acc1[ng] = f32x4{0.f,0.f,0.f,0.f};
  const int ar1 = wq*16 + (lane & 15);
  #pragma unroll
  for (int ks = 0; ks < 4; ++ks){
    const short8 a = *(const short8*)((const char*)w3e + (ar1*128 + ks*32)*2 + kb);
    #pragma unroll
    for (int ng = 0; ng < 4; ++ng){
      const int row = ng*16 + (lane & 15);
      int off = row*256 + ks*64 + kb; off ^= ((row&7)<<4);
      const short8 bfr = *(const short8*)(B1 + off);
      acc1[ng] = __builtin_amdgcn_mfma_f32_16x16x32_bf16(a, bfr, acc1[ng], 0, 0, 0);
    }
  }
  #pragma unroll
  for (int j = 0; j < 4; ++j){
    const int r1 = wq*16 + (lane>>4)*4 + j;
    const float bv = b3[r1];
    #pragma unroll
    for (int ng = 0; ng < 4; ++ng){
      const int col = ng*16 + (lane & 15);
      float v = acc1[ng][j] + bv; v = v > 0.f ? v : 0.f;
      int off = col*128 + r1*2; off ^= ((col&7)<<4);
      *(short*)(B2 + off) = f2bs(v);
    }
  }
  __syncthreads();

  f32x4 acc2[2][4];
  #pragma unroll
  for (int mg = 0; mg < 2; ++mg)
    #pragma unroll
    for (int ng = 0; ng < 4; ++ng) acc2[mg][ng] = f32x4{0.f,0.f,0.f,0.f};
  #pragma unroll
  for (int ks = 0; ks < 2; ++ks){
    short8 bfr[4];
    #pragma unroll
    for (int ng = 0; ng < 4; ++ng){
      const int row = ng*16 + (lane & 15);
      int off = row*128 + ks*64 + kb; off ^= ((row&7)<<4);
      bfr[ng] = *(const short8*)(B2 + off);
    }
    #pragma unroll
    for (int mg = 0; mg < 2; ++mg){
      const int ar2 = wq*32 + mg*16 + (lane & 15);
      const short8 a = *(const short8*)((const char*)w4e + (ar2*64 + ks*32)*2 + kb);
      #pragma unroll
      for (int ng = 0; ng < 4; ++ng)
        acc2[mg][ng] = __builtin_amdgcn_mfma_f32_16x16x32_bf16(a, bfr[ng], acc2[mg][ng], 0, 0, 0);
    }
  }
  #pragma unroll
  for (int mg = 0; mg < 2; ++mg)
    #pragma unroll
    for (int j = 0; j < 4; ++j){
      const int cout = wq*32 + mg*16 + (lane>>4)*4 + j;
      const float bv = b4[cout];
      #pragma unroll
      for (int ng = 0; ng < 4; ++ng){
        const int n = n0 + ng*16 + (lane & 15);
        float v = acc2[mg][ng][j] + bv; v = v > 0.f ? v : 0.f;
        h4[(size_t)cout*NTOT + n] = f2b(v);
      }
    }
}

// K6: transpose h0/c0 [B,128] -> [128][B]
__global__ __launch_bounds__(256) void k_init(
    const float* __restrict__ h0, const float* __restrict__ c0,
    float* __restrict__ hT0, float* __restrict__ cT)
{
  const int idx = blockIdx.x*256 + threadIdx.x;   // 1M
  const int b = idx >> 7, c = idx & 127;
  hT0[c*BATCH + b] = h0[idx];
  cT [c*BATCH + b] = c0[idx];
}

// ---------------------------------------------------------------------------
// K-GX: xg[512][32768] = Wih @ x for 4 steps (one half). Single-bf16 A.
// ---------------------------------------------------------------------------
__global__ __launch_bounds__(256) void k_gatex(
    const bf16* __restrict__ h4, const bf16* __restrict__ wlx,
    float* __restrict__ xg, int half)
{
  __shared__ __align__(16) char Bs[32*256];
  const int tid = threadIdx.x, lane = tid & 63, wq = tid >> 6;
  const int n0 = blockIdx.x * 32;
  const int gcol = half*32768 + n0;

  for (int it = tid; it < 128*32; it += 256){
    const int cp = it >> 5, nl = it & 31;
    const bf16 v = h4[(size_t)cp*NTOT + gcol + nl];
    int off = nl*256 + cp*2; off ^= ((nl&7)<<4);
    *(short*)(Bs + off) = *(const short*)&v;
  }
  __syncthreads();

  f32x4 acc[8][2];
  #pragma unroll
  for (int mg = 0; mg < 8; ++mg)
    #pragma unroll
    for (int ng = 0; ng < 2; ++ng) acc[mg][ng] = f32x4{0.f,0.f,0.f,0.f};

  int arow[8];
  #pragma unroll
  for (int mg = 0; mg < 8; ++mg) arow[mg] = wq*128 + mg*16 + (lane & 15);
  const int kb = (lane>>4)*16;

  #pragma unroll
  for (int ks = 0; ks < 4; ++ks){
    short8 bfr[2];
    #pragma unroll
    for (int ng = 0; ng < 2; ++ng){
      const int row = ng*16 + (lane & 15);
      int off = row*256 + ks*64 + kb; off ^= ((row&7)<<4);
      bfr[ng] = *(const short8*)(Bs + off);
    }
    #pragma unroll
    for (int mg = 0; mg < 8; ++mg){
      const short8 a = *(const short8*)((const char*)wlx +
          ((size_t)arow[mg]*128 + ks*32)*2 + kb);
      #pragma unroll
      for (int ng = 0; ng < 2; ++ng)
        acc[mg][ng] = __builtin_amdgcn_mfma_f32_16x16x32_bf16(
            a, bfr[ng], acc[mg][ng], 0, 0, 0);
    }
  }

  #pragma unroll
  for (int mg = 0; mg < 8; ++mg)
    #pragma unroll
    for (int j = 0; j < 4; ++j){
      const int row = wq*128 + mg*16 + (lane>>4)*4 + j;
      #pragma unroll
      for (int ng = 0; ng < 2; ++ng){
        const int col = n0 + ng*16 + (lane & 15);
        xg[(size_t)row*32768 + col] = acc[mg][ng][j];
      }
    }
}

// ---------------------------------------------------------------------------
// K7 v4 (r24): one recurrent LSTM step, single-bf16 Whh, K=128.
// Staging/read layout byte-identical to validated k_gatex (32x256 + XOR).
// 256 blocks x 32 batch cols.
// ---------------------------------------------------------------------------
__global__ __launch_bounds__(256) void k_lstm_rec(
    const float* __restrict__ xg, const bf16* __restrict__ wl1,
    const float* __restrict__ bih, const float* __restrict__ bhh,
    const float* __restrict__ hprev, float* __restrict__ hout,
    float* __restrict__ cT, int s)
{
  __shared__ __align__(16) char Bs[32*256];       // 8 KB
  const int tid = threadIdx.x, lane = tid & 63, wq = tid >> 6;
  const int b0 = blockIdx.x * 32;

  for (int it = tid; it < 128*32; it += 256){
    const int cp = it >> 5, bl = it & 31;
    const float v = hprev[cp*BATCH + b0 + bl];
    int off = bl*256 + cp*2; off ^= ((bl&7)<<4);
    *(short*)(Bs + off) = f2bs(v);
  }
  __syncthreads();

  const int c0r = wq*32;
  f32x4 acc[4][2][2];
  #pragma unroll
  for (int g = 0; g < 4; ++g)
    #pragma unroll
    for (int h = 0; h < 2; ++h)
      #pragma unroll
      for (int ng = 0; ng < 2; ++ng) acc[g][h][ng] = f32x4{0.f,0.f,0.f,0.f};

  int arow[4][2];
  #pragma unroll
  for (int g = 0; g < 4; ++g)
    #pragma unroll
    for (int h = 0; h < 2; ++h)
      arow[g][h] = (g*128 + c0r + h*16 + (lane&15))*256 + (lane>>4)*16;

  #pragma unroll
  for (int ks = 0; ks < 4; ++ks){
    short8 bfr[2];
    #pragma unroll
    for (int ng = 0; ng < 2; ++ng){
      const int row = ng*16 + (lane & 15);
      int off = row*256 + ks*64 + (lane>>4)*16; off ^= ((row&7)<<4);
      bfr[ng] = *(const short8*)(Bs + off);
    }
    #pragma unroll
    for (int g = 0; g < 4; ++g)
      #pragma unroll
      for (int h = 0; h < 2; ++h){
        const short8 a = *(const short8*)((const char*)wl1 + arow[g][h] + ks*64);
        #pragma unroll
        for (int ng = 0; ng < 2; ++ng)
          acc[g][h][ng] = __builtin_amdgcn_mfma_f32_16x16x32_bf16(
              a, bfr[ng], acc[g][h][ng], 0, 0, 0);
      }
  }

  const size_t xcolbase = (size_t)(s & 3)*8192 + b0;
  #pragma unroll
  for (int h = 0; h < 2; ++h)
    #pragma unroll
    for (int ng = 0; ng < 2; ++ng)
      #pragma unroll
      for (int j = 0; j < 4; ++j){
        const int c = c0r + h*16 + (lane>>4)*4 + j;
        const int b = b0 + ng*16 + (lane & 15);
        const size_t xc = xcolbase + ng*16 + (lane & 15);
        const float ig = acc[0][h][ng][j] + xg[(size_t)(0*128+c)*32768 + xc] + bih[c]       + bhh[c];
        const float fg = acc[1][h][ng][j] + xg[(size_t)(1*128+c)*32768 + xc] + bih[128 + c] + bhh[128 + c];
        const float gg = acc[2][h][ng][j] + xg[(size_t)(2*128+c)*32768 + xc] + bih[256 + c] + bhh[256 + c];
        const float og = acc[3][h][ng][j] + xg[(size_t)(3*128+c)*32768 + xc] + bih[384 + c] + bhh[384 + c];
        const float cold = cT[c*BATCH + b];
        const float cn = sigf(fg)*cold + sigf(ig)*tanhfast(gg);
        const float hn = sigf(og)*tanhfast(cn);
        cT  [c*BATCH + b] = cn;
        hout[c*BATCH + b] = hn;
      }
}

// K8a: P[s][b] = sigmoid(ow . hseq[s][:,b] + ob)
__global__ __launch_bounds__(256) void k_headp(
    const float* __restrict__ hseq, const float* __restrict__ ow,
    const float* __restrict__ ob, float* __restrict__ P)
{
  const int idx = blockIdx.x*256 + threadIdx.x;   // 65536
  const int s = idx >> 13, b = idx & (BATCH-1);
  const float* hp = hseq + (size_t)s*HID*BATCH;
  float acc = ob[0];
  for (int c = 0; c < 128; ++c) acc += ow[c]*hp[c*BATCH + b];
  P[s*BATCH + b] = sigf(acc);
}
// K8b: final = 1 - prod(1 - P[s])
__global__ __launch_bounds__(256) void k_head2(
    const float* __restrict__ P, float* __restrict__ outp)
{
  const int b = blockIdx.x*256 + threadIdx.x;     // 8192
  float prod = 1.f;
  #pragma unroll
  for (int s = 0; s < 8; ++s) prod *= (1.f - P[s*BATCH + b]);
  outp[b] = 1.f - prod;
}

// K9: transpose h_fin, c_fin to [B,128] in d_out
__global__ __launch_bounds__(256) void k_outT(
    const float* __restrict__ h7, const float* __restrict__ cT,
    float* __restrict__ out)
{
  const int idx = blockIdx.x*256 + threadIdx.x;   // 1M
  const int b = idx >> 7, c = idx & 127;
  out[8192 + idx]           = h7[c*BATCH + b];
  out[8192 + 1048576 + idx] = cT[c*BATCH + b];
}

// ---------------------------------------------------------------------------
extern "C" void kernel_launch(void* const* d_in, const int* in_sizes, int n_in,
                              void* d_out, int out_size, void* d_ws, size_t ws_size,
                              hipStream_t stream)
{
  (void)in_sizes; (void)n_in; (void)out_size; (void)ws_size;
  const float* audio = (const float*)d_in[0];
  const float* h0    = (const float*)d_in[1];
  const float* c0    = (const float*)d_in[2];
  const float* stftw = (const float*)d_in[3];
  const float* w1 = (const float*)d_in[4];  const float* b1 = (const float*)d_in[5];
  const float* w2 = (const float*)d_in[6];  const float* b2 = (const float*)d_in[7];
  const float* w3 = (const float*)d_in[8];  const float* b3 = (const float*)d_in[9];
  const float* w4 = (const float*)d_in[10]; const float* b4 = (const float*)d_in[11];
  const float* wih = (const float*)d_in[12]; const float* whh = (const float*)d_in[13];
  const float* bih = (const float*)d_in[14]; const float* bhh = (const float*)d_in[15];
  const float* ow  = (const float*)d_in[16]; const float* ob  = (const float*)d_in[17];
  float* out = (float*)d_out;

  // Workspace schedule (validated r18/r20/r23; wl1 replaces wl3, smaller):
  char* ws = (char*)d_ws;
  bf16*  mag  = (bf16*) (ws + 0);
  bf16*  w2b  = (bf16*) (ws + 0);
  bf16*  w3e  = (bf16*) (ws + 1048576);
  bf16*  w4e  = (bf16*) (ws + 1081344);
  bf16*  h4   = (bf16*) (ws + 8388608);
  float* xg   = (float*)(ws + 25165824);
  float* hseq = (float*)(ws + 92274688);
  float* hT0  = (float*)(ws + 125829120);
  float* cT   = (float*)(ws + 130023424);
  bf16*  h1   = (bf16*) (ws + 67633152);
  bf16*  Wbf  = (bf16*) (ws + 67633152);
  bf16*  h2   = (bf16*) (ws + 134742016);
  bf16*  w1b  = (bf16*) (ws + 134742016);
  bf16*  wl1  = (bf16*) (ws + 134742016);
  bf16*  wlx  = (bf16*) (ws + 135135232);
  float* Pbuf = (float*)(ws + 135397376);

  k_wcvt  <<<258, 256, 0, stream>>>(stftw, Wbf);
  k_w1cvt <<<240, 256, 0, stream>>>(w1, w1b);
  k_stft3<<<2048, 256, 0, stream>>>(audio, Wbf, mag);
  k_enc1_gemm<<<2048, 256, 0, stream>>>(mag, w1b, b1, h1);
  k_w2cvt <<<96, 256, 0, stream>>>(w2, w2b);            // after enc1: mag dead
  k_w34cvt<<<64, 256, 0, stream>>>(w3, w4, w3e, w4e);   // after enc1: mag dead
  k_enc2_gemm<<<2048, 256, 0, stream>>>(h1, w2b, b2, h2);
  k_init <<<4096, 256, 0, stream>>>(h0, c0, hT0, cT);   // after enc2: h1 dead
  k_enc34<<<1024, 256, 0, stream>>>(h2, w3e, b3, w4e, b4, h4);
  k_wlcvt1<<<256, 256, 0, stream>>>(whh, wl1);          // after enc34: h2 dead
  k_wlxcvt<<<256, 256, 0, stream>>>(wih, wlx);
  for (int half = 0; half < 2; ++half){
    k_gatex<<<1024, 256, 0, stream>>>(h4, wlx, xg, half);
    for (int q = 0; q < 4; ++q){
      const int s = half*4 + q;
      const float* hprev = (s == 0) ? hT0 : (hseq + (size_t)(s-1)*HID*BATCH);
      k_lstm_rec<<<256, 256, 0, stream>>>(xg, wl1, bih, bhh, hprev,
                                          hseq + (size_t)s*HID*BATCH, cT, s);
    }
  }
  k_headp<<<256, 256, 0, stream>>>(hseq, ow, ob, Pbuf);
  k_head2<<<32, 256, 0, stream>>>(Pbuf, out);
  k_outT<<<4096, 256, 0, stream>>>(hseq + (size_t)7*HID*BATCH, cT, out);
}

// Round 25
// 435.439 us; speedup vs baseline: 1.9533x; 1.0829x over previous
//
#include <hip/hip_runtime.h>
#include <hip/hip_bf16.h>
#include <math.h>

typedef __hip_bfloat16 bf16;
typedef __attribute__((ext_vector_type(4))) float f32x4;
typedef __attribute__((ext_vector_type(8))) short short8;
typedef __attribute__((ext_vector_type(4))) short short4v;

#define BATCH   8192
#define NTOT    65536      // 8 chunks * BATCH
#define NW      262144     // 8 chunks * 4 frames * BATCH
#define HID     128

__device__ __forceinline__ float b2f(bf16 v){ return __bfloat162float(v); }
__device__ __forceinline__ bf16  f2b(float v){ return __float2bfloat16(v); }
__device__ __forceinline__ short f2bs(float v){
  bf16 b = __float2bfloat16(v);
  return *reinterpret_cast<short*>(&b);
}
__device__ __forceinline__ float sigf(float x){ return 1.0f/(1.0f+__expf(-x)); }
__device__ __forceinline__ float tanhfast(float x){
  return 1.0f - 2.0f/(__expf(2.0f*x)+1.0f);
}

// ---------------------------------------------------------------------------
// Weight conversion — ALL single bf16 (validated r23/r24).
// ---------------------------------------------------------------------------
__global__ __launch_bounds__(256) void k_wcvt(        // stft W -> bf16 [258][256]
    const float* __restrict__ W, bf16* __restrict__ Wb)
{
  const int idx = blockIdx.x*256 + threadIdx.x;
  if (idx < 258*256) Wb[idx] = f2b(W[idx]);
}
__global__ __launch_bounds__(256) void k_w1cvt(       // w1 -> [3][128][160] bf16
    const float* __restrict__ w1, bf16* __restrict__ w1b)
{
  const int idx = blockIdx.x*256 + threadIdx.x;       // 61440
  if (idx >= 61440) return;
  const int dt = idx / 20480, rem = idx % 20480;
  const int cout = rem / 160, k = rem % 160;
  const float v = (k < 129) ? w1[(cout*129 + k)*3 + dt] : 0.f;
  w1b[idx] = f2b(v);
}
__global__ __launch_bounds__(256) void k_w2cvt(       // w2 -> [3][64][128] bf16
    const float* __restrict__ w2, bf16* __restrict__ w2b)
{
  const int idx = blockIdx.x*256 + threadIdx.x;       // 24576
  if (idx >= 24576) return;
  const int dt = idx >> 13, cout = (idx >> 7) & 63, k = idx & 127;
  w2b[idx] = f2b(w2[(cout*128 + k)*3 + dt]);
}
// enc3 taps 1,2 -> w3e[64][128]; enc4 center -> w4e[128][64]
__global__ __launch_bounds__(256) void k_w34cvt(
    const float* __restrict__ w3, const float* __restrict__ w4,
    bf16* __restrict__ w3e, bf16* __restrict__ w4e)
{
  const int idx = blockIdx.x*256 + threadIdx.x;       // 16384
  if (idx >= 16384) return;
  if (idx < 8192){
    const int row = idx >> 7, k = idx & 127;
    const int cin = k >> 1, t = k & 1;
    w3e[idx] = f2b(w3[(row*64 + cin)*3 + 1 + t]);
  } else {
    const int i2 = idx - 8192;
    const int row = i2 >> 6, cin = i2 & 63;
    w4e[i2] = f2b(w4[(row*64 + cin)*3 + 1]);
  }
}
__global__ __launch_bounds__(256) void k_wlcvt1(      // Whh [512][128]
    const float* __restrict__ whh, bf16* __restrict__ wl1)
{
  const int idx = blockIdx.x*256 + threadIdx.x;       // 65536
  if (idx >= 65536) return;
  wl1[idx] = f2b(whh[idx]);
}
__global__ __launch_bounds__(256) void k_wlxcvt(      // Wih [512][128]
    const float* __restrict__ wih, bf16* __restrict__ wlx)
{
  const int idx = blockIdx.x*256 + threadIdx.x;       // 65536
  if (idx >= 65536) return;
  wlx[idx] = f2b(wih[idx]);
}

// ---------------------------------------------------------------------------
// K1 v5 (validated r19): STFT MFMA GEMM, per-pass A-tile staged in LDS.
// mag [129][NW].
// ---------------------------------------------------------------------------
__global__ __launch_bounds__(256) void k_stft3(
    const float* __restrict__ audio, const bf16* __restrict__ Wb,
    bf16* __restrict__ mag)
{
  __shared__ __align__(16) char ALDS[96*512];      // 48 KB
  __shared__ __align__(16) bf16 refl[4*8*64];      // 4 KB
  const int tid = threadIdx.x, lane = tid & 63, wq = tid >> 6;
  const int r0 = blockIdx.x * 4;                   // 2048 blocks
  const float* arow = audio + (size_t)(r0 + wq) * 4160;

  #pragma unroll
  for (int q = 0; q < 8; ++q){
    const int e = q*64 + lane;
    const int i = e >> 6, k = e & 63;
    refl[(wq*8 + i)*64 + k] = f2b(arow[512*i + 64 - k]);
  }

  const int kgo8 = (lane>>4)*8;
  short8 Bfrag[2][8];
  #pragma unroll
  for (int ng = 0; ng < 2; ++ng){
    const int wl = ng*16 + (lane & 15);
    const int i = wl >> 2, t = wl & 3;
    #pragma unroll
    for (int ks = 0; ks < 8; ++ks){
      const int kb = ks*32 + kgo8;
      if (t == 0 && kb < 64){
        Bfrag[ng][ks] = *(const short8*)(refl + (wq*8 + i)*64 + kb);
      } else {
        const float* src = arow + 512*i + 128*t - 64 + kb;
        const float4 v0 = *(const float4*)(src);
        const float4 v1 = *(const float4*)(src + 4);
        short8 s;
        s[0]=f2bs(v0.x); s[1]=f2bs(v0.y); s[2]=f2bs(v0.z); s[3]=f2bs(v0.w);
        s[4]=f2bs(v1.x); s[5]=f2bs(v1.y); s[6]=f2bs(v1.z); s[7]=f2bs(v1.w);
        Bfrag[ng][ks] = s;
      }
    }
  }

  const int kab = (lane>>4)*16;
  for (int pass = 0; pass < 3; ++pass){
    __syncthreads();
    for (int idx = tid; idx < 96*32; idx += 256){
      const int ar = idx >> 5;
      const int cb = (idx & 31) * 16;
      const int b3 = ar >> 5, reim = (ar >> 4) & 1, bl = ar & 15;
      int bin = pass*48 + b3*16 + bl;
      if (bin > 128) bin = 128;
      const int grow = bin + reim*129;
      int off = ar*512 + cb; off ^= ((ar&7)<<4);
      *(f32x4*)(ALDS + off) = *(const f32x4*)((const char*)Wb + grow*512 + cb);
    }
    __syncthreads();

    f32x4 accRe[3][2], accIm[3][2];
    #pragma unroll
    for (int b3 = 0; b3 < 3; ++b3)
      #pragma unroll
      for (int ng = 0; ng < 2; ++ng){
        accRe[b3][ng] = f32x4{0.f,0.f,0.f,0.f};
        accIm[b3][ng] = f32x4{0.f,0.f,0.f,0.f};
      }
    #pragma unroll
    for (int ks = 0; ks < 8; ++ks){
      #pragma unroll
      for (int b3 = 0; b3 < 3; ++b3){
        const int arRe = b3*32 + (lane & 15);
        const int arIm = arRe + 16;
        int offRe = arRe*512 + ks*64 + kab; offRe ^= ((arRe&7)<<4);
        int offIm = arIm*512 + ks*64 + kab; offIm ^= ((arIm&7)<<4);
        const short8 aRe = *(const short8*)(ALDS + offRe);
        const short8 aIm = *(const short8*)(ALDS + offIm);
        #pragma unroll
        for (int ng = 0; ng < 2; ++ng){
          accRe[b3][ng] = __builtin_amdgcn_mfma_f32_16x16x32_bf16(
              aRe, Bfrag[ng][ks], accRe[b3][ng], 0, 0, 0);
          accIm[b3][ng] = __builtin_amdgcn_mfma_f32_16x16x32_bf16(
              aIm, Bfrag[ng][ks], accIm[b3][ng], 0, 0, 0);
        }
      }
    }
    #pragma unroll
    for (int b3 = 0; b3 < 3; ++b3)
      #pragma unroll
      for (int j = 0; j < 4; ++j){
        const int bin = (pass*3 + b3)*16 + (lane>>4)*4 + j;
        if (bin <= 128){
          #pragma unroll
          for (int ng = 0; ng < 2; ++ng){
            const int wl = ng*16 + (lane & 15);
            const int i = wl >> 2, t = wl & 3;
            const float re = accRe[b3][ng][j], im = accIm[b3][ng][j];
            mag[(size_t)bin*NW + (size_t)i*32768 + (r0+wq)*4 + t] =
                f2b(sqrtf(re*re + im*im));
          }
        }
      }
  }
}

// ---------------------------------------------------------------------------
// K2 FUSED (r25): enc1 -> enc2 -> enc3 -> enc4 in one kernel, chained
// through LDS. Block = 32 n (2048 blocks). Phase layouts are byte-level
// copies of the validated enc1/enc2/enc34 kernels; only the epilogue->LDS
// write maps are new (each is the inverse of a validated staging map).
// LDS aliasing: Bs1[0,61440) phase1; Bs2[0,40960), B3[40960,49152),
// B4[49152,53248) later — all barrier-separated, over dead Bs1.
// h4 [128][NTOT].
// ---------------------------------------------------------------------------
#define E1_LDS (192*320)
__global__ __launch_bounds__(256) void k_enc1234(
    const bf16* __restrict__ mag,
    const bf16* __restrict__ w1b, const float* __restrict__ b1,
    const bf16* __restrict__ w2b, const float* __restrict__ b2,
    const bf16* __restrict__ w3e, const float* __restrict__ b3,
    const bf16* __restrict__ w4e, const float* __restrict__ b4,
    bf16* __restrict__ h4)
{
  __shared__ __align__(16) char Bs[E1_LDS];       // 60 KB
  char* const B3 = Bs + 40960;
  char* const B4 = Bs + 49152;
  const int tid = threadIdx.x, lane = tid & 63, wq = tid >> 6;
  const int n0 = blockIdx.x * 32;
  const int i  = n0 >> 13, b0 = n0 & 8191;
  const size_t colbase = (size_t)i*32768 + (size_t)b0*4;
  const int kb = (lane>>4)*16;
  const int wr = wq >> 1, wc = wq & 1;

  // ---- Phase 1: mag im2col -> Bs1 (validated enc1 staging) ----
  for (int off = tid*16; off < E1_LDS; off += 256*16)
    *(f32x4*)(Bs + off) = f32x4{0.f,0.f,0.f,0.f};
  __syncthreads();
  for (int it = tid; it < 129*64; it += 256){
    const int cin = it >> 6, seg = it & 63;
    const unsigned int pair =
        *(const unsigned int*)(mag + (size_t)cin*NW + colbase + seg*2);
    #pragma unroll
    for (int q = 0; q < 2; ++q){
      const int w = seg*2 + q;
      const int row = (w>>2)*6 + (w&3) + 1;
      int off = row*320 + cin*2; off ^= ((row&7)<<4);
      *(short*)(Bs + off) = (short)((q==0) ? (pair & 0xffff) : (pair >> 16));
    }
  }
  __syncthreads();

  // ---- enc1 MFMA (validated r23 single-bf16 A) ----
  f32x4 acc1[4][4];
  #pragma unroll
  for (int mg = 0; mg < 4; ++mg)
    #pragma unroll
    for (int ng = 0; ng < 4; ++ng) acc1[mg][ng] = f32x4{0.f,0.f,0.f,0.f};
  int brow[4], acol[4];
  #pragma unroll
  for (int ng = 0; ng < 4; ++ng){
    const int w = wc*64 + ng*16 + (lane & 15);
    brow[ng] = (w>>2)*6 + (w&3);
  }
  #pragma unroll
  for (int mg = 0; mg < 4; ++mg) acol[mg] = wr*64 + mg*16 + (lane & 15);

  for (int dt = 0; dt < 3; ++dt){
    #pragma unroll
    for (int ks = 0; ks < 5; ++ks){
      short8 afr[4], bfr[4];
      #pragma unroll
      for (int mg = 0; mg < 4; ++mg)
        afr[mg] = *(const short8*)((const char*)w1b +
            ((dt*128 + acol[mg])*160 + ks*32)*2 + kb);
      #pragma unroll
      for (int ng = 0; ng < 4; ++ng){
        const int row = brow[ng] + dt;
        int off = row*320 + ks*64 + kb; off ^= ((row&7)<<4);
        bfr[ng] = *(const short8*)(Bs + off);
      }
      #pragma unroll
      for (int mg = 0; mg < 4; ++mg)
        #pragma unroll
        for (int ng = 0; ng < 4; ++ng)
          acc1[mg][ng] = __builtin_amdgcn_mfma_f32_16x16x32_bf16(
              afr[mg], bfr[ng], acc1[mg][ng], 0, 0, 0);
    }
  }
  __syncthreads();                                // all Bs1 reads done

  // ---- Phase 2: h1 -> Bs2 (inverse of validated enc2 staging map) ----
  // zero pad rows (row5 = nloc*5): disjoint from h1 data rows, no race
  for (int it = tid; it < 32*16; it += 256){
    const int nloc = it >> 4, cb = (it & 15)*16;
    *(f32x4*)(Bs + (nloc*5)*256 + cb) = f32x4{0.f,0.f,0.f,0.f};
  }
  #pragma unroll
  for (int mg = 0; mg < 4; ++mg)
    #pragma unroll
    for (int j = 0; j < 4; ++j){
      const int cout = wr*64 + mg*16 + (lane>>4)*4 + j;
      const float bv = b1[cout];
      #pragma unroll
      for (int ng = 0; ng < 4; ++ng){
        const int w = wc*64 + ng*16 + (lane & 15);
        float v = acc1[mg][ng][j] + bv; v = v > 0.f ? v : 0.f;
        const int row5 = (w>>2)*5 + (w&3) + 1;
        int off = row5*256 + cout*2; off ^= ((row5&7)<<4);
        *(short*)(Bs + off) = f2bs(v);
      }
    }
  __syncthreads();

  // ---- enc2 MFMA (validated r23) ----
  f32x4 acc2[2][2];
  #pragma unroll
  for (int mg = 0; mg < 2; ++mg)
    #pragma unroll
    for (int ng = 0; ng < 2; ++ng) acc2[mg][ng] = f32x4{0.f,0.f,0.f,0.f};
  int brow2[2], acol2[2];
  #pragma unroll
  for (int ng = 0; ng < 2; ++ng){
    const int wl = wc*32 + ng*16 + (lane & 15);
    brow2[ng] = (wl>>1)*5 + (wl&1)*2;
  }
  #pragma unroll
  for (int mg = 0; mg < 2; ++mg) acol2[mg] = wr*32 + mg*16 + (lane & 15);

  for (int dt = 0; dt < 3; ++dt){
    #pragma unroll
    for (int ks = 0; ks < 4; ++ks){
      short8 afr[2], bfr[2];
      #pragma unroll
      for (int mg = 0; mg < 2; ++mg)
        afr[mg] = *(const short8*)((const char*)w2b +
            ((dt*64 + acol2[mg])*128 + ks*32)*2 + kb);
      #pragma unroll
      for (int ng = 0; ng < 2; ++ng){
        const int row = brow2[ng] + dt;
        int off = row*256 + ks*64 + kb; off ^= ((row&7)<<4);
        bfr[ng] = *(const short8*)(Bs + off);
      }
      #pragma unroll
      for (int mg = 0; mg < 2; ++mg)
        #pragma unroll
        for (int ng = 0; ng < 2; ++ng)
          acc2[mg][ng] = __builtin_amdgcn_mfma_f32_16x16x32_bf16(
              afr[mg], bfr[ng], acc2[mg][ng], 0, 0, 0);
    }
  }

  // ---- Phase 3: h2 -> B3 (validated enc34-B1 layout [32 n][128 k]) ----
  // B3 region = dead Bs1 tail; disjoint from Bs2 -> no pre-sync needed
  #pragma unroll
  for (int mg = 0; mg < 2; ++mg)
    #pragma unroll
    for (int j = 0; j < 4; ++j){
      const int cout2 = wr*32 + mg*16 + (lane>>4)*4 + j;
      const float bv = b2[cout2];
      #pragma unroll
      for (int ng = 0; ng < 2; ++ng){
        const int wl = wc*32 + ng*16 + (lane & 15);
        float v = acc2[mg][ng][j] + bv; v = v > 0.f ? v : 0.f;
        const int nloc = wl >> 1, tp = wl & 1;
        int off = nloc*256 + (cout2*2 + tp)*2; off ^= ((nloc&7)<<4);
        *(short*)(B3 + off) = f2bs(v);
      }
    }
  __syncthreads();

  // ---- enc3 MFMA (validated enc34 GEMM1, N=32) ----
  f32x4 acc3[2];
  acc3[0] = f32x4{0.f,0.f,0.f,0.f};
  acc3[1] = f32x4{0.f,0.f,0.f,0.f};
  const int ar1 = wq*16 + (lane & 15);
  #pragma unroll
  for (int ks = 0; ks < 4; ++ks){
    const short8 a = *(const short8*)((const char*)w3e + (ar1*128 + ks*32)*2 + kb);
    #pragma unroll
    for (int ng = 0; ng < 2; ++ng){
      const int row = ng*16 + (lane & 15);
      int off = row*256 + ks*64 + kb; off ^= ((row&7)<<4);
      const short8 bfr = *(const short8*)(B3 + off);
      acc3[ng] = __builtin_amdgcn_mfma_f32_16x16x32_bf16(a, bfr, acc3[ng], 0, 0, 0);
    }
  }

  // ---- Phase 4: h3 -> B4 (validated enc34-B2 layout [32 n][64 k]) ----
  #pragma unroll
  for (int j = 0; j < 4; ++j){
    const int r1 = wq*16 + (lane>>4)*4 + j;
    const float bv = b3[r1];
    #pragma unroll
    for (int ng = 0; ng < 2; ++ng){
      const int col = ng*16 + (lane & 15);
      float v = acc3[ng][j] + bv; v = v > 0.f ? v : 0.f;
      int off = col*128 + r1*2; off ^= ((col&7)<<4);
      *(short*)(B4 + off) = f2bs(v);
    }
  }
  __syncthreads();

  // ---- enc4 MFMA (validated enc34 GEMM2, N=32) + h4 store ----
  f32x4 acc4[2][2];
  #pragma unroll
  for (int mg = 0; mg < 2; ++mg)
    #pragma unroll
    for (int ng = 0; ng < 2; ++ng) acc4[mg][ng] = f32x4{0.f,0.f,0.f,0.f};
  #pragma unroll
  for (int ks = 0; ks < 2; ++ks){
    short8 bfr[2];
    #pragma unroll
    for (int ng = 0; ng < 2; ++ng){
      const int row = ng*16 + (lane & 15);
      int off = row*128 + ks*64 + kb; off ^= ((row&7)<<4);
      bfr[ng] = *(const short8*)(B4 + off);
    }
    #pragma unroll
    for (int mg = 0; mg < 2; ++mg){
      const int ar2 = wq*32 + mg*16 + (lane & 15);
      const short8 a = *(const short8*)((const char*)w4e + (ar2*64 + ks*32)*2 + kb);
      #pragma unroll
      for (int ng = 0; ng < 2; ++ng)
        acc4[mg][ng] = __builtin_amdgcn_mfma_f32_16x16x32_bf16(a, bfr[ng], acc4[mg][ng], 0, 0, 0);
    }
  }
  #pragma unroll
  for (int mg = 0; mg < 2; ++mg)
    #pragma unroll
    for (int j = 0; j < 4; ++j){
      const int cout = wq*32 + mg*16 + (lane>>4)*4 + j;
      const float bv = b4[cout];
      #pragma unroll
      for (int ng = 0; ng < 2; ++ng){
        const int n = n0 + ng*16 + (lane & 15);
        float v = acc4[mg][ng][j] + bv; v = v > 0.f ? v : 0.f;
        h4[(size_t)cout*NTOT + n] = f2b(v);
      }
    }
}

// K6: transpose h0/c0 [B,128] -> [128][B]
__global__ __launch_bounds__(256) void k_init(
    const float* __restrict__ h0, const float* __restrict__ c0,
    float* __restrict__ hT0, float* __restrict__ cT)
{
  const int idx = blockIdx.x*256 + threadIdx.x;   // 1M
  const int b = idx >> 7, c = idx & 127;
  hT0[c*BATCH + b] = h0[idx];
  cT [c*BATCH + b] = c0[idx];
}

// ---------------------------------------------------------------------------
// K-GX: xg[512][32768] = Wih @ x for 4 steps (one half). Single-bf16 A.
// ---------------------------------------------------------------------------
__global__ __launch_bounds__(256) void k_gatex(
    const bf16* __restrict__ h4, const bf16* __restrict__ wlx,
    float* __restrict__ xg, int half)
{
  __shared__ __align__(16) char Bs[32*256];
  const int tid = threadIdx.x, lane = tid & 63, wq = tid >> 6;
  const int n0 = blockIdx.x * 32;
  const int gcol = half*32768 + n0;

  for (int it = tid; it < 128*32; it += 256){
    const int cp = it >> 5, nl = it & 31;
    const bf16 v = h4[(size_t)cp*NTOT + gcol + nl];
    int off = nl*256 + cp*2; off ^= ((nl&7)<<4);
    *(short*)(Bs + off) = *(const short*)&v;
  }
  __syncthreads();

  f32x4 acc[8][2];
  #pragma unroll
  for (int mg = 0; mg < 8; ++mg)
    #pragma unroll
    for (int ng = 0; ng < 2; ++ng) acc[mg][ng] = f32x4{0.f,0.f,0.f,0.f};

  int arow[8];
  #pragma unroll
  for (int mg = 0; mg < 8; ++mg) arow[mg] = wq*128 + mg*16 + (lane & 15);
  const int kb = (lane>>4)*16;

  #pragma unroll
  for (int ks = 0; ks < 4; ++ks){
    short8 bfr[2];
    #pragma unroll
    for (int ng = 0; ng < 2; ++ng){
      const int row = ng*16 + (lane & 15);
      int off = row*256 + ks*64 + kb; off ^= ((row&7)<<4);
      bfr[ng] = *(const short8*)(Bs + off);
    }
    #pragma unroll
    for (int mg = 0; mg < 8; ++mg){
      const short8 a = *(const short8*)((const char*)wlx +
          ((size_t)arow[mg]*128 + ks*32)*2 + kb);
      #pragma unroll
      for (int ng = 0; ng < 2; ++ng)
        acc[mg][ng] = __builtin_amdgcn_mfma_f32_16x16x32_bf16(
            a, bfr[ng], acc[mg][ng], 0, 0, 0);
    }
  }

  #pragma unroll
  for (int mg = 0; mg < 8; ++mg)
    #pragma unroll
    for (int j = 0; j < 4; ++j){
      const int row = wq*128 + mg*16 + (lane>>4)*4 + j;
      #pragma unroll
      for (int ng = 0; ng < 2; ++ng){
        const int col = n0 + ng*16 + (lane & 15);
        xg[(size_t)row*32768 + col] = acc[mg][ng][j];
      }
    }
}

// ---------------------------------------------------------------------------
// K7 (validated r24): one recurrent LSTM step, single-bf16 Whh, K=128.
// 256 blocks x 32 batch cols.
// ---------------------------------------------------------------------------
__global__ __launch_bounds__(256) void k_lstm_rec(
    const float* __restrict__ xg, const bf16* __restrict__ wl1,
    const float* __restrict__ bih, const float* __restrict__ bhh,
    const float* __restrict__ hprev, float* __restrict__ hout,
    float* __restrict__ cT, int s)
{
  __shared__ __align__(16) char Bs[32*256];       // 8 KB
  const int tid = threadIdx.x, lane = tid & 63, wq = tid >> 6;
  const int b0 = blockIdx.x * 32;

  for (int it = tid; it < 128*32; it += 256){
    const int cp = it >> 5, bl = it & 31;
    const float v = hprev[cp*BATCH + b0 + bl];
    int off = bl*256 + cp*2; off ^= ((bl&7)<<4);
    *(short*)(Bs + off) = f2bs(v);
  }
  __syncthreads();

  const int c0r = wq*32;
  f32x4 acc[4][2][2];
  #pragma unroll
  for (int g = 0; g < 4; ++g)
    #pragma unroll
    for (int h = 0; h < 2; ++h)
      #pragma unroll
      for (int ng = 0; ng < 2; ++ng) acc[g][h][ng] = f32x4{0.f,0.f,0.f,0.f};

  int arow[4][2];
  #pragma unroll
  for (int g = 0; g < 4; ++g)
    #pragma unroll
    for (int h = 0; h < 2; ++h)
      arow[g][h] = (g*128 + c0r + h*16 + (lane&15))*256 + (lane>>4)*16;

  #pragma unroll
  for (int ks = 0; ks < 4; ++ks){
    short8 bfr[2];
    #pragma unroll
    for (int ng = 0; ng < 2; ++ng){
      const int row = ng*16 + (lane & 15);
      int off = row*256 + ks*64 + (lane>>4)*16; off ^= ((row&7)<<4);
      bfr[ng] = *(const short8*)(Bs + off);
    }
    #pragma unroll
    for (int g = 0; g < 4; ++g)
      #pragma unroll
      for (int h = 0; h < 2; ++h){
        const short8 a = *(const short8*)((const char*)wl1 + arow[g][h] + ks*64);
        #pragma unroll
        for (int ng = 0; ng < 2; ++ng)
          acc[g][h][ng] = __builtin_amdgcn_mfma_f32_16x16x32_bf16(
              a, bfr[ng], acc[g][h][ng], 0, 0, 0);
      }
  }

  const size_t xcolbase = (size_t)(s & 3)*8192 + b0;
  #pragma unroll
  for (int h = 0; h < 2; ++h)
    #pragma unroll
    for (int ng = 0; ng < 2; ++ng)
      #pragma unroll
      for (int j = 0; j < 4; ++j){
        const int c = c0r + h*16 + (lane>>4)*4 + j;
        const int b = b0 + ng*16 + (lane & 15);
        const size_t xc = xcolbase + ng*16 + (lane & 15);
        const float ig = acc[0][h][ng][j] + xg[(size_t)(0*128+c)*32768 + xc] + bih[c]       + bhh[c];
        const float fg = acc[1][h][ng][j] + xg[(size_t)(1*128+c)*32768 + xc] + bih[128 + c] + bhh[128 + c];
        const float gg = acc[2][h][ng][j] + xg[(size_t)(2*128+c)*32768 + xc] + bih[256 + c] + bhh[256 + c];
        const float og = acc[3][h][ng][j] + xg[(size_t)(3*128+c)*32768 + xc] + bih[384 + c] + bhh[384 + c];
        const float cold = cT[c*BATCH + b];
        const float cn = sigf(fg)*cold + sigf(ig)*tanhfast(gg);
        const float hn = sigf(og)*tanhfast(cn);
        cT  [c*BATCH + b] = cn;
        hout[c*BATCH + b] = hn;
      }
}

// K8a: P[s][b] = sigmoid(ow . hseq[s][:,b] + ob)
__global__ __launch_bounds__(256) void k_headp(
    const float* __restrict__ hseq, const float* __restrict__ ow,
    const float* __restrict__ ob, float* __restrict__ P)
{
  const int idx = blockIdx.x*256 + threadIdx.x;   // 65536
  const int s = idx >> 13, b = idx & (BATCH-1);
  const float* hp = hseq + (size_t)s*HID*BATCH;
  float acc = ob[0];
  for (int c = 0; c < 128; ++c) acc += ow[c]*hp[c*BATCH + b];
  P[s*BATCH + b] = sigf(acc);
}
// K8b: final = 1 - prod(1 - P[s])
__global__ __launch_bounds__(256) void k_head2(
    const float* __restrict__ P, float* __restrict__ outp)
{
  const int b = blockIdx.x*256 + threadIdx.x;     // 8192
  float prod = 1.f;
  #pragma unroll
  for (int s = 0; s < 8; ++s) prod *= (1.f - P[s*BATCH + b]);
  outp[b] = 1.f - prod;
}

// K9: transpose h_fin, c_fin to [B,128] in d_out
__global__ __launch_bounds__(256) void k_outT(
    const float* __restrict__ h7, const float* __restrict__ cT,
    float* __restrict__ out)
{
  const int idx = blockIdx.x*256 + threadIdx.x;   // 1M
  const int b = idx >> 7, c = idx & 127;
  out[8192 + idx]           = h7[c*BATCH + b];
  out[8192 + 1048576 + idx] = cT[c*BATCH + b];
}

// ---------------------------------------------------------------------------
extern "C" void kernel_launch(void* const* d_in, const int* in_sizes, int n_in,
                              void* d_out, int out_size, void* d_ws, size_t ws_size,
                              hipStream_t stream)
{
  (void)in_sizes; (void)n_in; (void)out_size; (void)ws_size;
  const float* audio = (const float*)d_in[0];
  const float* h0    = (const float*)d_in[1];
  const float* c0    = (const float*)d_in[2];
  const float* stftw = (const float*)d_in[3];
  const float* w1 = (const float*)d_in[4];  const float* b1 = (const float*)d_in[5];
  const float* w2 = (const float*)d_in[6];  const float* b2 = (const float*)d_in[7];
  const float* w3 = (const float*)d_in[8];  const float* b3 = (const float*)d_in[9];
  const float* w4 = (const float*)d_in[10]; const float* b4 = (const float*)d_in[11];
  const float* wih = (const float*)d_in[12]; const float* whh = (const float*)d_in[13];
  const float* bih = (const float*)d_in[14]; const float* bhh = (const float*)d_in[15];
  const float* ow  = (const float*)d_in[16]; const float* ob  = (const float*)d_in[17];
  float* out = (float*)d_out;

  // Workspace schedule (r25 re-audit; all weights cvt'd at t0 into
  // [134,742,016..135,208,960) — touched by nothing else; mag live t1->t2):
  //   t1 stft3:   mag  [0 .. 67,633,152)      reads Wbf@67,633,152 (dead after)
  //   t2 enc1234: h4   [67,633,152 .. 84,410,368)  (over dead Wbf)  reads mag
  //   t3 gatex:   xg   [0 .. 67,108,864)      (over dead mag)       reads h4
  //   t4 rec:     hseq [92,274,688 .. 125,829,120); hT0@125,829,120 cT@130,023,424
  //   t5 head:    Pbuf @135,397,376
  char* ws = (char*)d_ws;
  bf16*  Wbf  = (bf16*) (ws + 67633152);
  bf16*  h4   = (bf16*) (ws + 67633152);
  bf16*  mag  = (bf16*) (ws + 0);
  float* xg   = (float*)(ws + 0);
  float* hseq = (float*)(ws + 92274688);
  float* hT0  = (float*)(ws + 125829120);
  float* cT   = (float*)(ws + 130023424);
  bf16*  w1b  = (bf16*) (ws + 134742016);   // +122,880
  bf16*  w2b  = (bf16*) (ws + 134864896);   // +49,152
  bf16*  w3e  = (bf16*) (ws + 134914048);   // +16,384
  bf16*  w4e  = (bf16*) (ws + 134930432);   // +16,384 -> 134,946,816
  bf16*  wl1  = (bf16*) (ws + 134946816);   // +131,072
  bf16*  wlx  = (bf16*) (ws + 135077888);   // +131,072 -> 135,208,960
  float* Pbuf = (float*)(ws + 135397376);   // +262,144

  k_wcvt  <<<258, 256, 0, stream>>>(stftw, Wbf);
  k_w1cvt <<<240, 256, 0, stream>>>(w1, w1b);
  k_w2cvt <<<96, 256, 0, stream>>>(w2, w2b);
  k_w34cvt<<<64, 256, 0, stream>>>(w3, w4, w3e, w4e);
  k_wlcvt1<<<256, 256, 0, stream>>>(whh, wl1);
  k_wlxcvt<<<256, 256, 0, stream>>>(wih, wlx);
  k_init  <<<4096, 256, 0, stream>>>(h0, c0, hT0, cT);
  k_stft3<<<2048, 256, 0, stream>>>(audio, Wbf, mag);
  k_enc1234<<<2048, 256, 0, stream>>>(mag, w1b, b1, w2b, b2, w3e, b3,
                                      w4e, b4, h4);
  for (int half = 0; half < 2; ++half){
    k_gatex<<<1024, 256, 0, stream>>>(h4, wlx, xg, half);
    for (int q = 0; q < 4; ++q){
      const int s = half*4 + q;
      const float* hprev = (s == 0) ? hT0 : (hseq + (size_t)(s-1)*HID*BATCH);
      k_lstm_rec<<<256, 256, 0, stream>>>(xg, wl1, bih, bhh, hprev,
                                          hseq + (size_t)s*HID*BATCH, cT, s);
    }
  }
  k_headp<<<256, 256, 0, stream>>>(hseq, ow, ob, Pbuf);
  k_head2<<<32, 256, 0, stream>>>(Pbuf, out);
  k_outT<<<4096, 256, 0, stream>>>(hseq + (size_t)7*HID*BATCH, cT, out);
}

// Round 26
// 430.000 us; speedup vs baseline: 1.9780x; 1.0126x over previous
//
#include <hip/hip_runtime.h>
#include <hip/hip_bf16.h>
#include <math.h>

typedef __hip_bfloat16 bf16;
typedef __attribute__((ext_vector_type(4))) float f32x4;
typedef __attribute__((ext_vector_type(8))) short short8;
typedef __attribute__((ext_vector_type(4))) short short4v;

#define BATCH   8192
#define NTOT    65536      // 8 chunks * BATCH
#define NW      262144     // 8 chunks * 4 frames * BATCH
#define HID     128

__device__ __forceinline__ float b2f(bf16 v){ return __bfloat162float(v); }
__device__ __forceinline__ bf16  f2b(float v){ return __float2bfloat16(v); }
__device__ __forceinline__ short f2bs(float v){
  bf16 b = __float2bfloat16(v);
  return *reinterpret_cast<short*>(&b);
}
__device__ __forceinline__ float sigf(float x){ return 1.0f/(1.0f+__expf(-x)); }
__device__ __forceinline__ float tanhfast(float x){
  return 1.0f - 2.0f/(__expf(2.0f*x)+1.0f);
}

// ---------------------------------------------------------------------------
// Weight conversion — ALL single bf16 (validated r23/r24).
// ---------------------------------------------------------------------------
__global__ __launch_bounds__(256) void k_wcvt(        // stft W -> bf16 [258][256]
    const float* __restrict__ W, bf16* __restrict__ Wb)
{
  const int idx = blockIdx.x*256 + threadIdx.x;
  if (idx < 258*256) Wb[idx] = f2b(W[idx]);
}
__global__ __launch_bounds__(256) void k_w1cvt(       // w1 -> [3][128][160] bf16
    const float* __restrict__ w1, bf16* __restrict__ w1b)
{
  const int idx = blockIdx.x*256 + threadIdx.x;       // 61440
  if (idx >= 61440) return;
  const int dt = idx / 20480, rem = idx % 20480;
  const int cout = rem / 160, k = rem % 160;
  const float v = (k < 129) ? w1[(cout*129 + k)*3 + dt] : 0.f;
  w1b[idx] = f2b(v);
}
__global__ __launch_bounds__(256) void k_w2cvt(       // w2 -> [3][64][128] bf16
    const float* __restrict__ w2, bf16* __restrict__ w2b)
{
  const int idx = blockIdx.x*256 + threadIdx.x;       // 24576
  if (idx >= 24576) return;
  const int dt = idx >> 13, cout = (idx >> 7) & 63, k = idx & 127;
  w2b[idx] = f2b(w2[(cout*128 + k)*3 + dt]);
}
// enc3 taps 1,2 -> w3e[64][128]; enc4 center -> w4e[128][64]
__global__ __launch_bounds__(256) void k_w34cvt(
    const float* __restrict__ w3, const float* __restrict__ w4,
    bf16* __restrict__ w3e, bf16* __restrict__ w4e)
{
  const int idx = blockIdx.x*256 + threadIdx.x;       // 16384
  if (idx >= 16384) return;
  if (idx < 8192){
    const int row = idx >> 7, k = idx & 127;
    const int cin = k >> 1, t = k & 1;
    w3e[idx] = f2b(w3[(row*64 + cin)*3 + 1 + t]);
  } else {
    const int i2 = idx - 8192;
    const int row = i2 >> 6, cin = i2 & 63;
    w4e[i2] = f2b(w4[(row*64 + cin)*3 + 1]);
  }
}
__global__ __launch_bounds__(256) void k_wlcvt1(      // Whh [512][128]
    const float* __restrict__ whh, bf16* __restrict__ wl1)
{
  const int idx = blockIdx.x*256 + threadIdx.x;       // 65536
  if (idx >= 65536) return;
  wl1[idx] = f2b(whh[idx]);
}
__global__ __launch_bounds__(256) void k_wlxcvt(      // Wih [512][128]
    const float* __restrict__ wih, bf16* __restrict__ wlx)
{
  const int idx = blockIdx.x*256 + threadIdx.x;       // 65536
  if (idx >= 65536) return;
  wlx[idx] = f2b(wih[idx]);
}

// ---------------------------------------------------------------------------
// K1 v5 (validated r19): STFT MFMA GEMM, per-pass A-tile staged in LDS.
// mag [129][NW].
// ---------------------------------------------------------------------------
__global__ __launch_bounds__(256) void k_stft3(
    const float* __restrict__ audio, const bf16* __restrict__ Wb,
    bf16* __restrict__ mag)
{
  __shared__ __align__(16) char ALDS[96*512];      // 48 KB
  __shared__ __align__(16) bf16 refl[4*8*64];      // 4 KB
  const int tid = threadIdx.x, lane = tid & 63, wq = tid >> 6;
  const int r0 = blockIdx.x * 4;                   // 2048 blocks
  const float* arow = audio + (size_t)(r0 + wq) * 4160;

  #pragma unroll
  for (int q = 0; q < 8; ++q){
    const int e = q*64 + lane;
    const int i = e >> 6, k = e & 63;
    refl[(wq*8 + i)*64 + k] = f2b(arow[512*i + 64 - k]);
  }

  const int kgo8 = (lane>>4)*8;
  short8 Bfrag[2][8];
  #pragma unroll
  for (int ng = 0; ng < 2; ++ng){
    const int wl = ng*16 + (lane & 15);
    const int i = wl >> 2, t = wl & 3;
    #pragma unroll
    for (int ks = 0; ks < 8; ++ks){
      const int kb = ks*32 + kgo8;
      if (t == 0 && kb < 64){
        Bfrag[ng][ks] = *(const short8*)(refl + (wq*8 + i)*64 + kb);
      } else {
        const float* src = arow + 512*i + 128*t - 64 + kb;
        const float4 v0 = *(const float4*)(src);
        const float4 v1 = *(const float4*)(src + 4);
        short8 s;
        s[0]=f2bs(v0.x); s[1]=f2bs(v0.y); s[2]=f2bs(v0.z); s[3]=f2bs(v0.w);
        s[4]=f2bs(v1.x); s[5]=f2bs(v1.y); s[6]=f2bs(v1.z); s[7]=f2bs(v1.w);
        Bfrag[ng][ks] = s;
      }
    }
  }

  const int kab = (lane>>4)*16;
  for (int pass = 0; pass < 3; ++pass){
    __syncthreads();
    for (int idx = tid; idx < 96*32; idx += 256){
      const int ar = idx >> 5;
      const int cb = (idx & 31) * 16;
      const int b3 = ar >> 5, reim = (ar >> 4) & 1, bl = ar & 15;
      int bin = pass*48 + b3*16 + bl;
      if (bin > 128) bin = 128;
      const int grow = bin + reim*129;
      int off = ar*512 + cb; off ^= ((ar&7)<<4);
      *(f32x4*)(ALDS + off) = *(const f32x4*)((const char*)Wb + grow*512 + cb);
    }
    __syncthreads();

    f32x4 accRe[3][2], accIm[3][2];
    #pragma unroll
    for (int b3 = 0; b3 < 3; ++b3)
      #pragma unroll
      for (int ng = 0; ng < 2; ++ng){
        accRe[b3][ng] = f32x4{0.f,0.f,0.f,0.f};
        accIm[b3][ng] = f32x4{0.f,0.f,0.f,0.f};
      }
    #pragma unroll
    for (int ks = 0; ks < 8; ++ks){
      #pragma unroll
      for (int b3 = 0; b3 < 3; ++b3){
        const int arRe = b3*32 + (lane & 15);
        const int arIm = arRe + 16;
        int offRe = arRe*512 + ks*64 + kab; offRe ^= ((arRe&7)<<4);
        int offIm = arIm*512 + ks*64 + kab; offIm ^= ((arIm&7)<<4);
        const short8 aRe = *(const short8*)(ALDS + offRe);
        const short8 aIm = *(const short8*)(ALDS + offIm);
        #pragma unroll
        for (int ng = 0; ng < 2; ++ng){
          accRe[b3][ng] = __builtin_amdgcn_mfma_f32_16x16x32_bf16(
              aRe, Bfrag[ng][ks], accRe[b3][ng], 0, 0, 0);
          accIm[b3][ng] = __builtin_amdgcn_mfma_f32_16x16x32_bf16(
              aIm, Bfrag[ng][ks], accIm[b3][ng], 0, 0, 0);
        }
      }
    }
    #pragma unroll
    for (int b3 = 0; b3 < 3; ++b3)
      #pragma unroll
      for (int j = 0; j < 4; ++j){
        const int bin = (pass*3 + b3)*16 + (lane>>4)*4 + j;
        if (bin <= 128){
          #pragma unroll
          for (int ng = 0; ng < 2; ++ng){
            const int wl = ng*16 + (lane & 15);
            const int i = wl >> 2, t = wl & 3;
            const float re = accRe[b3][ng][j], im = accIm[b3][ng][j];
            mag[(size_t)bin*NW + (size_t)i*32768 + (r0+wq)*4 + t] =
                f2b(sqrtf(re*re + im*im));
          }
        }
      }
  }
}

// ---------------------------------------------------------------------------
// K2 FUSED (validated r25): enc1 -> enc2 -> enc3 -> enc4, chained via LDS.
// h4 [128][NTOT].
// ---------------------------------------------------------------------------
#define E1_LDS (192*320)
__global__ __launch_bounds__(256) void k_enc1234(
    const bf16* __restrict__ mag,
    const bf16* __restrict__ w1b, const float* __restrict__ b1,
    const bf16* __restrict__ w2b, const float* __restrict__ b2,
    const bf16* __restrict__ w3e, const float* __restrict__ b3,
    const bf16* __restrict__ w4e, const float* __restrict__ b4,
    bf16* __restrict__ h4)
{
  __shared__ __align__(16) char Bs[E1_LDS];       // 60 KB
  char* const B3 = Bs + 40960;
  char* const B4 = Bs + 49152;
  const int tid = threadIdx.x, lane = tid & 63, wq = tid >> 6;
  const int n0 = blockIdx.x * 32;
  const int i  = n0 >> 13, b0 = n0 & 8191;
  const size_t colbase = (size_t)i*32768 + (size_t)b0*4;
  const int kb = (lane>>4)*16;
  const int wr = wq >> 1, wc = wq & 1;

  for (int off = tid*16; off < E1_LDS; off += 256*16)
    *(f32x4*)(Bs + off) = f32x4{0.f,0.f,0.f,0.f};
  __syncthreads();
  for (int it = tid; it < 129*64; it += 256){
    const int cin = it >> 6, seg = it & 63;
    const unsigned int pair =
        *(const unsigned int*)(mag + (size_t)cin*NW + colbase + seg*2);
    #pragma unroll
    for (int q = 0; q < 2; ++q){
      const int w = seg*2 + q;
      const int row = (w>>2)*6 + (w&3) + 1;
      int off = row*320 + cin*2; off ^= ((row&7)<<4);
      *(short*)(Bs + off) = (short)((q==0) ? (pair & 0xffff) : (pair >> 16));
    }
  }
  __syncthreads();

  f32x4 acc1[4][4];
  #pragma unroll
  for (int mg = 0; mg < 4; ++mg)
    #pragma unroll
    for (int ng = 0; ng < 4; ++ng) acc1[mg][ng] = f32x4{0.f,0.f,0.f,0.f};
  int brow[4], acol[4];
  #pragma unroll
  for (int ng = 0; ng < 4; ++ng){
    const int w = wc*64 + ng*16 + (lane & 15);
    brow[ng] = (w>>2)*6 + (w&3);
  }
  #pragma unroll
  for (int mg = 0; mg < 4; ++mg) acol[mg] = wr*64 + mg*16 + (lane & 15);

  for (int dt = 0; dt < 3; ++dt){
    #pragma unroll
    for (int ks = 0; ks < 5; ++ks){
      short8 afr[4], bfr[4];
      #pragma unroll
      for (int mg = 0; mg < 4; ++mg)
        afr[mg] = *(const short8*)((const char*)w1b +
            ((dt*128 + acol[mg])*160 + ks*32)*2 + kb);
      #pragma unroll
      for (int ng = 0; ng < 4; ++ng){
        const int row = brow[ng] + dt;
        int off = row*320 + ks*64 + kb; off ^= ((row&7)<<4);
        bfr[ng] = *(const short8*)(Bs + off);
      }
      #pragma unroll
      for (int mg = 0; mg < 4; ++mg)
        #pragma unroll
        for (int ng = 0; ng < 4; ++ng)
          acc1[mg][ng] = __builtin_amdgcn_mfma_f32_16x16x32_bf16(
              afr[mg], bfr[ng], acc1[mg][ng], 0, 0, 0);
    }
  }
  __syncthreads();

  for (int it = tid; it < 32*16; it += 256){
    const int nloc = it >> 4, cb = (it & 15)*16;
    *(f32x4*)(Bs + (nloc*5)*256 + cb) = f32x4{0.f,0.f,0.f,0.f};
  }
  #pragma unroll
  for (int mg = 0; mg < 4; ++mg)
    #pragma unroll
    for (int j = 0; j < 4; ++j){
      const int cout = wr*64 + mg*16 + (lane>>4)*4 + j;
      const float bv = b1[cout];
      #pragma unroll
      for (int ng = 0; ng < 4; ++ng){
        const int w = wc*64 + ng*16 + (lane & 15);
        float v = acc1[mg][ng][j] + bv; v = v > 0.f ? v : 0.f;
        const int row5 = (w>>2)*5 + (w&3) + 1;
        int off = row5*256 + cout*2; off ^= ((row5&7)<<4);
        *(short*)(Bs + off) = f2bs(v);
      }
    }
  __syncthreads();

  f32x4 acc2[2][2];
  #pragma unroll
  for (int mg = 0; mg < 2; ++mg)
    #pragma unroll
    for (int ng = 0; ng < 2; ++ng) acc2[mg][ng] = f32x4{0.f,0.f,0.f,0.f};
  int brow2[2], acol2[2];
  #pragma unroll
  for (int ng = 0; ng < 2; ++ng){
    const int wl = wc*32 + ng*16 + (lane & 15);
    brow2[ng] = (wl>>1)*5 + (wl&1)*2;
  }
  #pragma unroll
  for (int mg = 0; mg < 2; ++mg) acol2[mg] = wr*32 + mg*16 + (lane & 15);

  for (int dt = 0; dt < 3; ++dt){
    #pragma unroll
    for (int ks = 0; ks < 4; ++ks){
      short8 afr[2], bfr[2];
      #pragma unroll
      for (int mg = 0; mg < 2; ++mg)
        afr[mg] = *(const short8*)((const char*)w2b +
            ((dt*64 + acol2[mg])*128 + ks*32)*2 + kb);
      #pragma unroll
      for (int ng = 0; ng < 2; ++ng){
        const int row = brow2[ng] + dt;
        int off = row*256 + ks*64 + kb; off ^= ((row&7)<<4);
        bfr[ng] = *(const short8*)(Bs + off);
      }
      #pragma unroll
      for (int mg = 0; mg < 2; ++mg)
        #pragma unroll
        for (int ng = 0; ng < 2; ++ng)
          acc2[mg][ng] = __builtin_amdgcn_mfma_f32_16x16x32_bf16(
              afr[mg], bfr[ng], acc2[mg][ng], 0, 0, 0);
    }
  }

  #pragma unroll
  for (int mg = 0; mg < 2; ++mg)
    #pragma unroll
    for (int j = 0; j < 4; ++j){
      const int cout2 = wr*32 + mg*16 + (lane>>4)*4 + j;
      const float bv = b2[cout2];
      #pragma unroll
      for (int ng = 0; ng < 2; ++ng){
        const int wl = wc*32 + ng*16 + (lane & 15);
        float v = acc2[mg][ng][j] + bv; v = v > 0.f ? v : 0.f;
        const int nloc = wl >> 1, tp = wl & 1;
        int off = nloc*256 + (cout2*2 + tp)*2; off ^= ((nloc&7)<<4);
        *(short*)(B3 + off) = f2bs(v);
      }
    }
  __syncthreads();

  f32x4 acc3[2];
  acc3[0] = f32x4{0.f,0.f,0.f,0.f};
  acc3[1] = f32x4{0.f,0.f,0.f,0.f};
  const int ar1 = wq*16 + (lane & 15);
  #pragma unroll
  for (int ks = 0; ks < 4; ++ks){
    const short8 a = *(const short8*)((const char*)w3e + (ar1*128 + ks*32)*2 + kb);
    #pragma unroll
    for (int ng = 0; ng < 2; ++ng){
      const int row = ng*16 + (lane & 15);
      int off = row*256 + ks*64 + kb; off ^= ((row&7)<<4);
      const short8 bfr = *(const short8*)(B3 + off);
      acc3[ng] = __builtin_amdgcn_mfma_f32_16x16x32_bf16(a, bfr, acc3[ng], 0, 0, 0);
    }
  }

  #pragma unroll
  for (int j = 0; j < 4; ++j){
    const int r1 = wq*16 + (lane>>4)*4 + j;
    const float bv = b3[r1];
    #pragma unroll
    for (int ng = 0; ng < 2; ++ng){
      const int col = ng*16 + (lane & 15);
      float v = acc3[ng][j] + bv; v = v > 0.f ? v : 0.f;
      int off = col*128 + r1*2; off ^= ((col&7)<<4);
      *(short*)(B4 + off) = f2bs(v);
    }
  }
  __syncthreads();

  f32x4 acc4[2][2];
  #pragma unroll
  for (int mg = 0; mg < 2; ++mg)
    #pragma unroll
    for (int ng = 0; ng < 2; ++ng) acc4[mg][ng] = f32x4{0.f,0.f,0.f,0.f};
  #pragma unroll
  for (int ks = 0; ks < 2; ++ks){
    short8 bfr[2];
    #pragma unroll
    for (int ng = 0; ng < 2; ++ng){
      const int row = ng*16 + (lane & 15);
      int off = row*128 + ks*64 + kb; off ^= ((row&7)<<4);
      bfr[ng] = *(const short8*)(B4 + off);
    }
    #pragma unroll
    for (int mg = 0; mg < 2; ++mg){
      const int ar2 = wq*32 + mg*16 + (lane & 15);
      const short8 a = *(const short8*)((const char*)w4e + (ar2*64 + ks*32)*2 + kb);
      #pragma unroll
      for (int ng = 0; ng < 2; ++ng)
        acc4[mg][ng] = __builtin_amdgcn_mfma_f32_16x16x32_bf16(a, bfr[ng], acc4[mg][ng], 0, 0, 0);
    }
  }
  #pragma unroll
  for (int mg = 0; mg < 2; ++mg)
    #pragma unroll
    for (int j = 0; j < 4; ++j){
      const int cout = wq*32 + mg*16 + (lane>>4)*4 + j;
      const float bv = b4[cout];
      #pragma unroll
      for (int ng = 0; ng < 2; ++ng){
        const int n = n0 + ng*16 + (lane & 15);
        float v = acc4[mg][ng][j] + bv; v = v > 0.f ? v : 0.f;
        h4[(size_t)cout*NTOT + n] = f2b(v);
      }
    }
}

// ---------------------------------------------------------------------------
// K-GX (r26: xg row stride 65536, both halves live): xg[512][65536] = Wih @ x.
// ---------------------------------------------------------------------------
__global__ __launch_bounds__(256) void k_gatex(
    const bf16* __restrict__ h4, const bf16* __restrict__ wlx,
    float* __restrict__ xg, int half)
{
  __shared__ __align__(16) char Bs[32*256];
  const int tid = threadIdx.x, lane = tid & 63, wq = tid >> 6;
  const int n0 = blockIdx.x * 32;
  const int gcol = half*32768 + n0;

  for (int it = tid; it < 128*32; it += 256){
    const int cp = it >> 5, nl = it & 31;
    const bf16 v = h4[(size_t)cp*NTOT + gcol + nl];
    int off = nl*256 + cp*2; off ^= ((nl&7)<<4);
    *(short*)(Bs + off) = *(const short*)&v;
  }
  __syncthreads();

  f32x4 acc[8][2];
  #pragma unroll
  for (int mg = 0; mg < 8; ++mg)
    #pragma unroll
    for (int ng = 0; ng < 2; ++ng) acc[mg][ng] = f32x4{0.f,0.f,0.f,0.f};

  int arow[8];
  #pragma unroll
  for (int mg = 0; mg < 8; ++mg) arow[mg] = wq*128 + mg*16 + (lane & 15);
  const int kb = (lane>>4)*16;

  #pragma unroll
  for (int ks = 0; ks < 4; ++ks){
    short8 bfr[2];
    #pragma unroll
    for (int ng = 0; ng < 2; ++ng){
      const int row = ng*16 + (lane & 15);
      int off = row*256 + ks*64 + kb; off ^= ((row&7)<<4);
      bfr[ng] = *(const short8*)(Bs + off);
    }
    #pragma unroll
    for (int mg = 0; mg < 8; ++mg){
      const short8 a = *(const short8*)((const char*)wlx +
          ((size_t)arow[mg]*128 + ks*32)*2 + kb);
      #pragma unroll
      for (int ng = 0; ng < 2; ++ng)
        acc[mg][ng] = __builtin_amdgcn_mfma_f32_16x16x32_bf16(
            a, bfr[ng], acc[mg][ng], 0, 0, 0);
    }
  }

  #pragma unroll
  for (int mg = 0; mg < 8; ++mg)
    #pragma unroll
    for (int j = 0; j < 4; ++j){
      const int row = wq*128 + mg*16 + (lane>>4)*4 + j;
      #pragma unroll
      for (int ng = 0; ng < 2; ++ng){
        const int col = gcol + ng*16 + (lane & 15);
        xg[(size_t)row*65536 + col] = acc[mg][ng][j];
      }
    }
}

// ---------------------------------------------------------------------------
// K7 FUSED (r26): all 8 LSTM steps + head + outputs in one kernel.
// 256 blocks x 32 batch cols. h lives in LDS across steps (r11-validated
// write-back pattern, r24-validated 32x256 XOR layout); c in registers;
// MFMA core = r24 lstm_rec verbatim; head logic = r11 k_lstm_all verbatim.
// Writes probs + h_fin + c_fin directly to d_out.
// ---------------------------------------------------------------------------
__global__ __launch_bounds__(256) void k_lstm_all2(
    const float* __restrict__ xg, const bf16* __restrict__ wl1,
    const float* __restrict__ bih, const float* __restrict__ bhh,
    const float* __restrict__ h0, const float* __restrict__ c0,
    const float* __restrict__ ow, const float* __restrict__ ob,
    float* __restrict__ out)
{
  __shared__ __align__(16) char Bs[32*256];       // 8 KB h tile
  __shared__ float Ppart[16*32];
  __shared__ float Pprod[32];
  const int tid = threadIdx.x, lane = tid & 63, wq = tid >> 6;
  const int b0 = blockIdx.x * 32;
  const int c0r = wq*32;

  // stage initial h from h0 [b,c]
  for (int it = tid; it < 128*32; it += 256){
    const int cp = it >> 5, bl = it & 31;
    const float v = h0[(size_t)(b0 + bl)*128 + cp];
    int off = bl*256 + cp*2; off ^= ((bl&7)<<4);
    *(short*)(Bs + off) = f2bs(v);
  }
  // per-thread constants + c state
  float cst[2][2][4], bsum[4][2][4], owv[2][4];
  #pragma unroll
  for (int h = 0; h < 2; ++h)
    #pragma unroll
    for (int j = 0; j < 4; ++j){
      const int c = c0r + h*16 + (lane>>4)*4 + j;
      owv[h][j] = ow[c];
      #pragma unroll
      for (int g = 0; g < 4; ++g)
        bsum[g][h][j] = bih[g*128 + c] + bhh[g*128 + c];
      #pragma unroll
      for (int ng = 0; ng < 2; ++ng)
        cst[h][ng][j] = c0[(size_t)(b0 + ng*16 + (lane & 15))*128 + c];
    }
  if (tid < 32) Pprod[tid] = 1.f;
  const float obv = ob[0];

  int arow[4][2];
  #pragma unroll
  for (int g = 0; g < 4; ++g)
    #pragma unroll
    for (int h = 0; h < 2; ++h)
      arow[g][h] = (g*128 + c0r + h*16 + (lane&15))*256 + (lane>>4)*16;

  __syncthreads();                                // h0 + Pprod visible

  for (int s = 0; s < 8; ++s){
    // ---- MFMA phase (r24 verbatim) ----
    f32x4 acc[4][2][2];
    #pragma unroll
    for (int g = 0; g < 4; ++g)
      #pragma unroll
      for (int h = 0; h < 2; ++h)
        #pragma unroll
        for (int ng = 0; ng < 2; ++ng) acc[g][h][ng] = f32x4{0.f,0.f,0.f,0.f};
    #pragma unroll
    for (int ks = 0; ks < 4; ++ks){
      short8 bfr[2];
      #pragma unroll
      for (int ng = 0; ng < 2; ++ng){
        const int row = ng*16 + (lane & 15);
        int off = row*256 + ks*64 + (lane>>4)*16; off ^= ((row&7)<<4);
        bfr[ng] = *(const short8*)(Bs + off);
      }
      #pragma unroll
      for (int g = 0; g < 4; ++g)
        #pragma unroll
        for (int h = 0; h < 2; ++h){
          const short8 a = *(const short8*)((const char*)wl1 + arow[g][h] + ks*64);
          #pragma unroll
          for (int ng = 0; ng < 2; ++ng)
            acc[g][h][ng] = __builtin_amdgcn_mfma_f32_16x16x32_bf16(
                a, bfr[ng], acc[g][h][ng], 0, 0, 0);
        }
    }
    __syncthreads();                              // Bs reads done (+ prev reduce)

    // ---- pointwise + h write-back + P partials ----
    float psum0 = 0.f, psum1 = 0.f;
    #pragma unroll
    for (int h = 0; h < 2; ++h)
      #pragma unroll
      for (int ng = 0; ng < 2; ++ng)
        #pragma unroll
        for (int j = 0; j < 4; ++j){
          const int c = c0r + h*16 + (lane>>4)*4 + j;
          const int b = b0 + ng*16 + (lane & 15);
          const size_t xc = (size_t)s*8192 + b;
          const float ig = acc[0][h][ng][j] + xg[(size_t)(0*128+c)*65536 + xc] + bsum[0][h][j];
          const float fg = acc[1][h][ng][j] + xg[(size_t)(1*128+c)*65536 + xc] + bsum[1][h][j];
          const float gg = acc[2][h][ng][j] + xg[(size_t)(2*128+c)*65536 + xc] + bsum[2][h][j];
          const float og = acc[3][h][ng][j] + xg[(size_t)(3*128+c)*65536 + xc] + bsum[3][h][j];
          const float cn = sigf(fg)*cst[h][ng][j] + sigf(ig)*tanhfast(gg);
          const float hn = sigf(og)*tanhfast(cn);
          cst[h][ng][j] = cn;
          const float pw = owv[h][j] * hn;
          if (ng == 0) psum0 += pw; else psum1 += pw;
          const int bl = ng*16 + (lane & 15);
          int off = bl*256 + c*2; off ^= ((bl&7)<<4);
          *(short*)(Bs + off) = f2bs(hn);
          if (s == 7){
            out[8192 + (size_t)b*128 + c]           = hn;
            out[8192 + 1048576 + (size_t)b*128 + c] = cn;
          }
        }
    Ppart[(wq*4 + (lane>>4))*32 + (lane & 15)]      = psum0;
    Ppart[(wq*4 + (lane>>4))*32 + 16 + (lane & 15)] = psum1;
    __syncthreads();                              // h + Ppart visible
    if (tid < 32){
      float a2 = obv;
      #pragma unroll
      for (int q2 = 0; q2 < 16; ++q2) a2 += Ppart[q2*32 + tid];
      Pprod[tid] *= (1.f - sigf(a2));
    }
  }
  if (tid < 32) out[b0 + tid] = 1.f - Pprod[tid];
}

// ---------------------------------------------------------------------------
extern "C" void kernel_launch(void* const* d_in, const int* in_sizes, int n_in,
                              void* d_out, int out_size, void* d_ws, size_t ws_size,
                              hipStream_t stream)
{
  (void)in_sizes; (void)n_in; (void)out_size; (void)ws_size;
  const float* audio = (const float*)d_in[0];
  const float* h0    = (const float*)d_in[1];
  const float* c0    = (const float*)d_in[2];
  const float* stftw = (const float*)d_in[3];
  const float* w1 = (const float*)d_in[4];  const float* b1 = (const float*)d_in[5];
  const float* w2 = (const float*)d_in[6];  const float* b2 = (const float*)d_in[7];
  const float* w3 = (const float*)d_in[8];  const float* b3 = (const float*)d_in[9];
  const float* w4 = (const float*)d_in[10]; const float* b4 = (const float*)d_in[11];
  const float* wih = (const float*)d_in[12]; const float* whh = (const float*)d_in[13];
  const float* bih = (const float*)d_in[14]; const float* bhh = (const float*)d_in[15];
  const float* ow  = (const float*)d_in[16]; const float* ob  = (const float*)d_in[17];
  float* out = (float*)d_out;

  // Workspace schedule (r26 re-audit):
  //   xg   [0 .. 134,217,728)            written t3 (gatex), read t4
  //   mag  [0 .. 67,633,152)             inside xg; live t1(stft)->t2(enc1234)
  //   h4   [134,217,728 .. 150,994,944)  written t2, read t3
  //   Wbf  [134,217,728 .. +132,096)     inside h4 slot; live t0->t1 (dead
  //                                      before h4 written at t2)
  //   w1b  @150,994,944 (+122,880) w2b @151,117,824 (+49,152)
  //   w3e  @151,166,976 (+16,384)  w4e @151,183,360 (+16,384)
  //   wl1  @151,199,744 (+131,072) wlx @151,330,816 (+131,072) -> 151,461,888
  char* ws = (char*)d_ws;
  float* xg   = (float*)(ws + 0);
  bf16*  mag  = (bf16*) (ws + 0);
  bf16*  h4   = (bf16*) (ws + 134217728);
  bf16*  Wbf  = (bf16*) (ws + 134217728);
  bf16*  w1b  = (bf16*) (ws + 150994944);
  bf16*  w2b  = (bf16*) (ws + 151117824);
  bf16*  w3e  = (bf16*) (ws + 151166976);
  bf16*  w4e  = (bf16*) (ws + 151183360);
  bf16*  wl1  = (bf16*) (ws + 151199744);
  bf16*  wlx  = (bf16*) (ws + 151330816);

  k_wcvt  <<<258, 256, 0, stream>>>(stftw, Wbf);
  k_w1cvt <<<240, 256, 0, stream>>>(w1, w1b);
  k_w2cvt <<<96, 256, 0, stream>>>(w2, w2b);
  k_w34cvt<<<64, 256, 0, stream>>>(w3, w4, w3e, w4e);
  k_wlcvt1<<<256, 256, 0, stream>>>(whh, wl1);
  k_wlxcvt<<<256, 256, 0, stream>>>(wih, wlx);
  k_stft3<<<2048, 256, 0, stream>>>(audio, Wbf, mag);
  k_enc1234<<<2048, 256, 0, stream>>>(mag, w1b, b1, w2b, b2, w3e, b3,
                                      w4e, b4, h4);
  k_gatex<<<1024, 256, 0, stream>>>(h4, wlx, xg, 0);
  k_gatex<<<1024, 256, 0, stream>>>(h4, wlx, xg, 1);
  k_lstm_all2<<<256, 256, 0, stream>>>(xg, wl1, bih, bhh, h0, c0, ow, ob, out);
}

// Round 27
// 428.663 us; speedup vs baseline: 1.9842x; 1.0031x over previous
//
#include <hip/hip_runtime.h>
#include <hip/hip_bf16.h>
#include <math.h>

typedef __hip_bfloat16 bf16;
typedef __attribute__((ext_vector_type(4))) float f32x4;
typedef __attribute__((ext_vector_type(8))) short short8;
typedef __attribute__((ext_vector_type(4))) short short4v;

#define BATCH   8192
#define NTOT    65536      // 8 chunks * BATCH
#define NW      262144     // 8 chunks * 4 frames * BATCH
#define HID     128

__device__ __forceinline__ float b2f(bf16 v){ return __bfloat162float(v); }
__device__ __forceinline__ bf16  f2b(float v){ return __float2bfloat16(v); }
__device__ __forceinline__ short f2bs(float v){
  bf16 b = __float2bfloat16(v);
  return *reinterpret_cast<short*>(&b);
}
__device__ __forceinline__ float sigf(float x){ return 1.0f/(1.0f+__expf(-x)); }
__device__ __forceinline__ float tanhfast(float x){
  return 1.0f - 2.0f/(__expf(2.0f*x)+1.0f);
}

// ---------------------------------------------------------------------------
// K0 (r27): ALL weight conversions in ONE kernel (range dispatch).
// Layouts identical to validated r23/r24 converters.
// ---------------------------------------------------------------------------
__global__ __launch_bounds__(256) void k_allcvt(
    const float* __restrict__ stftw, const float* __restrict__ w1,
    const float* __restrict__ w2, const float* __restrict__ w3,
    const float* __restrict__ w4, const float* __restrict__ whh,
    const float* __restrict__ wih,
    bf16* __restrict__ Wbf, bf16* __restrict__ w1b, bf16* __restrict__ w2b,
    bf16* __restrict__ w3e, bf16* __restrict__ w4e, bf16* __restrict__ wl1,
    bf16* __restrict__ wlx)
{
  int idx = blockIdx.x*256 + threadIdx.x;         // total 299,520
  if (idx < 66048){ Wbf[idx] = f2b(stftw[idx]); return; }
  idx -= 66048;
  if (idx < 61440){                               // w1 -> [3][128][160]
    const int dt = idx / 20480, rem = idx % 20480;
    const int cout = rem / 160, k = rem % 160;
    const float v = (k < 129) ? w1[(cout*129 + k)*3 + dt] : 0.f;
    w1b[idx] = f2b(v); return;
  }
  idx -= 61440;
  if (idx < 24576){                               // w2 -> [3][64][128]
    const int dt = idx >> 13, cout = (idx >> 7) & 63, k = idx & 127;
    w2b[idx] = f2b(w2[(cout*128 + k)*3 + dt]); return;
  }
  idx -= 24576;
  if (idx < 8192){                                // w3e[64][128]
    const int row = idx >> 7, k = idx & 127;
    const int cin = k >> 1, t = k & 1;
    w3e[idx] = f2b(w3[(row*64 + cin)*3 + 1 + t]); return;
  }
  idx -= 8192;
  if (idx < 8192){                                // w4e[128][64]
    const int row = idx >> 6, cin = idx & 63;
    w4e[idx] = f2b(w4[(row*64 + cin)*3 + 1]); return;
  }
  idx -= 8192;
  if (idx < 65536){ wl1[idx] = f2b(whh[idx]); return; }
  idx -= 65536;
  if (idx < 65536){ wlx[idx] = f2b(wih[idx]); return; }
}

// ---------------------------------------------------------------------------
// K1 v6 (r27): STFT MFMA GEMM; A-tile staged in HALF-K sub-passes (24 KB)
// -> LDS 28 KB total -> ~5 blocks/CU (was 53 KB / ~2 blocks). Row mapping,
// XOR swizzle, B fragments, epilogue all identical to validated v5.
// mag [129][NW].
// ---------------------------------------------------------------------------
__global__ __launch_bounds__(256) void k_stft3(
    const float* __restrict__ audio, const bf16* __restrict__ Wb,
    bf16* __restrict__ mag)
{
  __shared__ __align__(16) char ALDS[96*256];      // 24 KB (half-K tile)
  __shared__ __align__(16) bf16 refl[4*8*64];      // 4 KB
  const int tid = threadIdx.x, lane = tid & 63, wq = tid >> 6;
  const int r0 = blockIdx.x * 4;                   // 2048 blocks
  const float* arow = audio + (size_t)(r0 + wq) * 4160;

  #pragma unroll
  for (int q = 0; q < 8; ++q){
    const int e = q*64 + lane;
    const int i = e >> 6, k = e & 63;
    refl[(wq*8 + i)*64 + k] = f2b(arow[512*i + 64 - k]);
  }

  const int kgo8 = (lane>>4)*8;
  short8 Bfrag[2][8];
  #pragma unroll
  for (int ng = 0; ng < 2; ++ng){
    const int wl = ng*16 + (lane & 15);
    const int i = wl >> 2, t = wl & 3;
    #pragma unroll
    for (int ks = 0; ks < 8; ++ks){
      const int kb = ks*32 + kgo8;
      if (t == 0 && kb < 64){
        Bfrag[ng][ks] = *(const short8*)(refl + (wq*8 + i)*64 + kb);
      } else {
        const float* src = arow + 512*i + 128*t - 64 + kb;
        const float4 v0 = *(const float4*)(src);
        const float4 v1 = *(const float4*)(src + 4);
        short8 s;
        s[0]=f2bs(v0.x); s[1]=f2bs(v0.y); s[2]=f2bs(v0.z); s[3]=f2bs(v0.w);
        s[4]=f2bs(v1.x); s[5]=f2bs(v1.y); s[6]=f2bs(v1.z); s[7]=f2bs(v1.w);
        Bfrag[ng][ks] = s;
      }
    }
  }

  const int kab = (lane>>4)*16;
  for (int pass = 0; pass < 3; ++pass){
    f32x4 accRe[3][2], accIm[3][2];
    #pragma unroll
    for (int b3 = 0; b3 < 3; ++b3)
      #pragma unroll
      for (int ng = 0; ng < 2; ++ng){
        accRe[b3][ng] = f32x4{0.f,0.f,0.f,0.f};
        accIm[b3][ng] = f32x4{0.f,0.f,0.f,0.f};
      }
    #pragma unroll
    for (int khalf = 0; khalf < 2; ++khalf){
      __syncthreads();                             // prev readers done
      for (int idx = tid; idx < 96*16; idx += 256){
        const int ar = idx >> 4;
        const int cb = (idx & 15) * 16;
        const int b3 = ar >> 5, reim = (ar >> 4) & 1, bl = ar & 15;
        int bin = pass*48 + b3*16 + bl;
        if (bin > 128) bin = 128;
        const int grow = bin + reim*129;
        int off = ar*256 + cb; off ^= ((ar&7)<<4);
        *(f32x4*)(ALDS + off) =
            *(const f32x4*)((const char*)Wb + grow*512 + khalf*256 + cb);
      }
      __syncthreads();                             // tile ready
      #pragma unroll
      for (int ksl = 0; ksl < 4; ++ksl){
        const int ks = khalf*4 + ksl;              // compile-time (khalf unrolled)
        #pragma unroll
        for (int b3 = 0; b3 < 3; ++b3){
          const int arRe = b3*32 + (lane & 15);
          const int arIm = arRe + 16;
          int offRe = arRe*256 + ksl*64 + kab; offRe ^= ((arRe&7)<<4);
          int offIm = arIm*256 + ksl*64 + kab; offIm ^= ((arIm&7)<<4);
          const short8 aRe = *(const short8*)(ALDS + offRe);
          const short8 aIm = *(const short8*)(ALDS + offIm);
          #pragma unroll
          for (int ng = 0; ng < 2; ++ng){
            accRe[b3][ng] = __builtin_amdgcn_mfma_f32_16x16x32_bf16(
                aRe, Bfrag[ng][ks], accRe[b3][ng], 0, 0, 0);
            accIm[b3][ng] = __builtin_amdgcn_mfma_f32_16x16x32_bf16(
                aIm, Bfrag[ng][ks], accIm[b3][ng], 0, 0, 0);
          }
        }
      }
    }
    #pragma unroll
    for (int b3 = 0; b3 < 3; ++b3)
      #pragma unroll
      for (int j = 0; j < 4; ++j){
        const int bin = (pass*3 + b3)*16 + (lane>>4)*4 + j;
        if (bin <= 128){
          #pragma unroll
          for (int ng = 0; ng < 2; ++ng){
            const int wl = ng*16 + (lane & 15);
            const int i = wl >> 2, t = wl & 3;
            const float re = accRe[b3][ng][j], im = accIm[b3][ng][j];
            mag[(size_t)bin*NW + (size_t)i*32768 + (r0+wq)*4 + t] =
                f2b(sqrtf(re*re + im*im));
          }
        }
      }
  }
}

// ---------------------------------------------------------------------------
// K2 FUSED (validated r25): enc1 -> enc2 -> enc3 -> enc4, chained via LDS.
// h4 [128][NTOT].
// ---------------------------------------------------------------------------
#define E1_LDS (192*320)
__global__ __launch_bounds__(256) void k_enc1234(
    const bf16* __restrict__ mag,
    const bf16* __restrict__ w1b, const float* __restrict__ b1,
    const bf16* __restrict__ w2b, const float* __restrict__ b2,
    const bf16* __restrict__ w3e, const float* __restrict__ b3,
    const bf16* __restrict__ w4e, const float* __restrict__ b4,
    bf16* __restrict__ h4)
{
  __shared__ __align__(16) char Bs[E1_LDS];       // 60 KB
  char* const B3 = Bs + 40960;
  char* const B4 = Bs + 49152;
  const int tid = threadIdx.x, lane = tid & 63, wq = tid >> 6;
  const int n0 = blockIdx.x * 32;
  const int i  = n0 >> 13, b0 = n0 & 8191;
  const size_t colbase = (size_t)i*32768 + (size_t)b0*4;
  const int kb = (lane>>4)*16;
  const int wr = wq >> 1, wc = wq & 1;

  for (int off = tid*16; off < E1_LDS; off += 256*16)
    *(f32x4*)(Bs + off) = f32x4{0.f,0.f,0.f,0.f};
  __syncthreads();
  for (int it = tid; it < 129*64; it += 256){
    const int cin = it >> 6, seg = it & 63;
    const unsigned int pair =
        *(const unsigned int*)(mag + (size_t)cin*NW + colbase + seg*2);
    #pragma unroll
    for (int q = 0; q < 2; ++q){
      const int w = seg*2 + q;
      const int row = (w>>2)*6 + (w&3) + 1;
      int off = row*320 + cin*2; off ^= ((row&7)<<4);
      *(short*)(Bs + off) = (short)((q==0) ? (pair & 0xffff) : (pair >> 16));
    }
  }
  __syncthreads();

  f32x4 acc1[4][4];
  #pragma unroll
  for (int mg = 0; mg < 4; ++mg)
    #pragma unroll
    for (int ng = 0; ng < 4; ++ng) acc1[mg][ng] = f32x4{0.f,0.f,0.f,0.f};
  int brow[4], acol[4];
  #pragma unroll
  for (int ng = 0; ng < 4; ++ng){
    const int w = wc*64 + ng*16 + (lane & 15);
    brow[ng] = (w>>2)*6 + (w&3);
  }
  #pragma unroll
  for (int mg = 0; mg < 4; ++mg) acol[mg] = wr*64 + mg*16 + (lane & 15);

  for (int dt = 0; dt < 3; ++dt){
    #pragma unroll
    for (int ks = 0; ks < 5; ++ks){
      short8 afr[4], bfr[4];
      #pragma unroll
      for (int mg = 0; mg < 4; ++mg)
        afr[mg] = *(const short8*)((const char*)w1b +
            ((dt*128 + acol[mg])*160 + ks*32)*2 + kb);
      #pragma unroll
      for (int ng = 0; ng < 4; ++ng){
        const int row = brow[ng] + dt;
        int off = row*320 + ks*64 + kb; off ^= ((row&7)<<4);
        bfr[ng] = *(const short8*)(Bs + off);
      }
      #pragma unroll
      for (int mg = 0; mg < 4; ++mg)
        #pragma unroll
        for (int ng = 0; ng < 4; ++ng)
          acc1[mg][ng] = __builtin_amdgcn_mfma_f32_16x16x32_bf16(
              afr[mg], bfr[ng], acc1[mg][ng], 0, 0, 0);
    }
  }
  __syncthreads();

  for (int it = tid; it < 32*16; it += 256){
    const int nloc = it >> 4, cb = (it & 15)*16;
    *(f32x4*)(Bs + (nloc*5)*256 + cb) = f32x4{0.f,0.f,0.f,0.f};
  }
  #pragma unroll
  for (int mg = 0; mg < 4; ++mg)
    #pragma unroll
    for (int j = 0; j < 4; ++j){
      const int cout = wr*64 + mg*16 + (lane>>4)*4 + j;
      const float bv = b1[cout];
      #pragma unroll
      for (int ng = 0; ng < 4; ++ng){
        const int w = wc*64 + ng*16 + (lane & 15);
        float v = acc1[mg][ng][j] + bv; v = v > 0.f ? v : 0.f;
        const int row5 = (w>>2)*5 + (w&3) + 1;
        int off = row5*256 + cout*2; off ^= ((row5&7)<<4);
        *(short*)(Bs + off) = f2bs(v);
      }
    }
  __syncthreads();

  f32x4 acc2[2][2];
  #pragma unroll
  for (int mg = 0; mg < 2; ++mg)
    #pragma unroll
    for (int ng = 0; ng < 2; ++ng) acc2[mg][ng] = f32x4{0.f,0.f,0.f,0.f};
  int brow2[2], acol2[2];
  #pragma unroll
  for (int ng = 0; ng < 2; ++ng){
    const int wl = wc*32 + ng*16 + (lane & 15);
    brow2[ng] = (wl>>1)*5 + (wl&1)*2;
  }
  #pragma unroll
  for (int mg = 0; mg < 2; ++mg) acol2[mg] = wr*32 + mg*16 + (lane & 15);

  for (int dt = 0; dt < 3; ++dt){
    #pragma unroll
    for (int ks = 0; ks < 4; ++ks){
      short8 afr[2], bfr[2];
      #pragma unroll
      for (int mg = 0; mg < 2; ++mg)
        afr[mg] = *(const short8*)((const char*)w2b +
            ((dt*64 + acol2[mg])*128 + ks*32)*2 + kb);
      #pragma unroll
      for (int ng = 0; ng < 2; ++ng){
        const int row = brow2[ng] + dt;
        int off = row*256 + ks*64 + kb; off ^= ((row&7)<<4);
        bfr[ng] = *(const short8*)(Bs + off);
      }
      #pragma unroll
      for (int mg = 0; mg < 2; ++mg)
        #pragma unroll
        for (int ng = 0; ng < 2; ++ng)
          acc2[mg][ng] = __builtin_amdgcn_mfma_f32_16x16x32_bf16(
              afr[mg], bfr[ng], acc2[mg][ng], 0, 0, 0);
    }
  }

  #pragma unroll
  for (int mg = 0; mg < 2; ++mg)
    #pragma unroll
    for (int j = 0; j < 4; ++j){
      const int cout2 = wr*32 + mg*16 + (lane>>4)*4 + j;
      const float bv = b2[cout2];
      #pragma unroll
      for (int ng = 0; ng < 2; ++ng){
        const int wl = wc*32 + ng*16 + (lane & 15);
        float v = acc2[mg][ng][j] + bv; v = v > 0.f ? v : 0.f;
        const int nloc = wl >> 1, tp = wl & 1;
        int off = nloc*256 + (cout2*2 + tp)*2; off ^= ((nloc&7)<<4);
        *(short*)(B3 + off) = f2bs(v);
      }
    }
  __syncthreads();

  f32x4 acc3[2];
  acc3[0] = f32x4{0.f,0.f,0.f,0.f};
  acc3[1] = f32x4{0.f,0.f,0.f,0.f};
  const int ar1 = wq*16 + (lane & 15);
  #pragma unroll
  for (int ks = 0; ks < 4; ++ks){
    const short8 a = *(const short8*)((const char*)w3e + (ar1*128 + ks*32)*2 + kb);
    #pragma unroll
    for (int ng = 0; ng < 2; ++ng){
      const int row = ng*16 + (lane & 15);
      int off = row*256 + ks*64 + kb; off ^= ((row&7)<<4);
      const short8 bfr = *(const short8*)(B3 + off);
      acc3[ng] = __builtin_amdgcn_mfma_f32_16x16x32_bf16(a, bfr, acc3[ng], 0, 0, 0);
    }
  }

  #pragma unroll
  for (int j = 0; j < 4; ++j){
    const int r1 = wq*16 + (lane>>4)*4 + j;
    const float bv = b3[r1];
    #pragma unroll
    for (int ng = 0; ng < 2; ++ng){
      const int col = ng*16 + (lane & 15);
      float v = acc3[ng][j] + bv; v = v > 0.f ? v : 0.f;
      int off = col*128 + r1*2; off ^= ((col&7)<<4);
      *(short*)(B4 + off) = f2bs(v);
    }
  }
  __syncthreads();

  f32x4 acc4[2][2];
  #pragma unroll
  for (int mg = 0; mg < 2; ++mg)
    #pragma unroll
    for (int ng = 0; ng < 2; ++ng) acc4[mg][ng] = f32x4{0.f,0.f,0.f,0.f};
  #pragma unroll
  for (int ks = 0; ks < 2; ++ks){
    short8 bfr[2];
    #pragma unroll
    for (int ng = 0; ng < 2; ++ng){
      const int row = ng*16 + (lane & 15);
      int off = row*128 + ks*64 + kb; off ^= ((row&7)<<4);
      bfr[ng] = *(const short8*)(B4 + off);
    }
    #pragma unroll
    for (int mg = 0; mg < 2; ++mg){
      const int ar2 = wq*32 + mg*16 + (lane & 15);
      const short8 a = *(const short8*)((const char*)w4e + (ar2*64 + ks*32)*2 + kb);
      #pragma unroll
      for (int ng = 0; ng < 2; ++ng)
        acc4[mg][ng] = __builtin_amdgcn_mfma_f32_16x16x32_bf16(a, bfr[ng], acc4[mg][ng], 0, 0, 0);
    }
  }
  #pragma unroll
  for (int mg = 0; mg < 2; ++mg)
    #pragma unroll
    for (int j = 0; j < 4; ++j){
      const int cout = wq*32 + mg*16 + (lane>>4)*4 + j;
      const float bv = b4[cout];
      #pragma unroll
      for (int ng = 0; ng < 2; ++ng){
        const int n = n0 + ng*16 + (lane & 15);
        float v = acc4[mg][ng][j] + bv; v = v > 0.f ? v : 0.f;
        h4[(size_t)cout*NTOT + n] = f2b(v);
      }
    }
}

// ---------------------------------------------------------------------------
// K-GX (validated r26): xg[512][65536] = Wih @ x.
// ---------------------------------------------------------------------------
__global__ __launch_bounds__(256) void k_gatex(
    const bf16* __restrict__ h4, const bf16* __restrict__ wlx,
    float* __restrict__ xg, int half)
{
  __shared__ __align__(16) char Bs[32*256];
  const int tid = threadIdx.x, lane = tid & 63, wq = tid >> 6;
  const int n0 = blockIdx.x * 32;
  const int gcol = half*32768 + n0;

  for (int it = tid; it < 128*32; it += 256){
    const int cp = it >> 5, nl = it & 31;
    const bf16 v = h4[(size_t)cp*NTOT + gcol + nl];
    int off = nl*256 + cp*2; off ^= ((nl&7)<<4);
    *(short*)(Bs + off) = *(const short*)&v;
  }
  __syncthreads();

  f32x4 acc[8][2];
  #pragma unroll
  for (int mg = 0; mg < 8; ++mg)
    #pragma unroll
    for (int ng = 0; ng < 2; ++ng) acc[mg][ng] = f32x4{0.f,0.f,0.f,0.f};

  int arow[8];
  #pragma unroll
  for (int mg = 0; mg < 8; ++mg) arow[mg] = wq*128 + mg*16 + (lane & 15);
  const int kb = (lane>>4)*16;

  #pragma unroll
  for (int ks = 0; ks < 4; ++ks){
    short8 bfr[2];
    #pragma unroll
    for (int ng = 0; ng < 2; ++ng){
      const int row = ng*16 + (lane & 15);
      int off = row*256 + ks*64 + kb; off ^= ((row&7)<<4);
      bfr[ng] = *(const short8*)(Bs + off);
    }
    #pragma unroll
    for (int mg = 0; mg < 8; ++mg){
      const short8 a = *(const short8*)((const char*)wlx +
          ((size_t)arow[mg]*128 + ks*32)*2 + kb);
      #pragma unroll
      for (int ng = 0; ng < 2; ++ng)
        acc[mg][ng] = __builtin_amdgcn_mfma_f32_16x16x32_bf16(
            a, bfr[ng], acc[mg][ng], 0, 0, 0);
    }
  }

  #pragma unroll
  for (int mg = 0; mg < 8; ++mg)
    #pragma unroll
    for (int j = 0; j < 4; ++j){
      const int row = wq*128 + mg*16 + (lane>>4)*4 + j;
      #pragma unroll
      for (int ng = 0; ng < 2; ++ng){
        const int col = gcol + ng*16 + (lane & 15);
        xg[(size_t)row*65536 + col] = acc[mg][ng][j];
      }
    }
}

// ---------------------------------------------------------------------------
// K7 FUSED (validated r26): all 8 LSTM steps + head + outputs.
// ---------------------------------------------------------------------------
__global__ __launch_bounds__(256) void k_lstm_all2(
    const float* __restrict__ xg, const bf16* __restrict__ wl1,
    const float* __restrict__ bih, const float* __restrict__ bhh,
    const float* __restrict__ h0, const float* __restrict__ c0,
    const float* __restrict__ ow, const float* __restrict__ ob,
    float* __restrict__ out)
{
  __shared__ __align__(16) char Bs[32*256];       // 8 KB h tile
  __shared__ float Ppart[16*32];
  __shared__ float Pprod[32];
  const int tid = threadIdx.x, lane = tid & 63, wq = tid >> 6;
  const int b0 = blockIdx.x * 32;
  const int c0r = wq*32;

  for (int it = tid; it < 128*32; it += 256){
    const int cp = it >> 5, bl = it & 31;
    const float v = h0[(size_t)(b0 + bl)*128 + cp];
    int off = bl*256 + cp*2; off ^= ((bl&7)<<4);
    *(short*)(Bs + off) = f2bs(v);
  }
  float cst[2][2][4], bsum[4][2][4], owv[2][4];
  #pragma unroll
  for (int h = 0; h < 2; ++h)
    #pragma unroll
    for (int j = 0; j < 4; ++j){
      const int c = c0r + h*16 + (lane>>4)*4 + j;
      owv[h][j] = ow[c];
      #pragma unroll
      for (int g = 0; g < 4; ++g)
        bsum[g][h][j] = bih[g*128 + c] + bhh[g*128 + c];
      #pragma unroll
      for (int ng = 0; ng < 2; ++ng)
        cst[h][ng][j] = c0[(size_t)(b0 + ng*16 + (lane & 15))*128 + c];
    }
  if (tid < 32) Pprod[tid] = 1.f;
  const float obv = ob[0];

  int arow[4][2];
  #pragma unroll
  for (int g = 0; g < 4; ++g)
    #pragma unroll
    for (int h = 0; h < 2; ++h)
      arow[g][h] = (g*128 + c0r + h*16 + (lane&15))*256 + (lane>>4)*16;

  __syncthreads();

  for (int s = 0; s < 8; ++s){
    f32x4 acc[4][2][2];
    #pragma unroll
    for (int g = 0; g < 4; ++g)
      #pragma unroll
      for (int h = 0; h < 2; ++h)
        #pragma unroll
        for (int ng = 0; ng < 2; ++ng) acc[g][h][ng] = f32x4{0.f,0.f,0.f,0.f};
    #pragma unroll
    for (int ks = 0; ks < 4; ++ks){
      short8 bfr[2];
      #pragma unroll
      for (int ng = 0; ng < 2; ++ng){
        const int row = ng*16 + (lane & 15);
        int off = row*256 + ks*64 + (lane>>4)*16; off ^= ((row&7)<<4);
        bfr[ng] = *(const short8*)(Bs + off);
      }
      #pragma unroll
      for (int g = 0; g < 4; ++g)
        #pragma unroll
        for (int h = 0; h < 2; ++h){
          const short8 a = *(const short8*)((const char*)wl1 + arow[g][h] + ks*64);
          #pragma unroll
          for (int ng = 0; ng < 2; ++ng)
            acc[g][h][ng] = __builtin_amdgcn_mfma_f32_16x16x32_bf16(
                a, bfr[ng], acc[g][h][ng], 0, 0, 0);
        }
    }
    __syncthreads();

    float psum0 = 0.f, psum1 = 0.f;
    #pragma unroll
    for (int h = 0; h < 2; ++h)
      #pragma unroll
      for (int ng = 0; ng < 2; ++ng)
        #pragma unroll
        for (int j = 0; j < 4; ++j){
          const int c = c0r + h*16 + (lane>>4)*4 + j;
          const int b = b0 + ng*16 + (lane & 15);
          const size_t xc = (size_t)s*8192 + b;
          const float ig = acc[0][h][ng][j] + xg[(size_t)(0*128+c)*65536 + xc] + bsum[0][h][j];
          const float fg = acc[1][h][ng][j] + xg[(size_t)(1*128+c)*65536 + xc] + bsum[1][h][j];
          const float gg = acc[2][h][ng][j] + xg[(size_t)(2*128+c)*65536 + xc] + bsum[2][h][j];
          const float og = acc[3][h][ng][j] + xg[(size_t)(3*128+c)*65536 + xc] + bsum[3][h][j];
          const float cn = sigf(fg)*cst[h][ng][j] + sigf(ig)*tanhfast(gg);
          const float hn = sigf(og)*tanhfast(cn);
          cst[h][ng][j] = cn;
          const float pw = owv[h][j] * hn;
          if (ng == 0) psum0 += pw; else psum1 += pw;
          const int bl = ng*16 + (lane & 15);
          int off = bl*256 + c*2; off ^= ((bl&7)<<4);
          *(short*)(Bs + off) = f2bs(hn);
          if (s == 7){
            out[8192 + (size_t)b*128 + c]           = hn;
            out[8192 + 1048576 + (size_t)b*128 + c] = cn;
          }
        }
    Ppart[(wq*4 + (lane>>4))*32 + (lane & 15)]      = psum0;
    Ppart[(wq*4 + (lane>>4))*32 + 16 + (lane & 15)] = psum1;
    __syncthreads();
    if (tid < 32){
      float a2 = obv;
      #pragma unroll
      for (int q2 = 0; q2 < 16; ++q2) a2 += Ppart[q2*32 + tid];
      Pprod[tid] *= (1.f - sigf(a2));
    }
  }
  if (tid < 32) out[b0 + tid] = 1.f - Pprod[tid];
}

// ---------------------------------------------------------------------------
extern "C" void kernel_launch(void* const* d_in, const int* in_sizes, int n_in,
                              void* d_out, int out_size, void* d_ws, size_t ws_size,
                              hipStream_t stream)
{
  (void)in_sizes; (void)n_in; (void)out_size; (void)ws_size;
  const float* audio = (const float*)d_in[0];
  const float* h0    = (const float*)d_in[1];
  const float* c0    = (const float*)d_in[2];
  const float* stftw = (const float*)d_in[3];
  const float* w1 = (const float*)d_in[4];  const float* b1 = (const float*)d_in[5];
  const float* w2 = (const float*)d_in[6];  const float* b2 = (const float*)d_in[7];
  const float* w3 = (const float*)d_in[8];  const float* b3 = (const float*)d_in[9];
  const float* w4 = (const float*)d_in[10]; const float* b4 = (const float*)d_in[11];
  const float* wih = (const float*)d_in[12]; const float* whh = (const float*)d_in[13];
  const float* bih = (const float*)d_in[14]; const float* bhh = (const float*)d_in[15];
  const float* ow  = (const float*)d_in[16]; const float* ob  = (const float*)d_in[17];
  float* out = (float*)d_out;

  // Workspace schedule (validated r26):
  char* ws = (char*)d_ws;
  float* xg   = (float*)(ws + 0);
  bf16*  mag  = (bf16*) (ws + 0);
  bf16*  h4   = (bf16*) (ws + 134217728);
  bf16*  Wbf  = (bf16*) (ws + 134217728);
  bf16*  w1b  = (bf16*) (ws + 150994944);
  bf16*  w2b  = (bf16*) (ws + 151117824);
  bf16*  w3e  = (bf16*) (ws + 151166976);
  bf16*  w4e  = (bf16*) (ws + 151183360);
  bf16*  wl1  = (bf16*) (ws + 151199744);
  bf16*  wlx  = (bf16*) (ws + 151330816);

  k_allcvt<<<1170, 256, 0, stream>>>(stftw, w1, w2, w3, w4, whh, wih,
                                     Wbf, w1b, w2b, w3e, w4e, wl1, wlx);
  k_stft3<<<2048, 256, 0, stream>>>(audio, Wbf, mag);
  k_enc1234<<<2048, 256, 0, stream>>>(mag, w1b, b1, w2b, b2, w3e, b3,
                                      w4e, b4, h4);
  k_gatex<<<1024, 256, 0, stream>>>(h4, wlx, xg, 0);
  k_gatex<<<1024, 256, 0, stream>>>(h4, wlx, xg, 1);
  k_lstm_all2<<<256, 256, 0, stream>>>(xg, wl1, bih, bhh, h0, c0, ow, ob, out);
}